// Round 8
// baseline (234.118 us; speedup 1.0000x reference)
//
#include <hip/hip_runtime.h>
#include <hip/hip_bf16.h>
#include <math.h>

#define LSEQ 320
#define CS 384
#define CZ 128
#define CH 16
#define NH 12
#define PQ 4
#define PV 8
#define EPSF 1e-8f

typedef short short8 __attribute__((ext_vector_type(8)));
typedef float f32x4 __attribute__((ext_vector_type(4)));

// float -> bf16 (RNE)
__device__ __forceinline__ unsigned short f2b(float x) {
    union { float f; unsigned u; } v; v.f = x;
    unsigned r = (v.u + 0x7FFF + ((v.u >> 16) & 1)) >> 16;
    return (unsigned short)r;
}
__device__ __forceinline__ float b2f(unsigned short h) {
    union { unsigned u; float f; } v; v.u = ((unsigned)h) << 16;
    return v.f;
}

// workspace float offsets (~25 MB total; ws >= 256MB per fillBuffer evidence)
#define OFF_Q       0         // fp32 [320][192]
#define OFF_KV      61440     // fp32 [320][384]
#define OFF_QPT     184320    // fp32 [320][48][6]
#define OFF_KPT     276480    // fp32 [320][48][6]
#define OFF_KNRM    368640    // fp32 [48][320]
#define OFF_ATTHI   552960    // bf16 [16][320][320] (planes 12-15 zeroed)
#define OFF_ATTLO   1372160   // bf16 [16][320][320]
#define OFF_CCHI    2191360   // bf16 [320][2400]
#define OFF_CCLO    2575360   // bf16 [320][2400]
#define OFF_SHI     2959360   // bf16 [320][384]
#define OFF_SMID    2990080
#define OFF_SLO     3020800
#define OFF_WCATHI  3051520   // bf16 [384][1776]
#define OFF_WCATMID 3392512
#define OFF_WCATLO  3733504
#define OFF_BCAT    4074496   // fp32 [1776]
#define OFF_WOHI    4076272   // bf16 [2400][384]
#define OFF_WOLO    4537072
#define OFF_VKVHI   4997872   // bf16 [12][64][320]
#define OFF_VKVLO   5120752
#define OFF_QPR     5243632   // fp32 [320][288]
#define OFF_KVPR    5335792   // fp32 [320][864]
#define OFF_GATE    5612272   // fp32 [320][48]
#define OFF_PART    5627632   // fp32 [5][320][384]

// ---------------- kernel 0: cast inputs (3-way s/wcat, 2-way wo), zero phantom ----
// items: s 122880 | wcat 681984 | bcat 1776 | wo 921600 | ph_hi 204800 | ph_lo 204800
//        -> 2137840 -> 8352 blocks
__global__ __launch_bounds__(256) void k_cast(
    const float* __restrict__ s,
    const float* __restrict__ Wq, const float* __restrict__ bq,
    const float* __restrict__ Wkv, const float* __restrict__ bkv,
    const float* __restrict__ Wqp, const float* __restrict__ bqp,
    const float* __restrict__ Wkvp, const float* __restrict__ bkvp,
    const float* __restrict__ Wg, const float* __restrict__ bg,
    const float* __restrict__ Wo,
    unsigned short* __restrict__ s_hi, unsigned short* __restrict__ s_mid,
    unsigned short* __restrict__ s_lo,
    unsigned short* __restrict__ w_hi, unsigned short* __restrict__ w_mid,
    unsigned short* __restrict__ w_lo,
    float* __restrict__ bcat,
    unsigned short* __restrict__ wo_hi, unsigned short* __restrict__ wo_lo,
    float* __restrict__ ph_hi, float* __restrict__ ph_lo)
{
    int i = blockIdx.x * 256 + threadIdx.x;
    if (i < 122880) {
        float x = s[i];
        unsigned short hi = f2b(x);
        float r1 = x - b2f(hi);
        unsigned short mid = f2b(r1);
        s_hi[i] = hi; s_mid[i] = mid; s_lo[i] = f2b(r1 - b2f(mid));
        return;
    }
    i -= 122880;
    if (i < 681984) {
        int k = i / 1776, c = i - k * 1776;
        float v;
        if (c < 192)       v = Wq[(size_t)k * 192 + c];
        else if (c < 576)  v = Wkv[(size_t)k * 384 + c - 192];
        else if (c < 864)  v = Wqp[(size_t)k * 288 + c - 576];
        else if (c < 1728) v = Wkvp[(size_t)k * 864 + c - 864];
        else               v = Wg[(size_t)k * 48 + c - 1728];
        unsigned short hi = f2b(v);
        float r1 = v - b2f(hi);
        unsigned short mid = f2b(r1);
        w_hi[i] = hi; w_mid[i] = mid; w_lo[i] = f2b(r1 - b2f(mid));
        return;
    }
    i -= 681984;
    if (i < 1776) {
        float v;
        if (i < 192)       v = bq[i];
        else if (i < 576)  v = bkv[i - 192];
        else if (i < 864)  v = bqp[i - 576];
        else if (i < 1728) v = bkvp[i - 864];
        else               v = bg[i - 1728];
        bcat[i] = v;
        return;
    }
    i -= 1776;
    if (i < 921600) {
        float v = Wo[i];
        unsigned short hi = f2b(v);
        wo_hi[i] = hi; wo_lo[i] = f2b(v - b2f(hi));
        return;
    }
    i -= 921600;
    if (i < 204800) { ph_hi[i] = 0.0f; return; }
    i -= 204800;
    if (i < 204800) ph_lo[i] = 0.0f;
}

// ---------------- kernel 1: projection GEMM, 3-way split MFMA (fp32-equivalent) ----
// grid (37 n-tiles of 48, 5 m-tiles of 64), 256 thr.
__global__ __launch_bounds__(256) void k_proj(
    const unsigned short* __restrict__ s_hi, const unsigned short* __restrict__ s_mid,
    const unsigned short* __restrict__ s_lo,
    const unsigned short* __restrict__ wc_hi, const unsigned short* __restrict__ wc_mid,
    const unsigned short* __restrict__ wc_lo,
    const float* __restrict__ bcat,
    float* __restrict__ qo, float* __restrict__ kvo,
    float* __restrict__ qpr, float* __restrict__ kvpr, float* __restrict__ gate)
{
    __shared__ unsigned short a_h[64][56], a_m[64][56], a_l[64][56];
    __shared__ unsigned short w_h[48][56], w_m[48][56], w_l[48][56];
    int col0 = blockIdx.x * 48, l0 = blockIdx.y * 64;
    int tid = threadIdx.x;
    int lane = tid & 63, w = tid >> 6;
    int ncol = lane & 15, blk = lane >> 4, mrow = (lane >> 4) * 4;

    float* dst; int nc, cbase; bool sig = false;
    if (col0 < 192)       { nc = 192; cbase = col0;        dst = qo;   }
    else if (col0 < 576)  { nc = 384; cbase = col0 - 192;  dst = kvo;  }
    else if (col0 < 864)  { nc = 288; cbase = col0 - 576;  dst = qpr;  }
    else if (col0 < 1728) { nc = 864; cbase = col0 - 864;  dst = kvpr; }
    else                  { nc = 48;  cbase = 0;           dst = gate; sig = true; }

    f32x4 acc[3] = {};
    for (int k0 = 0; k0 < 384; k0 += 32) {
        __syncthreads();
        {
            int row = tid >> 2, seg = tid & 3;
            size_t off = (size_t)(l0 + row) * 384 + k0 + seg * 8;
            *(short8*)&a_h[row][seg * 8] = *(const short8*)(s_hi + off);
            *(short8*)&a_m[row][seg * 8] = *(const short8*)(s_mid + off);
            *(short8*)&a_l[row][seg * 8] = *(const short8*)(s_lo + off);
        }
        if (tid < 96) {
            int kk = tid / 3, coff = (tid % 3) * 16;
            size_t off = (size_t)(k0 + kk) * 1776 + col0 + coff;
            short8 h0 = *(const short8*)(wc_hi + off);
            short8 h1 = *(const short8*)(wc_hi + off + 8);
            short8 m0 = *(const short8*)(wc_mid + off);
            short8 m1 = *(const short8*)(wc_mid + off + 8);
            short8 l0v = *(const short8*)(wc_lo + off);
            short8 l1v = *(const short8*)(wc_lo + off + 8);
            #pragma unroll
            for (int i = 0; i < 8; i++) {
                w_h[coff + i][kk]     = (unsigned short)h0[i];
                w_h[coff + 8 + i][kk] = (unsigned short)h1[i];
                w_m[coff + i][kk]     = (unsigned short)m0[i];
                w_m[coff + 8 + i][kk] = (unsigned short)m1[i];
                w_l[coff + i][kk]     = (unsigned short)l0v[i];
                w_l[coff + 8 + i][kk] = (unsigned short)l1v[i];
            }
        }
        __syncthreads();
        short8 afh = *(short8*)&a_h[w * 16 + ncol][blk * 8];
        short8 afm = *(short8*)&a_m[w * 16 + ncol][blk * 8];
        short8 afl = *(short8*)&a_l[w * 16 + ncol][blk * 8];
        #pragma unroll
        for (int s3 = 0; s3 < 3; s3++) {
            short8 bfh = *(short8*)&w_h[s3 * 16 + ncol][blk * 8];
            short8 bfm = *(short8*)&w_m[s3 * 16 + ncol][blk * 8];
            short8 bfl = *(short8*)&w_l[s3 * 16 + ncol][blk * 8];
            acc[s3] = __builtin_amdgcn_mfma_f32_16x16x32_bf16(afm, bfm, acc[s3], 0, 0, 0);
            acc[s3] = __builtin_amdgcn_mfma_f32_16x16x32_bf16(afh, bfl, acc[s3], 0, 0, 0);
            acc[s3] = __builtin_amdgcn_mfma_f32_16x16x32_bf16(afl, bfh, acc[s3], 0, 0, 0);
            acc[s3] = __builtin_amdgcn_mfma_f32_16x16x32_bf16(afh, bfm, acc[s3], 0, 0, 0);
            acc[s3] = __builtin_amdgcn_mfma_f32_16x16x32_bf16(afm, bfh, acc[s3], 0, 0, 0);
            acc[s3] = __builtin_amdgcn_mfma_f32_16x16x32_bf16(afh, bfh, acc[s3], 0, 0, 0);
        }
    }
    #pragma unroll
    for (int s3 = 0; s3 < 3; s3++) {
        float bv = bcat[col0 + s3 * 16 + ncol];
        int cloc = cbase + s3 * 16 + ncol;
        #pragma unroll
        for (int r = 0; r < 4; r++) {
            float v2 = acc[s3][r] + bv;
            if (sig) v2 = 1.0f / (1.0f + expf(-v2));
            dst[(size_t)(l0 + w * 16 + mrow + r) * nc + cloc] = v2;
        }
    }
}

// ---------------- kernel 2: frame transforms + vkvT hi/lo + k-dir norms ----------
__global__ __launch_bounds__(256) void k_points(
    const float* __restrict__ qpr, const float* __restrict__ kvpr, const float* __restrict__ gate,
    const float* __restrict__ rot, const float* __restrict__ trans,
    const float* __restrict__ kv,
    float* __restrict__ qpt, float* __restrict__ kpt, float* __restrict__ knrm,
    unsigned short* __restrict__ vkv_hi, unsigned short* __restrict__ vkv_lo)
{
    __shared__ float vsh[96][6];
    int l = blockIdx.x, t = threadIdx.x;
    const float* R = rot + l * 9;
    float tx = trans[l * 3], ty = trans[l * 3 + 1], tz = trans[l * 3 + 2];
    if (t < 192) {
        const float* src; float g = 1.0f; float* dst = nullptr; int vj = -1;
        if (t < 48)      { src = qpr + (size_t)l * 288 + t * 6; g = gate[l * 48 + t]; dst = qpt + ((size_t)l * 48 + t) * 6; }
        else if (t < 96) { int j = t - 48; src = kvpr + (size_t)l * 864 + j * 6; dst = kpt + ((size_t)l * 48 + j) * 6; }
        else             { int j = t - 96; src = kvpr + (size_t)l * 864 + 288 + j * 6; vj = j; }
        float px = src[0], py = src[1], pz = src[2], ux = src[3], uy = src[4], uz = src[5];
        float c0 = R[0] * px + R[1] * py + R[2] * pz + tx;
        float c1 = R[3] * px + R[4] * py + R[5] * pz + ty;
        float c2 = R[6] * px + R[7] * py + R[8] * pz + tz;
        float d0 = R[0] * ux + R[1] * uy + R[2] * uz;
        float d1 = R[3] * ux + R[4] * uy + R[5] * uz;
        float d2 = R[6] * ux + R[7] * uy + R[8] * uz;
        if (vj >= 0) {
            vsh[vj][0] = c0; vsh[vj][1] = c1; vsh[vj][2] = c2;
            vsh[vj][3] = d0; vsh[vj][4] = d1; vsh[vj][5] = d2;
        } else {
            dst[0] = c0 * g; dst[1] = c1 * g; dst[2] = c2 * g;
            dst[3] = d0 * g; dst[4] = d1 * g; dst[5] = d2 * g;
            if (t >= 48) {
                knrm[(size_t)(t - 48) * 320 + l] = sqrtf(d0 * d0 + d1 * d1 + d2 * d2);
            }
        }
    }
    __syncthreads();
    #pragma unroll
    for (int e = 0; e < 3; e++) {
        int u = t * 3 + e;   // < 768
        int h = u >> 6, n = u & 63;
        float val;
        if (n < 16) val = kv[(size_t)l * 384 + 192 + h * 16 + n];
        else        val = vsh[h * 8 + (n - 16) / 6][(n - 16) % 6];
        unsigned short hi = f2b(val);
        size_t idx = ((size_t)h * 64 + n) * 320 + l;
        vkv_hi[idx] = hi;
        vkv_lo[idx] = f2b(val - b2f(hi));
    }
}

// ---------------- kernel 3: attention logits + softmax -> att hi/lo ----------------
// grid (80, 12), 256 thr = 4 waves (one iq per wave, all share h).
__global__ __launch_bounds__(256) void k_att(
    const float* __restrict__ qb, const float* __restrict__ kvb,
    const float* __restrict__ qpt, const float* __restrict__ kpt,
    const float* __restrict__ knrm,
    const float* __restrict__ fm, const float* __restrict__ gw,
    const float* __restrict__ dwp, const float* __restrict__ hwp,
    unsigned short* __restrict__ att_hi, unsigned short* __restrict__ att_lo)
{
    __shared__ float kp_sh[320][45];
    int tid = threadIdx.x;
    int w = tid >> 6, lane = tid & 63;
    int iq = blockIdx.x * 4 + w;
    int h = blockIdx.y;

    for (int idx = tid; idx < 320 * 44; idx += 256) {
        int kk = idx / 44, j = idx - kk * 44;
        float v;
        if (j < 24)      v = kpt[(size_t)kk * 288 + h * 24 + j];
        else if (j < 40) v = kvb[(size_t)kk * 384 + h * 16 + (j - 24)];
        else             v = knrm[(size_t)(h * 4 + (j - 40)) * 320 + kk];
        kp_sh[kk][j] = v;
    }
    __syncthreads();

    float qv[CH];
    #pragma unroll
    for (int c = 0; c < CH; c++) qv[c] = qb[(size_t)iq * 192 + h * CH + c];
    float qp[24];
    #pragma unroll
    for (int j = 0; j < 24; j++) qp[j] = qpt[(size_t)iq * 288 + h * 24 + j];
    float nq[PQ], nq2[PQ];
    #pragma unroll
    for (int p = 0; p < PQ; p++) {
        float x = qp[p * 6 + 3], y = qp[p * 6 + 4], zz = qp[p * 6 + 5];
        nq2[p] = x * x + y * y + zz * zz;
        nq[p] = sqrtf(nq2[p]);
    }
    float dwv = dwp[0], g0 = gw[0], g1 = gw[1], hwv = hwp[h];
    float fmi = fm[iq];

    float lg[5];
    #pragma unroll
    for (int r = 0; r < 5; r++) {
        int kk = r * 64 + lane;
        const float* row = &kp_sh[kk][0];

        float scalar = 0.f;
        #pragma unroll
        for (int c = 0; c < CH; c++) scalar += qv[c] * row[24 + c];
        scalar *= 0.25f;

        float pos = 0.f;
        #pragma unroll
        for (int p = 0; p < PQ; p++) {
            float dx = qp[p * 6] - row[p * 6];
            float dy = qp[p * 6 + 1] - row[p * 6 + 1];
            float dz = qp[p * 6 + 2] - row[p * 6 + 2];
            float d = __builtin_amdgcn_sqrtf(dx * dx + dy * dy + dz * dz);
            float de = d + EPSF;
            pos += d + __logf(de) + __builtin_amdgcn_rcpf(de);
        }
        pos *= 0.25f;

        float dir = 0.f;
        #pragma unroll
        for (int p = 0; p < PQ; p++) {
            float kx = row[p * 6 + 3], ky = row[p * 6 + 4], kz = row[p * 6 + 5];
            float nk = row[40 + p];
            float nk2 = nk * nk;
            float cm = 0.f, dself = 0.f;
            #pragma unroll
            for (int pq = 0; pq < PQ; pq++) {
                float dq = qp[pq * 6 + 3] * kx + qp[pq * 6 + 4] * ky + qp[pq * 6 + 5] * kz;
                if (pq == p) dself = dq;
                cm += __builtin_amdgcn_sqrtf(fmaxf(nq2[pq] * nk2 - dq * dq, 0.0f));
            }
            cm *= 0.25f;
            dir += dself - cm * __builtin_amdgcn_rcpf(nq[p] * nk + EPSF);
        }
        dir *= 0.25f;

        float logit = scalar + dwv * (g0 * pos + g1 * dir);
        logit *= hwv;
        logit += 100000.0f * (fmi * fm[kk] - 1.0f);
        lg[r] = logit;
    }

    float mx = lg[0];
    #pragma unroll
    for (int r = 1; r < 5; r++) mx = fmaxf(mx, lg[r]);
    for (int m = 32; m; m >>= 1) mx = fmaxf(mx, __shfl_xor(mx, m, 64));

    float e[5], sm = 0.f;
    #pragma unroll
    for (int r = 0; r < 5; r++) { e[r] = __expf(lg[r] - mx); sm += e[r]; }
    for (int m = 32; m; m >>= 1) sm += __shfl_xor(sm, m, 64);
    float inv = 1.0f / sm;
    #pragma unroll
    for (int r = 0; r < 5; r++) {
        float p = e[r] * inv;
        unsigned short hi = f2b(p);
        size_t idx = ((size_t)h * 320 + iq) * 320 + r * 64 + lane;
        att_hi[idx] = hi;
        att_lo[idx] = f2b(p - b2f(hi));
    }
}

// ---------------- kernel 5: o_scalar + o_geom via split MFMA + fused finish ------
// per (iq-tile of 16, h): [16 x 320] @ [320 x 64]. grid (20,12), 64 thr.
__global__ __launch_bounds__(64) void k_sv(
    const unsigned short* __restrict__ att_hi, const unsigned short* __restrict__ att_lo,
    const unsigned short* __restrict__ vkv_hi, const unsigned short* __restrict__ vkv_lo,
    const float* __restrict__ rot, const float* __restrict__ trans,
    unsigned short* __restrict__ cc_hi, unsigned short* __restrict__ cc_lo)
{
    __shared__ unsigned short a_hi[16][56];
    __shared__ unsigned short a_lo[16][56];
    __shared__ unsigned short bt_hi[64][56];
    __shared__ unsigned short bt_lo[64][56];
    __shared__ float ogsh[16][49];
    int iq0 = blockIdx.x * 16, h = blockIdx.y;
    int tid = threadIdx.x;
    int ncol = tid & 15, blk = tid >> 4, mrow = (tid >> 4) * 4;

    f32x4 acc[4] = {};
    for (int k0 = 0; k0 < 320; k0 += 32) {
        __syncthreads();
        {
            int row = tid >> 2, seg = tid & 3;
            size_t off = ((size_t)h * 320 + iq0 + row) * 320 + k0 + seg * 8;
            *(short8*)&a_hi[row][seg * 8] = *(const short8*)(att_hi + off);
            *(short8*)&a_lo[row][seg * 8] = *(const short8*)(att_lo + off);
        }
        {
            size_t off = ((size_t)h * 64 + tid) * 320 + k0;
            #pragma unroll
            for (int j2 = 0; j2 < 4; j2++) {
                *(short8*)&bt_hi[tid][j2 * 8] = *(const short8*)(vkv_hi + off + j2 * 8);
                *(short8*)&bt_lo[tid][j2 * 8] = *(const short8*)(vkv_lo + off + j2 * 8);
            }
        }
        __syncthreads();
        short8 afh = *(short8*)&a_hi[ncol][blk * 8];
        short8 afl = *(short8*)&a_lo[ncol][blk * 8];
        #pragma unroll
        for (int s4 = 0; s4 < 4; s4++) {
            short8 bfh = *(short8*)&bt_hi[s4 * 16 + ncol][blk * 8];
            short8 bfl = *(short8*)&bt_lo[s4 * 16 + ncol][blk * 8];
            acc[s4] = __builtin_amdgcn_mfma_f32_16x16x32_bf16(afh, bfh, acc[s4], 0, 0, 0);
            acc[s4] = __builtin_amdgcn_mfma_f32_16x16x32_bf16(afh, bfl, acc[s4], 0, 0, 0);
            acc[s4] = __builtin_amdgcn_mfma_f32_16x16x32_bf16(afl, bfh, acc[s4], 0, 0, 0);
        }
    }
    #pragma unroll
    for (int s4 = 0; s4 < 4; s4++) {
        int n = s4 * 16 + ncol;
        #pragma unroll
        for (int r = 0; r < 4; r++) {
            int iq = iq0 + mrow + r;
            float v = acc[s4][r];
            if (n < 16) {
                unsigned short hi = f2b(v);
                size_t idx = (size_t)iq * 2400 + h * 16 + n;
                cc_hi[idx] = hi;
                cc_lo[idx] = f2b(v - b2f(hi));
            } else {
                ogsh[mrow + r][n - 16] = v;
            }
        }
    }
    __syncthreads();
    #pragma unroll
    for (int t2 = tid; t2 < 128; t2 += 64) {
        int iqr = t2 >> 3, p = t2 & 7;
        int l = iq0 + iqr;
        const float* R = rot + l * 9;
        float tx = trans[l * 3], ty = trans[l * 3 + 1], tz = trans[l * 3 + 2];
        const float* o = &ogsh[iqr][p * 6];
        float gx = o[0] - tx, gy = o[1] - ty, gz = o[2] - tz;
        float l0 = R[0] * gx + R[3] * gy + R[6] * gz;
        float l1 = R[1] * gx + R[4] * gy + R[7] * gz;
        float l2 = R[2] * gx + R[5] * gy + R[8] * gz;
        float dx = o[3], dy = o[4], dz = o[5];
        float e0 = R[0] * dx + R[3] * dy + R[6] * dz;
        float e1 = R[1] * dx + R[4] * dy + R[7] * dz;
        float e2 = R[2] * dx + R[5] * dy + R[8] * dz;
        float n = sqrtf(e0 * e0 + e1 * e1 + e2 * e2);
        float inv = 1.0f / fmaxf(n, 1e-12f);
        float ln = sqrtf(l0 * l0 + l1 * l1 + l2 * l2);
        float vals[7] = { l0, l1, l2, e0 * inv, e1 * inv, e2 * inv, ln };
        size_t base = (size_t)l * 2400 + 192 + (h * PV + p) * 7;
        #pragma unroll
        for (int j = 0; j < 7; j++) {
            unsigned short hi = f2b(vals[j]);
            cc_hi[base + j] = hi;
            cc_lo[base + j] = f2b(vals[j] - b2f(hi));
        }
    }
}

// ---------------- kernel 6: o_pair via MFMA (att hi+lo, z plain bf16) -------------
// per iq: [16(h) x 320] @ [320 x 128]. grid (320), 256 thr.
__global__ __launch_bounds__(256) void k_pair(
    const unsigned short* __restrict__ att_hi, const unsigned short* __restrict__ att_lo,
    const float* __restrict__ z,
    unsigned short* __restrict__ cc_hi, unsigned short* __restrict__ cc_lo)
{
    __shared__ unsigned short a_hi[16][56];
    __shared__ unsigned short a_lo[16][56];
    __shared__ unsigned short zt_sh[128][56];
    int iq = blockIdx.x;
    int tid = threadIdx.x;
    int lane = tid & 63, w = tid >> 6;
    int ncol = lane & 15, blk = lane >> 4, mrow = (lane >> 4) * 4;

    f32x4 acc[2] = {};
    for (int k0 = 0; k0 < 320; k0 += 32) {
        __syncthreads();
        if (tid < 64) {
            int row = tid >> 2, seg = tid & 3;
            size_t off = (size_t)row * 102400 + (size_t)iq * 320 + k0 + seg * 8;
            *(short8*)&a_hi[row][seg * 8] = *(const short8*)(att_hi + off);
            *(short8*)&a_lo[row][seg * 8] = *(const short8*)(att_lo + off);
        }
        {
            int kk = tid >> 3, cb = (tid & 7) * 16;
            const float* src = z + ((size_t)iq * 320 + k0 + kk) * 128 + cb;
            #pragma unroll
            for (int g4 = 0; g4 < 4; g4++) {
                float4 f = *(const float4*)(src + g4 * 4);
                zt_sh[cb + g4 * 4 + 0][kk] = f2b(f.x);
                zt_sh[cb + g4 * 4 + 1][kk] = f2b(f.y);
                zt_sh[cb + g4 * 4 + 2][kk] = f2b(f.z);
                zt_sh[cb + g4 * 4 + 3][kk] = f2b(f.w);
            }
        }
        __syncthreads();
        short8 afh = *(short8*)&a_hi[ncol][blk * 8];
        short8 afl = *(short8*)&a_lo[ncol][blk * 8];
        #pragma unroll
        for (int s2 = 0; s2 < 2; s2++) {
            short8 bf = *(short8*)&zt_sh[w * 32 + s2 * 16 + ncol][blk * 8];
            acc[s2] = __builtin_amdgcn_mfma_f32_16x16x32_bf16(afl, bf, acc[s2], 0, 0, 0);
            acc[s2] = __builtin_amdgcn_mfma_f32_16x16x32_bf16(afh, bf, acc[s2], 0, 0, 0);
        }
    }
    #pragma unroll
    for (int s2 = 0; s2 < 2; s2++) {
        int n = w * 32 + s2 * 16 + ncol;
        #pragma unroll
        for (int r = 0; r < 4; r++) {
            int h = mrow + r;
            if (h < 12) {
                float v = acc[s2][r];
                unsigned short hi = f2b(v);
                size_t idx = (size_t)iq * 2400 + 864 + h * 128 + n;
                cc_hi[idx] = hi;
                cc_lo[idx] = f2b(v - b2f(hi));
            }
        }
    }
}

// ---------------- kernel 8: partials = cc @ Wo via split MFMA (no atomics) --------
// grid (5 m-tiles of 64, 8 n-tiles of 48, 5 k-splits of 480), 256 thr.
__global__ __launch_bounds__(256) void k_gemm(
    const unsigned short* __restrict__ cc_hi, const unsigned short* __restrict__ cc_lo,
    const unsigned short* __restrict__ wo_hi, const unsigned short* __restrict__ wo_lo,
    float* __restrict__ part)
{
    __shared__ unsigned short a_hi[64][56];
    __shared__ unsigned short a_lo[64][56];
    __shared__ unsigned short w_hi[48][56];
    __shared__ unsigned short w_lo[48][56];
    int iq0 = blockIdx.x * 64, col0 = blockIdx.y * 48, ks = blockIdx.z;
    int tid = threadIdx.x;
    int lane = tid & 63, w = tid >> 6;
    int ncol = lane & 15, blk = lane >> 4, mrow = (lane >> 4) * 4;

    f32x4 acc[3] = {};
    for (int kc = 0; kc < 15; kc++) {
        int k0 = ks * 480 + kc * 32;
        __syncthreads();
        {
            int row = tid >> 2, seg = tid & 3;
            size_t off = (size_t)(iq0 + row) * 2400 + k0 + seg * 8;
            *(short8*)&a_hi[row][seg * 8] = *(const short8*)(cc_hi + off);
            *(short8*)&a_lo[row][seg * 8] = *(const short8*)(cc_lo + off);
        }
        if (tid < 96) {
            int kk = tid / 3, coff = (tid % 3) * 16;
            size_t off = (size_t)(k0 + kk) * 384 + col0 + coff;
            short8 h0 = *(const short8*)(wo_hi + off);
            short8 h1 = *(const short8*)(wo_hi + off + 8);
            short8 l0v = *(const short8*)(wo_lo + off);
            short8 l1v = *(const short8*)(wo_lo + off + 8);
            #pragma unroll
            for (int i = 0; i < 8; i++) {
                w_hi[coff + i][kk]     = (unsigned short)h0[i];
                w_hi[coff + 8 + i][kk] = (unsigned short)h1[i];
                w_lo[coff + i][kk]     = (unsigned short)l0v[i];
                w_lo[coff + 8 + i][kk] = (unsigned short)l1v[i];
            }
        }
        __syncthreads();
        short8 afh = *(short8*)&a_hi[w * 16 + ncol][blk * 8];
        short8 afl = *(short8*)&a_lo[w * 16 + ncol][blk * 8];
        #pragma unroll
        for (int s3 = 0; s3 < 3; s3++) {
            short8 bfh = *(short8*)&w_hi[s3 * 16 + ncol][blk * 8];
            short8 bfl = *(short8*)&w_lo[s3 * 16 + ncol][blk * 8];
            acc[s3] = __builtin_amdgcn_mfma_f32_16x16x32_bf16(afh, bfh, acc[s3], 0, 0, 0);
            acc[s3] = __builtin_amdgcn_mfma_f32_16x16x32_bf16(afh, bfl, acc[s3], 0, 0, 0);
            acc[s3] = __builtin_amdgcn_mfma_f32_16x16x32_bf16(afl, bfh, acc[s3], 0, 0, 0);
        }
    }
    #pragma unroll
    for (int s3 = 0; s3 < 3; s3++) {
        int cn = col0 + s3 * 16 + ncol;
        #pragma unroll
        for (int r = 0; r < 4; r++)
            part[((size_t)ks * 320 + iq0 + w * 16 + mrow + r) * 384 + cn] = acc[s3][r];
    }
}

// ---------------- kernel 9: out = bo + sum of 5 partials (deterministic) ----------
__global__ __launch_bounds__(256) void k_reduce(
    const float* __restrict__ part, const float* __restrict__ bo, float* __restrict__ out)
{
    int i = blockIdx.x * 256 + threadIdx.x;   // < 122880
    float v = bo[i % CS];
    #pragma unroll
    for (int ks = 0; ks < 5; ks++) v += part[(size_t)ks * 122880 + i];
    out[i] = v;
}

extern "C" void kernel_launch(void* const* d_in, const int* in_sizes, int n_in,
                              void* d_out, int out_size, void* d_ws, size_t ws_size,
                              hipStream_t stream)
{
    const float* s     = (const float*)d_in[0];
    const float* rot   = (const float*)d_in[1];
    const float* trans = (const float*)d_in[2];
    const float* z     = (const float*)d_in[3];
    const float* fm    = (const float*)d_in[4];
    const float* Wq    = (const float*)d_in[5];
    const float* bq    = (const float*)d_in[6];
    const float* Wkv   = (const float*)d_in[7];
    const float* bkv   = (const float*)d_in[8];
    const float* Wqp   = (const float*)d_in[9];
    const float* bqp   = (const float*)d_in[10];
    const float* Wkvp  = (const float*)d_in[11];
    const float* bkvp  = (const float*)d_in[12];
    const float* Wg    = (const float*)d_in[13];
    const float* bg    = (const float*)d_in[14];
    const float* gw    = (const float*)d_in[15];
    const float* dw    = (const float*)d_in[16];
    const float* hw    = (const float*)d_in[17];
    const float* Wo    = (const float*)d_in[18];
    const float* bo    = (const float*)d_in[19];

    float* ws = (float*)d_ws;
    float*          q       = ws + OFF_Q;
    float*          kv      = ws + OFF_KV;
    float*          qpt     = ws + OFF_QPT;
    float*          kpt     = ws + OFF_KPT;
    float*          knrm    = ws + OFF_KNRM;
    unsigned short* att_hi  = (unsigned short*)(ws + OFF_ATTHI);
    unsigned short* att_lo  = (unsigned short*)(ws + OFF_ATTLO);
    float*          ph_hi   = ws + OFF_ATTHI + 12 * 51200;
    float*          ph_lo   = ws + OFF_ATTLO + 12 * 51200;
    unsigned short* cc_hi   = (unsigned short*)(ws + OFF_CCHI);
    unsigned short* cc_lo   = (unsigned short*)(ws + OFF_CCLO);
    unsigned short* s_hi    = (unsigned short*)(ws + OFF_SHI);
    unsigned short* s_mid   = (unsigned short*)(ws + OFF_SMID);
    unsigned short* s_lo    = (unsigned short*)(ws + OFF_SLO);
    unsigned short* wc_hi   = (unsigned short*)(ws + OFF_WCATHI);
    unsigned short* wc_mid  = (unsigned short*)(ws + OFF_WCATMID);
    unsigned short* wc_lo   = (unsigned short*)(ws + OFF_WCATLO);
    float*          bcat    = ws + OFF_BCAT;
    unsigned short* wo_hi   = (unsigned short*)(ws + OFF_WOHI);
    unsigned short* wo_lo   = (unsigned short*)(ws + OFF_WOLO);
    unsigned short* vkv_hi  = (unsigned short*)(ws + OFF_VKVHI);
    unsigned short* vkv_lo  = (unsigned short*)(ws + OFF_VKVLO);
    float*          qpr     = ws + OFF_QPR;
    float*          kvpr    = ws + OFF_KVPR;
    float*          gate    = ws + OFF_GATE;
    float*          part    = ws + OFF_PART;
    float* out = (float*)d_out;

    k_cast<<<dim3(8352), dim3(256), 0, stream>>>(s, Wq, bq, Wkv, bkv, Wqp, bqp,
                                                 Wkvp, bkvp, Wg, bg, Wo,
                                                 s_hi, s_mid, s_lo, wc_hi, wc_mid, wc_lo,
                                                 bcat, wo_hi, wo_lo, ph_hi, ph_lo);
    k_proj<<<dim3(37, 5), dim3(256), 0, stream>>>(s_hi, s_mid, s_lo, wc_hi, wc_mid, wc_lo,
                                                  bcat, q, kv, qpr, kvpr, gate);
    k_points<<<dim3(LSEQ), dim3(256), 0, stream>>>(qpr, kvpr, gate, rot, trans, kv,
                                                   qpt, kpt, knrm, vkv_hi, vkv_lo);
    k_att<<<dim3(80, NH), dim3(256), 0, stream>>>(q, kv, qpt, kpt, knrm, fm, gw, dw, hw,
                                                  att_hi, att_lo);
    k_sv<<<dim3(20, NH), dim3(64), 0, stream>>>(att_hi, att_lo, vkv_hi, vkv_lo,
                                                rot, trans, cc_hi, cc_lo);
    k_pair<<<dim3(LSEQ), dim3(256), 0, stream>>>(att_hi, att_lo, z, cc_hi, cc_lo);
    k_gemm<<<dim3(5, 8, 5), dim3(256), 0, stream>>>(cc_hi, cc_lo, wo_hi, wo_lo, part);
    k_reduce<<<dim3(480), dim3(256), 0, stream>>>(part, bo, out);
}

// Round 9
// 232.370 us; speedup vs baseline: 1.0075x; 1.0075x over previous
//
#include <hip/hip_runtime.h>
#include <hip/hip_bf16.h>
#include <math.h>

#define LSEQ 320
#define CS 384
#define CZ 128
#define CH 16
#define NH 12
#define PQ 4
#define PV 8
#define EPSF 1e-8f

typedef short short8 __attribute__((ext_vector_type(8)));
typedef float f32x4 __attribute__((ext_vector_type(4)));

// float -> bf16 (RNE)
__device__ __forceinline__ unsigned short f2b(float x) {
    union { float f; unsigned u; } v; v.f = x;
    unsigned r = (v.u + 0x7FFF + ((v.u >> 16) & 1)) >> 16;
    return (unsigned short)r;
}
__device__ __forceinline__ float b2f(unsigned short h) {
    union { unsigned u; float f; } v; v.u = ((unsigned)h) << 16;
    return v.f;
}

// workspace float offsets (~25 MB total; ws >= 256MB per fillBuffer evidence)
#define OFF_Q       0         // fp32 [320][192]
#define OFF_KV      61440     // fp32 [320][384]
#define OFF_QPT     184320    // fp32 [320][48][6]
#define OFF_KPT     276480    // fp32 [320][48][6]
#define OFF_KNRM    368640    // fp32 [48][320]
#define OFF_ATTHI   552960    // bf16 [16][320][320] (planes 12-15 zeroed)
#define OFF_ATTLO   1372160   // bf16 [16][320][320]
#define OFF_CCHI    2191360   // bf16 [320][2400]
#define OFF_CCLO    2575360   // bf16 [320][2400]
#define OFF_SHI     2959360   // bf16 [320][384]
#define OFF_SMID    2990080
#define OFF_SLO     3020800
#define OFF_WCATHI  3051520   // bf16 [384][1776]
#define OFF_WCATMID 3392512
#define OFF_WCATLO  3733504
#define OFF_BCAT    4074496   // fp32 [1776]
#define OFF_WOHI    4076272   // bf16 [2400][384]
#define OFF_WOLO    4537072
#define OFF_VKVHI   4997872   // bf16 [12][64][320]
#define OFF_VKVLO   5120752
#define OFF_QPR     5243632   // fp32 [320][288]
#define OFF_KVPR    5335792   // fp32 [320][864]
#define OFF_GATE    5612272   // fp32 [320][48]
#define OFF_PART    5627632   // fp32 [5][320][384]

// ---------------- kernel 0: cast inputs (3-way s/wcat, 2-way wo), zero phantom ----
// items: s 122880 | wcat 681984 | bcat 1776 | wo 921600 | ph_hi 204800 | ph_lo 204800
//        -> 2137840 -> 8352 blocks
__global__ __launch_bounds__(256) void k_cast(
    const float* __restrict__ s,
    const float* __restrict__ Wq, const float* __restrict__ bq,
    const float* __restrict__ Wkv, const float* __restrict__ bkv,
    const float* __restrict__ Wqp, const float* __restrict__ bqp,
    const float* __restrict__ Wkvp, const float* __restrict__ bkvp,
    const float* __restrict__ Wg, const float* __restrict__ bg,
    const float* __restrict__ Wo,
    unsigned short* __restrict__ s_hi, unsigned short* __restrict__ s_mid,
    unsigned short* __restrict__ s_lo,
    unsigned short* __restrict__ w_hi, unsigned short* __restrict__ w_mid,
    unsigned short* __restrict__ w_lo,
    float* __restrict__ bcat,
    unsigned short* __restrict__ wo_hi, unsigned short* __restrict__ wo_lo,
    float* __restrict__ ph_hi, float* __restrict__ ph_lo)
{
    int i = blockIdx.x * 256 + threadIdx.x;
    if (i < 122880) {
        float x = s[i];
        unsigned short hi = f2b(x);
        float r1 = x - b2f(hi);
        unsigned short mid = f2b(r1);
        s_hi[i] = hi; s_mid[i] = mid; s_lo[i] = f2b(r1 - b2f(mid));
        return;
    }
    i -= 122880;
    if (i < 681984) {
        int k = i / 1776, c = i - k * 1776;
        float v;
        if (c < 192)       v = Wq[(size_t)k * 192 + c];
        else if (c < 576)  v = Wkv[(size_t)k * 384 + c - 192];
        else if (c < 864)  v = Wqp[(size_t)k * 288 + c - 576];
        else if (c < 1728) v = Wkvp[(size_t)k * 864 + c - 864];
        else               v = Wg[(size_t)k * 48 + c - 1728];
        unsigned short hi = f2b(v);
        float r1 = v - b2f(hi);
        unsigned short mid = f2b(r1);
        w_hi[i] = hi; w_mid[i] = mid; w_lo[i] = f2b(r1 - b2f(mid));
        return;
    }
    i -= 681984;
    if (i < 1776) {
        float v;
        if (i < 192)       v = bq[i];
        else if (i < 576)  v = bkv[i - 192];
        else if (i < 864)  v = bqp[i - 576];
        else if (i < 1728) v = bkvp[i - 864];
        else               v = bg[i - 1728];
        bcat[i] = v;
        return;
    }
    i -= 1776;
    if (i < 921600) {
        float v = Wo[i];
        unsigned short hi = f2b(v);
        wo_hi[i] = hi; wo_lo[i] = f2b(v - b2f(hi));
        return;
    }
    i -= 921600;
    if (i < 204800) { ph_hi[i] = 0.0f; return; }
    i -= 204800;
    if (i < 204800) ph_lo[i] = 0.0f;
}

// ---------------- kernel 1: projection GEMM, 3-way split MFMA (fp32-equivalent) ----
// grid (37 n-tiles of 48, 5 m-tiles of 64), 256 thr.
__global__ __launch_bounds__(256) void k_proj(
    const unsigned short* __restrict__ s_hi, const unsigned short* __restrict__ s_mid,
    const unsigned short* __restrict__ s_lo,
    const unsigned short* __restrict__ wc_hi, const unsigned short* __restrict__ wc_mid,
    const unsigned short* __restrict__ wc_lo,
    const float* __restrict__ bcat,
    float* __restrict__ qo, float* __restrict__ kvo,
    float* __restrict__ qpr, float* __restrict__ kvpr, float* __restrict__ gate)
{
    __shared__ unsigned short a_h[64][56], a_m[64][56], a_l[64][56];
    __shared__ unsigned short w_h[48][56], w_m[48][56], w_l[48][56];
    int col0 = blockIdx.x * 48, l0 = blockIdx.y * 64;
    int tid = threadIdx.x;
    int lane = tid & 63, w = tid >> 6;
    int ncol = lane & 15, blk = lane >> 4, mrow = (lane >> 4) * 4;

    float* dst; int nc, cbase; bool sig = false;
    if (col0 < 192)       { nc = 192; cbase = col0;        dst = qo;   }
    else if (col0 < 576)  { nc = 384; cbase = col0 - 192;  dst = kvo;  }
    else if (col0 < 864)  { nc = 288; cbase = col0 - 576;  dst = qpr;  }
    else if (col0 < 1728) { nc = 864; cbase = col0 - 864;  dst = kvpr; }
    else                  { nc = 48;  cbase = 0;           dst = gate; sig = true; }

    f32x4 acc[3] = {};
    for (int k0 = 0; k0 < 384; k0 += 32) {
        __syncthreads();
        {
            int row = tid >> 2, seg = tid & 3;
            size_t off = (size_t)(l0 + row) * 384 + k0 + seg * 8;
            *(short8*)&a_h[row][seg * 8] = *(const short8*)(s_hi + off);
            *(short8*)&a_m[row][seg * 8] = *(const short8*)(s_mid + off);
            *(short8*)&a_l[row][seg * 8] = *(const short8*)(s_lo + off);
        }
        if (tid < 96) {
            int kk = tid / 3, coff = (tid % 3) * 16;
            size_t off = (size_t)(k0 + kk) * 1776 + col0 + coff;
            short8 h0 = *(const short8*)(wc_hi + off);
            short8 h1 = *(const short8*)(wc_hi + off + 8);
            short8 m0 = *(const short8*)(wc_mid + off);
            short8 m1 = *(const short8*)(wc_mid + off + 8);
            short8 l0v = *(const short8*)(wc_lo + off);
            short8 l1v = *(const short8*)(wc_lo + off + 8);
            #pragma unroll
            for (int i = 0; i < 8; i++) {
                w_h[coff + i][kk]     = (unsigned short)h0[i];
                w_h[coff + 8 + i][kk] = (unsigned short)h1[i];
                w_m[coff + i][kk]     = (unsigned short)m0[i];
                w_m[coff + 8 + i][kk] = (unsigned short)m1[i];
                w_l[coff + i][kk]     = (unsigned short)l0v[i];
                w_l[coff + 8 + i][kk] = (unsigned short)l1v[i];
            }
        }
        __syncthreads();
        short8 afh = *(short8*)&a_h[w * 16 + ncol][blk * 8];
        short8 afm = *(short8*)&a_m[w * 16 + ncol][blk * 8];
        short8 afl = *(short8*)&a_l[w * 16 + ncol][blk * 8];
        #pragma unroll
        for (int s3 = 0; s3 < 3; s3++) {
            short8 bfh = *(short8*)&w_h[s3 * 16 + ncol][blk * 8];
            short8 bfm = *(short8*)&w_m[s3 * 16 + ncol][blk * 8];
            short8 bfl = *(short8*)&w_l[s3 * 16 + ncol][blk * 8];
            acc[s3] = __builtin_amdgcn_mfma_f32_16x16x32_bf16(afm, bfm, acc[s3], 0, 0, 0);
            acc[s3] = __builtin_amdgcn_mfma_f32_16x16x32_bf16(afh, bfl, acc[s3], 0, 0, 0);
            acc[s3] = __builtin_amdgcn_mfma_f32_16x16x32_bf16(afl, bfh, acc[s3], 0, 0, 0);
            acc[s3] = __builtin_amdgcn_mfma_f32_16x16x32_bf16(afh, bfm, acc[s3], 0, 0, 0);
            acc[s3] = __builtin_amdgcn_mfma_f32_16x16x32_bf16(afm, bfh, acc[s3], 0, 0, 0);
            acc[s3] = __builtin_amdgcn_mfma_f32_16x16x32_bf16(afh, bfh, acc[s3], 0, 0, 0);
        }
    }
    #pragma unroll
    for (int s3 = 0; s3 < 3; s3++) {
        float bv = bcat[col0 + s3 * 16 + ncol];
        int cloc = cbase + s3 * 16 + ncol;
        #pragma unroll
        for (int r = 0; r < 4; r++) {
            float v2 = acc[s3][r] + bv;
            if (sig) v2 = 1.0f / (1.0f + expf(-v2));
            dst[(size_t)(l0 + w * 16 + mrow + r) * nc + cloc] = v2;
        }
    }
}

// ---------------- kernel 2: frame transforms + vkvT hi/lo + k-dir norms ----------
__global__ __launch_bounds__(256) void k_points(
    const float* __restrict__ qpr, const float* __restrict__ kvpr, const float* __restrict__ gate,
    const float* __restrict__ rot, const float* __restrict__ trans,
    const float* __restrict__ kv,
    float* __restrict__ qpt, float* __restrict__ kpt, float* __restrict__ knrm,
    unsigned short* __restrict__ vkv_hi, unsigned short* __restrict__ vkv_lo)
{
    __shared__ float vsh[96][6];
    int l = blockIdx.x, t = threadIdx.x;
    const float* R = rot + l * 9;
    float tx = trans[l * 3], ty = trans[l * 3 + 1], tz = trans[l * 3 + 2];
    if (t < 192) {
        const float* src; float g = 1.0f; float* dst = nullptr; int vj = -1;
        if (t < 48)      { src = qpr + (size_t)l * 288 + t * 6; g = gate[l * 48 + t]; dst = qpt + ((size_t)l * 48 + t) * 6; }
        else if (t < 96) { int j = t - 48; src = kvpr + (size_t)l * 864 + j * 6; dst = kpt + ((size_t)l * 48 + j) * 6; }
        else             { int j = t - 96; src = kvpr + (size_t)l * 864 + 288 + j * 6; vj = j; }
        float px = src[0], py = src[1], pz = src[2], ux = src[3], uy = src[4], uz = src[5];
        float c0 = R[0] * px + R[1] * py + R[2] * pz + tx;
        float c1 = R[3] * px + R[4] * py + R[5] * pz + ty;
        float c2 = R[6] * px + R[7] * py + R[8] * pz + tz;
        float d0 = R[0] * ux + R[1] * uy + R[2] * uz;
        float d1 = R[3] * ux + R[4] * uy + R[5] * uz;
        float d2 = R[6] * ux + R[7] * uy + R[8] * uz;
        if (vj >= 0) {
            vsh[vj][0] = c0; vsh[vj][1] = c1; vsh[vj][2] = c2;
            vsh[vj][3] = d0; vsh[vj][4] = d1; vsh[vj][5] = d2;
        } else {
            dst[0] = c0 * g; dst[1] = c1 * g; dst[2] = c2 * g;
            dst[3] = d0 * g; dst[4] = d1 * g; dst[5] = d2 * g;
            if (t >= 48) {
                knrm[(size_t)(t - 48) * 320 + l] = sqrtf(d0 * d0 + d1 * d1 + d2 * d2);
            }
        }
    }
    __syncthreads();
    #pragma unroll
    for (int e = 0; e < 3; e++) {
        int u = t * 3 + e;   // < 768
        int h = u >> 6, n = u & 63;
        float val;
        if (n < 16) val = kv[(size_t)l * 384 + 192 + h * 16 + n];
        else        val = vsh[h * 8 + (n - 16) / 6][(n - 16) % 6];
        unsigned short hi = f2b(val);
        size_t idx = ((size_t)h * 64 + n) * 320 + l;
        vkv_hi[idx] = hi;
        vkv_lo[idx] = f2b(val - b2f(hi));
    }
}

// ---------------- kernel 3: attention logits + softmax -> att hi/lo ----------------
// grid (80, 12), 256 thr = 4 waves (one iq per wave, all share h).
// Two-phase k staging (192 + 128 rows) keeps LDS at 34.6 KB -> 4 blocks/CU.
// LDS row per k: [0..23] kpt slice | [24..39] kv head | [40..43] nk | [44] pad
__global__ __launch_bounds__(256) void k_att(
    const float* __restrict__ qb, const float* __restrict__ kvb,
    const float* __restrict__ qpt, const float* __restrict__ kpt,
    const float* __restrict__ knrm,
    const float* __restrict__ fm, const float* __restrict__ gw,
    const float* __restrict__ dwp, const float* __restrict__ hwp,
    unsigned short* __restrict__ att_hi, unsigned short* __restrict__ att_lo)
{
    __shared__ float kp_sh[192][45];
    int tid = threadIdx.x;
    int w = tid >> 6, lane = tid & 63;
    int iq = blockIdx.x * 4 + w;
    int h = blockIdx.y;

    float qv[CH];
    #pragma unroll
    for (int c = 0; c < CH; c++) qv[c] = qb[(size_t)iq * 192 + h * CH + c];
    float qp[24];
    #pragma unroll
    for (int j = 0; j < 24; j++) qp[j] = qpt[(size_t)iq * 288 + h * 24 + j];
    float nq[PQ], nq2[PQ];
    #pragma unroll
    for (int p = 0; p < PQ; p++) {
        float x = qp[p * 6 + 3], y = qp[p * 6 + 4], zz = qp[p * 6 + 5];
        nq2[p] = x * x + y * y + zz * zz;
        nq[p] = sqrtf(nq2[p]);
    }
    float dwv = dwp[0], g0 = gw[0], g1 = gw[1], hwv = hwp[h];
    float fmi = fm[iq];

    float lg[5];
    #pragma unroll
    for (int phase = 0; phase < 2; phase++) {
        int kbase = phase * 192;
        int krows = phase ? 128 : 192;
        __syncthreads();
        for (int idx = tid; idx < krows * 44; idx += 256) {
            int kk = idx / 44, j = idx - kk * 44;
            float v;
            if (j < 24)      v = kpt[(size_t)(kbase + kk) * 288 + h * 24 + j];
            else if (j < 40) v = kvb[(size_t)(kbase + kk) * 384 + h * 16 + (j - 24)];
            else             v = knrm[(size_t)(h * 4 + (j - 40)) * 320 + kbase + kk];
            kp_sh[kk][j] = v;
        }
        __syncthreads();
        int r0 = phase ? 3 : 0, r1 = phase ? 5 : 3;
        for (int r = r0; r < r1; r++) {
            int kk = r * 64 + lane;
            const float* row = &kp_sh[kk - kbase][0];

            float scalar = 0.f;
            #pragma unroll
            for (int c = 0; c < CH; c++) scalar += qv[c] * row[24 + c];
            scalar *= 0.25f;

            float pos = 0.f;
            #pragma unroll
            for (int p = 0; p < PQ; p++) {
                float dx = qp[p * 6] - row[p * 6];
                float dy = qp[p * 6 + 1] - row[p * 6 + 1];
                float dz = qp[p * 6 + 2] - row[p * 6 + 2];
                float d = __builtin_amdgcn_sqrtf(dx * dx + dy * dy + dz * dz);
                float de = d + EPSF;
                pos += d + __logf(de) + __builtin_amdgcn_rcpf(de);
            }
            pos *= 0.25f;

            float dir = 0.f;
            #pragma unroll
            for (int p = 0; p < PQ; p++) {
                float kx = row[p * 6 + 3], ky = row[p * 6 + 4], kz = row[p * 6 + 5];
                float nk = row[40 + p];
                float nk2 = nk * nk;
                float cm = 0.f, dself = 0.f;
                #pragma unroll
                for (int pq = 0; pq < PQ; pq++) {
                    float dq = qp[pq * 6 + 3] * kx + qp[pq * 6 + 4] * ky + qp[pq * 6 + 5] * kz;
                    if (pq == p) dself = dq;
                    cm += __builtin_amdgcn_sqrtf(fmaxf(nq2[pq] * nk2 - dq * dq, 0.0f));
                }
                cm *= 0.25f;
                dir += dself - cm * __builtin_amdgcn_rcpf(nq[p] * nk + EPSF);
            }
            dir *= 0.25f;

            float logit = scalar + dwv * (g0 * pos + g1 * dir);
            logit *= hwv;
            logit += 100000.0f * (fmi * fm[kk] - 1.0f);
            lg[r] = logit;
        }
    }

    float mx = lg[0];
    #pragma unroll
    for (int r = 1; r < 5; r++) mx = fmaxf(mx, lg[r]);
    for (int m = 32; m; m >>= 1) mx = fmaxf(mx, __shfl_xor(mx, m, 64));

    float e[5], sm = 0.f;
    #pragma unroll
    for (int r = 0; r < 5; r++) { e[r] = __expf(lg[r] - mx); sm += e[r]; }
    for (int m = 32; m; m >>= 1) sm += __shfl_xor(sm, m, 64);
    float inv = 1.0f / sm;
    #pragma unroll
    for (int r = 0; r < 5; r++) {
        float p = e[r] * inv;
        unsigned short hi = f2b(p);
        size_t idx = ((size_t)h * 320 + iq) * 320 + r * 64 + lane;
        att_hi[idx] = hi;
        att_lo[idx] = f2b(p - b2f(hi));
    }
}

// ---------------- kernel 5: o_scalar + o_geom via split MFMA + fused finish ------
// per (iq-tile of 16, h): [16 x 320] @ [320 x 64]. grid (20,12), 64 thr.
__global__ __launch_bounds__(64) void k_sv(
    const unsigned short* __restrict__ att_hi, const unsigned short* __restrict__ att_lo,
    const unsigned short* __restrict__ vkv_hi, const unsigned short* __restrict__ vkv_lo,
    const float* __restrict__ rot, const float* __restrict__ trans,
    unsigned short* __restrict__ cc_hi, unsigned short* __restrict__ cc_lo)
{
    __shared__ unsigned short a_hi[16][56];
    __shared__ unsigned short a_lo[16][56];
    __shared__ unsigned short bt_hi[64][56];
    __shared__ unsigned short bt_lo[64][56];
    __shared__ float ogsh[16][49];
    int iq0 = blockIdx.x * 16, h = blockIdx.y;
    int tid = threadIdx.x;
    int ncol = tid & 15, blk = tid >> 4, mrow = (tid >> 4) * 4;

    f32x4 acc[4] = {};
    for (int k0 = 0; k0 < 320; k0 += 32) {
        __syncthreads();
        {
            int row = tid >> 2, seg = tid & 3;
            size_t off = ((size_t)h * 320 + iq0 + row) * 320 + k0 + seg * 8;
            *(short8*)&a_hi[row][seg * 8] = *(const short8*)(att_hi + off);
            *(short8*)&a_lo[row][seg * 8] = *(const short8*)(att_lo + off);
        }
        {
            size_t off = ((size_t)h * 64 + tid) * 320 + k0;
            #pragma unroll
            for (int j2 = 0; j2 < 4; j2++) {
                *(short8*)&bt_hi[tid][j2 * 8] = *(const short8*)(vkv_hi + off + j2 * 8);
                *(short8*)&bt_lo[tid][j2 * 8] = *(const short8*)(vkv_lo + off + j2 * 8);
            }
        }
        __syncthreads();
        short8 afh = *(short8*)&a_hi[ncol][blk * 8];
        short8 afl = *(short8*)&a_lo[ncol][blk * 8];
        #pragma unroll
        for (int s4 = 0; s4 < 4; s4++) {
            short8 bfh = *(short8*)&bt_hi[s4 * 16 + ncol][blk * 8];
            short8 bfl = *(short8*)&bt_lo[s4 * 16 + ncol][blk * 8];
            acc[s4] = __builtin_amdgcn_mfma_f32_16x16x32_bf16(afh, bfh, acc[s4], 0, 0, 0);
            acc[s4] = __builtin_amdgcn_mfma_f32_16x16x32_bf16(afh, bfl, acc[s4], 0, 0, 0);
            acc[s4] = __builtin_amdgcn_mfma_f32_16x16x32_bf16(afl, bfh, acc[s4], 0, 0, 0);
        }
    }
    #pragma unroll
    for (int s4 = 0; s4 < 4; s4++) {
        int n = s4 * 16 + ncol;
        #pragma unroll
        for (int r = 0; r < 4; r++) {
            int iq = iq0 + mrow + r;
            float v = acc[s4][r];
            if (n < 16) {
                unsigned short hi = f2b(v);
                size_t idx = (size_t)iq * 2400 + h * 16 + n;
                cc_hi[idx] = hi;
                cc_lo[idx] = f2b(v - b2f(hi));
            } else {
                ogsh[mrow + r][n - 16] = v;
            }
        }
    }
    __syncthreads();
    #pragma unroll
    for (int t2 = tid; t2 < 128; t2 += 64) {
        int iqr = t2 >> 3, p = t2 & 7;
        int l = iq0 + iqr;
        const float* R = rot + l * 9;
        float tx = trans[l * 3], ty = trans[l * 3 + 1], tz = trans[l * 3 + 2];
        const float* o = &ogsh[iqr][p * 6];
        float gx = o[0] - tx, gy = o[1] - ty, gz = o[2] - tz;
        float l0 = R[0] * gx + R[3] * gy + R[6] * gz;
        float l1 = R[1] * gx + R[4] * gy + R[7] * gz;
        float l2 = R[2] * gx + R[5] * gy + R[8] * gz;
        float dx = o[3], dy = o[4], dz = o[5];
        float e0 = R[0] * dx + R[3] * dy + R[6] * dz;
        float e1 = R[1] * dx + R[4] * dy + R[7] * dz;
        float e2 = R[2] * dx + R[5] * dy + R[8] * dz;
        float n = sqrtf(e0 * e0 + e1 * e1 + e2 * e2);
        float inv = 1.0f / fmaxf(n, 1e-12f);
        float ln = sqrtf(l0 * l0 + l1 * l1 + l2 * l2);
        float vals[7] = { l0, l1, l2, e0 * inv, e1 * inv, e2 * inv, ln };
        size_t base = (size_t)l * 2400 + 192 + (h * PV + p) * 7;
        #pragma unroll
        for (int j = 0; j < 7; j++) {
            unsigned short hi = f2b(vals[j]);
            cc_hi[base + j] = hi;
            cc_lo[base + j] = f2b(vals[j] - b2f(hi));
        }
    }
}

// ---------------- kernel 6: o_pair via MFMA (att hi+lo, z plain bf16) -------------
// per iq: [16(h) x 320] @ [320 x 128]. grid (320), 256 thr.
__global__ __launch_bounds__(256) void k_pair(
    const unsigned short* __restrict__ att_hi, const unsigned short* __restrict__ att_lo,
    const float* __restrict__ z,
    unsigned short* __restrict__ cc_hi, unsigned short* __restrict__ cc_lo)
{
    __shared__ unsigned short a_hi[16][56];
    __shared__ unsigned short a_lo[16][56];
    __shared__ unsigned short zt_sh[128][56];
    int iq = blockIdx.x;
    int tid = threadIdx.x;
    int lane = tid & 63, w = tid >> 6;
    int ncol = lane & 15, blk = lane >> 4, mrow = (lane >> 4) * 4;

    f32x4 acc[2] = {};
    for (int k0 = 0; k0 < 320; k0 += 32) {
        __syncthreads();
        if (tid < 64) {
            int row = tid >> 2, seg = tid & 3;
            size_t off = (size_t)row * 102400 + (size_t)iq * 320 + k0 + seg * 8;
            *(short8*)&a_hi[row][seg * 8] = *(const short8*)(att_hi + off);
            *(short8*)&a_lo[row][seg * 8] = *(const short8*)(att_lo + off);
        }
        {
            int kk = tid >> 3, cb = (tid & 7) * 16;
            const float* src = z + ((size_t)iq * 320 + k0 + kk) * 128 + cb;
            #pragma unroll
            for (int g4 = 0; g4 < 4; g4++) {
                float4 f = *(const float4*)(src + g4 * 4);
                zt_sh[cb + g4 * 4 + 0][kk] = f2b(f.x);
                zt_sh[cb + g4 * 4 + 1][kk] = f2b(f.y);
                zt_sh[cb + g4 * 4 + 2][kk] = f2b(f.z);
                zt_sh[cb + g4 * 4 + 3][kk] = f2b(f.w);
            }
        }
        __syncthreads();
        short8 afh = *(short8*)&a_hi[ncol][blk * 8];
        short8 afl = *(short8*)&a_lo[ncol][blk * 8];
        #pragma unroll
        for (int s2 = 0; s2 < 2; s2++) {
            short8 bf = *(short8*)&zt_sh[w * 32 + s2 * 16 + ncol][blk * 8];
            acc[s2] = __builtin_amdgcn_mfma_f32_16x16x32_bf16(afl, bf, acc[s2], 0, 0, 0);
            acc[s2] = __builtin_amdgcn_mfma_f32_16x16x32_bf16(afh, bf, acc[s2], 0, 0, 0);
        }
    }
    #pragma unroll
    for (int s2 = 0; s2 < 2; s2++) {
        int n = w * 32 + s2 * 16 + ncol;
        #pragma unroll
        for (int r = 0; r < 4; r++) {
            int h = mrow + r;
            if (h < 12) {
                float v = acc[s2][r];
                unsigned short hi = f2b(v);
                size_t idx = (size_t)iq * 2400 + 864 + h * 128 + n;
                cc_hi[idx] = hi;
                cc_lo[idx] = f2b(v - b2f(hi));
            }
        }
    }
}

// ---------------- kernel 8: partials = cc @ Wo via split MFMA (no atomics) --------
// grid (5 m-tiles of 64, 8 n-tiles of 48, 5 k-splits of 480), 256 thr.
__global__ __launch_bounds__(256) void k_gemm(
    const unsigned short* __restrict__ cc_hi, const unsigned short* __restrict__ cc_lo,
    const unsigned short* __restrict__ wo_hi, const unsigned short* __restrict__ wo_lo,
    float* __restrict__ part)
{
    __shared__ unsigned short a_hi[64][56];
    __shared__ unsigned short a_lo[64][56];
    __shared__ unsigned short w_hi[48][56];
    __shared__ unsigned short w_lo[48][56];
    int iq0 = blockIdx.x * 64, col0 = blockIdx.y * 48, ks = blockIdx.z;
    int tid = threadIdx.x;
    int lane = tid & 63, w = tid >> 6;
    int ncol = lane & 15, blk = lane >> 4, mrow = (lane >> 4) * 4;

    f32x4 acc[3] = {};
    for (int kc = 0; kc < 15; kc++) {
        int k0 = ks * 480 + kc * 32;
        __syncthreads();
        {
            int row = tid >> 2, seg = tid & 3;
            size_t off = (size_t)(iq0 + row) * 2400 + k0 + seg * 8;
            *(short8*)&a_hi[row][seg * 8] = *(const short8*)(cc_hi + off);
            *(short8*)&a_lo[row][seg * 8] = *(const short8*)(cc_lo + off);
        }
        if (tid < 96) {
            int kk = tid / 3, coff = (tid % 3) * 16;
            size_t off = (size_t)(k0 + kk) * 384 + col0 + coff;
            short8 h0 = *(const short8*)(wo_hi + off);
            short8 h1 = *(const short8*)(wo_hi + off + 8);
            short8 l0v = *(const short8*)(wo_lo + off);
            short8 l1v = *(const short8*)(wo_lo + off + 8);
            #pragma unroll
            for (int i = 0; i < 8; i++) {
                w_hi[coff + i][kk]     = (unsigned short)h0[i];
                w_hi[coff + 8 + i][kk] = (unsigned short)h1[i];
                w_lo[coff + i][kk]     = (unsigned short)l0v[i];
                w_lo[coff + 8 + i][kk] = (unsigned short)l1v[i];
            }
        }
        __syncthreads();
        short8 afh = *(short8*)&a_hi[w * 16 + ncol][blk * 8];
        short8 afl = *(short8*)&a_lo[w * 16 + ncol][blk * 8];
        #pragma unroll
        for (int s3 = 0; s3 < 3; s3++) {
            short8 bfh = *(short8*)&w_hi[s3 * 16 + ncol][blk * 8];
            short8 bfl = *(short8*)&w_lo[s3 * 16 + ncol][blk * 8];
            acc[s3] = __builtin_amdgcn_mfma_f32_16x16x32_bf16(afh, bfh, acc[s3], 0, 0, 0);
            acc[s3] = __builtin_amdgcn_mfma_f32_16x16x32_bf16(afh, bfl, acc[s3], 0, 0, 0);
            acc[s3] = __builtin_amdgcn_mfma_f32_16x16x32_bf16(afl, bfh, acc[s3], 0, 0, 0);
        }
    }
    #pragma unroll
    for (int s3 = 0; s3 < 3; s3++) {
        int cn = col0 + s3 * 16 + ncol;
        #pragma unroll
        for (int r = 0; r < 4; r++)
            part[((size_t)ks * 320 + iq0 + w * 16 + mrow + r) * 384 + cn] = acc[s3][r];
    }
}

// ---------------- kernel 9: out = bo + sum of 5 partials (deterministic) ----------
__global__ __launch_bounds__(256) void k_reduce(
    const float* __restrict__ part, const float* __restrict__ bo, float* __restrict__ out)
{
    int i = blockIdx.x * 256 + threadIdx.x;   // < 122880
    float v = bo[i % CS];
    #pragma unroll
    for (int ks = 0; ks < 5; ks++) v += part[(size_t)ks * 122880 + i];
    out[i] = v;
}

extern "C" void kernel_launch(void* const* d_in, const int* in_sizes, int n_in,
                              void* d_out, int out_size, void* d_ws, size_t ws_size,
                              hipStream_t stream)
{
    const float* s     = (const float*)d_in[0];
    const float* rot   = (const float*)d_in[1];
    const float* trans = (const float*)d_in[2];
    const float* z     = (const float*)d_in[3];
    const float* fm    = (const float*)d_in[4];
    const float* Wq    = (const float*)d_in[5];
    const float* bq    = (const float*)d_in[6];
    const float* Wkv   = (const float*)d_in[7];
    const float* bkv   = (const float*)d_in[8];
    const float* Wqp   = (const float*)d_in[9];
    const float* bqp   = (const float*)d_in[10];
    const float* Wkvp  = (const float*)d_in[11];
    const float* bkvp  = (const float*)d_in[12];
    const float* Wg    = (const float*)d_in[13];
    const float* bg    = (const float*)d_in[14];
    const float* gw    = (const float*)d_in[15];
    const float* dw    = (const float*)d_in[16];
    const float* hw    = (const float*)d_in[17];
    const float* Wo    = (const float*)d_in[18];
    const float* bo    = (const float*)d_in[19];

    float* ws = (float*)d_ws;
    float*          q       = ws + OFF_Q;
    float*          kv      = ws + OFF_KV;
    float*          qpt     = ws + OFF_QPT;
    float*          kpt     = ws + OFF_KPT;
    float*          knrm    = ws + OFF_KNRM;
    unsigned short* att_hi  = (unsigned short*)(ws + OFF_ATTHI);
    unsigned short* att_lo  = (unsigned short*)(ws + OFF_ATTLO);
    float*          ph_hi   = ws + OFF_ATTHI + 12 * 51200;
    float*          ph_lo   = ws + OFF_ATTLO + 12 * 51200;
    unsigned short* cc_hi   = (unsigned short*)(ws + OFF_CCHI);
    unsigned short* cc_lo   = (unsigned short*)(ws + OFF_CCLO);
    unsigned short* s_hi    = (unsigned short*)(ws + OFF_SHI);
    unsigned short* s_mid   = (unsigned short*)(ws + OFF_SMID);
    unsigned short* s_lo    = (unsigned short*)(ws + OFF_SLO);
    unsigned short* wc_hi   = (unsigned short*)(ws + OFF_WCATHI);
    unsigned short* wc_mid  = (unsigned short*)(ws + OFF_WCATMID);
    unsigned short* wc_lo   = (unsigned short*)(ws + OFF_WCATLO);
    float*          bcat    = ws + OFF_BCAT;
    unsigned short* wo_hi   = (unsigned short*)(ws + OFF_WOHI);
    unsigned short* wo_lo   = (unsigned short*)(ws + OFF_WOLO);
    unsigned short* vkv_hi  = (unsigned short*)(ws + OFF_VKVHI);
    unsigned short* vkv_lo  = (unsigned short*)(ws + OFF_VKVLO);
    float*          qpr     = ws + OFF_QPR;
    float*          kvpr    = ws + OFF_KVPR;
    float*          gate    = ws + OFF_GATE;
    float*          part    = ws + OFF_PART;
    float* out = (float*)d_out;

    k_cast<<<dim3(8352), dim3(256), 0, stream>>>(s, Wq, bq, Wkv, bkv, Wqp, bqp,
                                                 Wkvp, bkvp, Wg, bg, Wo,
                                                 s_hi, s_mid, s_lo, wc_hi, wc_mid, wc_lo,
                                                 bcat, wo_hi, wo_lo, ph_hi, ph_lo);
    k_proj<<<dim3(37, 5), dim3(256), 0, stream>>>(s_hi, s_mid, s_lo, wc_hi, wc_mid, wc_lo,
                                                  bcat, q, kv, qpr, kvpr, gate);
    k_points<<<dim3(LSEQ), dim3(256), 0, stream>>>(qpr, kvpr, gate, rot, trans, kv,
                                                   qpt, kpt, knrm, vkv_hi, vkv_lo);
    k_att<<<dim3(80, NH), dim3(256), 0, stream>>>(q, kv, qpt, kpt, knrm, fm, gw, dw, hw,
                                                  att_hi, att_lo);
    k_sv<<<dim3(20, NH), dim3(64), 0, stream>>>(att_hi, att_lo, vkv_hi, vkv_lo,
                                                rot, trans, cc_hi, cc_lo);
    k_pair<<<dim3(LSEQ), dim3(256), 0, stream>>>(att_hi, att_lo, z, cc_hi, cc_lo);
    k_gemm<<<dim3(5, 8, 5), dim3(256), 0, stream>>>(cc_hi, cc_lo, wo_hi, wo_lo, part);
    k_reduce<<<dim3(480), dim3(256), 0, stream>>>(part, bo, out);
}

// Round 10
// 219.227 us; speedup vs baseline: 1.0679x; 1.0600x over previous
//
#include <hip/hip_runtime.h>
#include <hip/hip_bf16.h>
#include <math.h>

#define LSEQ 320
#define CS 384
#define CZ 128
#define CH 16
#define NH 12
#define PQ 4
#define PV 8
#define EPSF 1e-8f

typedef short short8 __attribute__((ext_vector_type(8)));
typedef float f32x4 __attribute__((ext_vector_type(4)));

// float -> bf16 (RNE)
__device__ __forceinline__ unsigned short f2b(float x) {
    union { float f; unsigned u; } v; v.f = x;
    unsigned r = (v.u + 0x7FFF + ((v.u >> 16) & 1)) >> 16;
    return (unsigned short)r;
}
__device__ __forceinline__ float b2f(unsigned short h) {
    union { unsigned u; float f; } v; v.u = ((unsigned)h) << 16;
    return v.f;
}

// workspace float offsets (~26 MB total; ws >= 256MB per fillBuffer evidence)
#define OFF_Q       0         // fp32 [320][192]
#define OFF_KV      61440     // fp32 [320][384]
#define OFF_QPT     184320    // fp32 [320][48][6]
#define OFF_ATTHI   552960    // bf16 [16][320][320] (planes 12-15 zeroed)
#define OFF_ATTLO   1372160   // bf16 [16][320][320]
#define OFF_CCHI    2191360   // bf16 [320][2400]
#define OFF_CCLO    2575360   // bf16 [320][2400]
#define OFF_SHI     2959360   // bf16 [320][384]
#define OFF_SMID    2990080
#define OFF_SLO     3020800
#define OFF_WCATHI  3051520   // bf16 [384][1776]
#define OFF_WCATMID 3392512
#define OFF_WCATLO  3733504
#define OFF_BCAT    4074496   // fp32 [1776]
#define OFF_WOHI    4076272   // bf16 [2400][384]
#define OFF_WOLO    4537072
#define OFF_VKVHI   4997872   // bf16 [12][64][320]
#define OFF_VKVLO   5120752
#define OFF_QPR     5243632   // fp32 [320][288]
#define OFF_KVPR    5335792   // fp32 [320][864]
#define OFF_GATE    5612272   // fp32 [320][48]
#define OFF_PART    5627632   // fp32 [5][320][384]
#define OFF_KROW    6242032   // fp32 [12][320][48]  (kpt slice | k-head | nk | pad)

// ---------------- kernel 0: cast inputs (3-way s/wcat, 2-way wo), zero phantom ----
// items: s 122880 | wcat 681984 | bcat 1776 | wo 921600 | ph_hi 204800 | ph_lo 204800
//        -> 2137840 -> 8352 blocks
__global__ __launch_bounds__(256) void k_cast(
    const float* __restrict__ s,
    const float* __restrict__ Wq, const float* __restrict__ bq,
    const float* __restrict__ Wkv, const float* __restrict__ bkv,
    const float* __restrict__ Wqp, const float* __restrict__ bqp,
    const float* __restrict__ Wkvp, const float* __restrict__ bkvp,
    const float* __restrict__ Wg, const float* __restrict__ bg,
    const float* __restrict__ Wo,
    unsigned short* __restrict__ s_hi, unsigned short* __restrict__ s_mid,
    unsigned short* __restrict__ s_lo,
    unsigned short* __restrict__ w_hi, unsigned short* __restrict__ w_mid,
    unsigned short* __restrict__ w_lo,
    float* __restrict__ bcat,
    unsigned short* __restrict__ wo_hi, unsigned short* __restrict__ wo_lo,
    float* __restrict__ ph_hi, float* __restrict__ ph_lo)
{
    int i = blockIdx.x * 256 + threadIdx.x;
    if (i < 122880) {
        float x = s[i];
        unsigned short hi = f2b(x);
        float r1 = x - b2f(hi);
        unsigned short mid = f2b(r1);
        s_hi[i] = hi; s_mid[i] = mid; s_lo[i] = f2b(r1 - b2f(mid));
        return;
    }
    i -= 122880;
    if (i < 681984) {
        int k = i / 1776, c = i - k * 1776;
        float v;
        if (c < 192)       v = Wq[(size_t)k * 192 + c];
        else if (c < 576)  v = Wkv[(size_t)k * 384 + c - 192];
        else if (c < 864)  v = Wqp[(size_t)k * 288 + c - 576];
        else if (c < 1728) v = Wkvp[(size_t)k * 864 + c - 864];
        else               v = Wg[(size_t)k * 48 + c - 1728];
        unsigned short hi = f2b(v);
        float r1 = v - b2f(hi);
        unsigned short mid = f2b(r1);
        w_hi[i] = hi; w_mid[i] = mid; w_lo[i] = f2b(r1 - b2f(mid));
        return;
    }
    i -= 681984;
    if (i < 1776) {
        float v;
        if (i < 192)       v = bq[i];
        else if (i < 576)  v = bkv[i - 192];
        else if (i < 864)  v = bqp[i - 576];
        else if (i < 1728) v = bkvp[i - 864];
        else               v = bg[i - 1728];
        bcat[i] = v;
        return;
    }
    i -= 1776;
    if (i < 921600) {
        float v = Wo[i];
        unsigned short hi = f2b(v);
        wo_hi[i] = hi; wo_lo[i] = f2b(v - b2f(hi));
        return;
    }
    i -= 921600;
    if (i < 204800) { ph_hi[i] = 0.0f; return; }
    i -= 204800;
    if (i < 204800) ph_lo[i] = 0.0f;
}

// ---------------- kernel 1: projection GEMM, 3-way split MFMA (fp32-equivalent) ----
// grid (37 n-tiles of 48, 5 m-tiles of 64), 256 thr.
__global__ __launch_bounds__(256) void k_proj(
    const unsigned short* __restrict__ s_hi, const unsigned short* __restrict__ s_mid,
    const unsigned short* __restrict__ s_lo,
    const unsigned short* __restrict__ wc_hi, const unsigned short* __restrict__ wc_mid,
    const unsigned short* __restrict__ wc_lo,
    const float* __restrict__ bcat,
    float* __restrict__ qo, float* __restrict__ kvo,
    float* __restrict__ qpr, float* __restrict__ kvpr, float* __restrict__ gate)
{
    __shared__ unsigned short a_h[64][56], a_m[64][56], a_l[64][56];
    __shared__ unsigned short w_h[48][56], w_m[48][56], w_l[48][56];
    int col0 = blockIdx.x * 48, l0 = blockIdx.y * 64;
    int tid = threadIdx.x;
    int lane = tid & 63, w = tid >> 6;
    int ncol = lane & 15, blk = lane >> 4, mrow = (lane >> 4) * 4;

    float* dst; int nc, cbase; bool sig = false;
    if (col0 < 192)       { nc = 192; cbase = col0;        dst = qo;   }
    else if (col0 < 576)  { nc = 384; cbase = col0 - 192;  dst = kvo;  }
    else if (col0 < 864)  { nc = 288; cbase = col0 - 576;  dst = qpr;  }
    else if (col0 < 1728) { nc = 864; cbase = col0 - 864;  dst = kvpr; }
    else                  { nc = 48;  cbase = 0;           dst = gate; sig = true; }

    f32x4 acc[3] = {};
    for (int k0 = 0; k0 < 384; k0 += 32) {
        __syncthreads();
        {
            int row = tid >> 2, seg = tid & 3;
            size_t off = (size_t)(l0 + row) * 384 + k0 + seg * 8;
            *(short8*)&a_h[row][seg * 8] = *(const short8*)(s_hi + off);
            *(short8*)&a_m[row][seg * 8] = *(const short8*)(s_mid + off);
            *(short8*)&a_l[row][seg * 8] = *(const short8*)(s_lo + off);
        }
        if (tid < 96) {
            int kk = tid / 3, coff = (tid % 3) * 16;
            size_t off = (size_t)(k0 + kk) * 1776 + col0 + coff;
            short8 h0 = *(const short8*)(wc_hi + off);
            short8 h1 = *(const short8*)(wc_hi + off + 8);
            short8 m0 = *(const short8*)(wc_mid + off);
            short8 m1 = *(const short8*)(wc_mid + off + 8);
            short8 l0v = *(const short8*)(wc_lo + off);
            short8 l1v = *(const short8*)(wc_lo + off + 8);
            #pragma unroll
            for (int i = 0; i < 8; i++) {
                w_h[coff + i][kk]     = (unsigned short)h0[i];
                w_h[coff + 8 + i][kk] = (unsigned short)h1[i];
                w_m[coff + i][kk]     = (unsigned short)m0[i];
                w_m[coff + 8 + i][kk] = (unsigned short)m1[i];
                w_l[coff + i][kk]     = (unsigned short)l0v[i];
                w_l[coff + 8 + i][kk] = (unsigned short)l1v[i];
            }
        }
        __syncthreads();
        short8 afh = *(short8*)&a_h[w * 16 + ncol][blk * 8];
        short8 afm = *(short8*)&a_m[w * 16 + ncol][blk * 8];
        short8 afl = *(short8*)&a_l[w * 16 + ncol][blk * 8];
        #pragma unroll
        for (int s3 = 0; s3 < 3; s3++) {
            short8 bfh = *(short8*)&w_h[s3 * 16 + ncol][blk * 8];
            short8 bfm = *(short8*)&w_m[s3 * 16 + ncol][blk * 8];
            short8 bfl = *(short8*)&w_l[s3 * 16 + ncol][blk * 8];
            acc[s3] = __builtin_amdgcn_mfma_f32_16x16x32_bf16(afm, bfm, acc[s3], 0, 0, 0);
            acc[s3] = __builtin_amdgcn_mfma_f32_16x16x32_bf16(afh, bfl, acc[s3], 0, 0, 0);
            acc[s3] = __builtin_amdgcn_mfma_f32_16x16x32_bf16(afl, bfh, acc[s3], 0, 0, 0);
            acc[s3] = __builtin_amdgcn_mfma_f32_16x16x32_bf16(afh, bfm, acc[s3], 0, 0, 0);
            acc[s3] = __builtin_amdgcn_mfma_f32_16x16x32_bf16(afm, bfh, acc[s3], 0, 0, 0);
            acc[s3] = __builtin_amdgcn_mfma_f32_16x16x32_bf16(afh, bfh, acc[s3], 0, 0, 0);
        }
    }
    #pragma unroll
    for (int s3 = 0; s3 < 3; s3++) {
        float bv = bcat[col0 + s3 * 16 + ncol];
        int cloc = cbase + s3 * 16 + ncol;
        #pragma unroll
        for (int r = 0; r < 4; r++) {
            float v2 = acc[s3][r] + bv;
            if (sig) v2 = 1.0f / (1.0f + expf(-v2));
            dst[(size_t)(l0 + w * 16 + mrow + r) * nc + cloc] = v2;
        }
    }
}

// ---------------- kernel 2: frame transforms + vkvT hi/lo + krow table ----------
__global__ __launch_bounds__(256) void k_points(
    const float* __restrict__ qpr, const float* __restrict__ kvpr, const float* __restrict__ gate,
    const float* __restrict__ rot, const float* __restrict__ trans,
    const float* __restrict__ kv,
    float* __restrict__ qpt, float* __restrict__ krow,
    unsigned short* __restrict__ vkv_hi, unsigned short* __restrict__ vkv_lo)
{
    __shared__ float vsh[96][6];
    __shared__ float kp_s[48][6];
    __shared__ float kn_s[48];
    int l = blockIdx.x, t = threadIdx.x;
    const float* R = rot + l * 9;
    float tx = trans[l * 3], ty = trans[l * 3 + 1], tz = trans[l * 3 + 2];
    if (t < 192) {
        const float* src; float g = 1.0f; float* dst = nullptr; int vj = -1, kj = -1;
        if (t < 48)      { src = qpr + (size_t)l * 288 + t * 6; g = gate[l * 48 + t]; dst = qpt + ((size_t)l * 48 + t) * 6; }
        else if (t < 96) { kj = t - 48; src = kvpr + (size_t)l * 864 + kj * 6; }
        else             { int j = t - 96; src = kvpr + (size_t)l * 864 + 288 + j * 6; vj = j; }
        float px = src[0], py = src[1], pz = src[2], ux = src[3], uy = src[4], uz = src[5];
        float c0 = R[0] * px + R[1] * py + R[2] * pz + tx;
        float c1 = R[3] * px + R[4] * py + R[5] * pz + ty;
        float c2 = R[6] * px + R[7] * py + R[8] * pz + tz;
        float d0 = R[0] * ux + R[1] * uy + R[2] * uz;
        float d1 = R[3] * ux + R[4] * uy + R[5] * uz;
        float d2 = R[6] * ux + R[7] * uy + R[8] * uz;
        if (vj >= 0) {
            vsh[vj][0] = c0; vsh[vj][1] = c1; vsh[vj][2] = c2;
            vsh[vj][3] = d0; vsh[vj][4] = d1; vsh[vj][5] = d2;
        } else if (kj >= 0) {
            kp_s[kj][0] = c0; kp_s[kj][1] = c1; kp_s[kj][2] = c2;
            kp_s[kj][3] = d0; kp_s[kj][4] = d1; kp_s[kj][5] = d2;
            kn_s[kj] = sqrtf(d0 * d0 + d1 * d1 + d2 * d2);
        } else {
            dst[0] = c0 * g; dst[1] = c1 * g; dst[2] = c2 * g;
            dst[3] = d0 * g; dst[4] = d1 * g; dst[5] = d2 * g;
        }
    }
    __syncthreads();
    // vkvT
    #pragma unroll
    for (int e = 0; e < 3; e++) {
        int u = t * 3 + e;   // < 768
        int h = u >> 6, n = u & 63;
        float val;
        if (n < 16) val = kv[(size_t)l * 384 + 192 + h * 16 + n];
        else        val = vsh[h * 8 + (n - 16) / 6][(n - 16) % 6];
        unsigned short hi = f2b(val);
        size_t idx = ((size_t)h * 64 + n) * 320 + l;
        vkv_hi[idx] = hi;
        vkv_lo[idx] = f2b(val - b2f(hi));
    }
    // krow: [h][l][48] = kpt slice(24) | k-head(16) | nk(4) | pad(4)
    for (int idx = t; idx < 576; idx += 256) {
        int h = idx / 48, j = idx - h * 48;
        float v;
        if (j < 24)      v = kp_s[h * 4 + j / 6][j % 6];
        else if (j < 40) v = kv[(size_t)l * 384 + h * 16 + (j - 24)];
        else if (j < 44) v = kn_s[h * 4 + (j - 40)];
        else             v = 0.0f;
        krow[((size_t)h * 320 + l) * 48 + j] = v;
    }
}

// ---------------- kernel 3: attention logits + softmax -> att hi/lo ----------------
// grid (80, 12), 256 thr = 4 waves (one iq per wave, all share h).
// No LDS: each lane reads its dense 44-float k-row straight from krow (L2-resident).
__global__ __launch_bounds__(256) void k_att(
    const float* __restrict__ qb, const float* __restrict__ qpt,
    const float* __restrict__ krow,
    const float* __restrict__ fm, const float* __restrict__ gw,
    const float* __restrict__ dwp, const float* __restrict__ hwp,
    unsigned short* __restrict__ att_hi, unsigned short* __restrict__ att_lo)
{
    int tid = threadIdx.x;
    int w = tid >> 6, lane = tid & 63;
    int iq = blockIdx.x * 4 + w;
    int h = blockIdx.y;

    float qv[CH];
    #pragma unroll
    for (int c = 0; c < CH; c++) qv[c] = qb[(size_t)iq * 192 + h * CH + c];
    float qp[24];
    #pragma unroll
    for (int j = 0; j < 24; j++) qp[j] = qpt[(size_t)iq * 288 + h * 24 + j];
    float nq[PQ], nq2[PQ];
    #pragma unroll
    for (int p = 0; p < PQ; p++) {
        float x = qp[p * 6 + 3], y = qp[p * 6 + 4], zz = qp[p * 6 + 5];
        nq2[p] = x * x + y * y + zz * zz;
        nq[p] = sqrtf(nq2[p]);
    }
    float dwv = dwp[0], g0 = gw[0], g1 = gw[1], hwv = hwp[h];
    float fmi = fm[iq];

    float lg[5];
    #pragma unroll
    for (int r = 0; r < 5; r++) {
        int kk = r * 64 + lane;
        const float* row = krow + ((size_t)h * 320 + kk) * 48;

        float scalar = 0.f;
        #pragma unroll
        for (int c = 0; c < CH; c++) scalar += qv[c] * row[24 + c];
        scalar *= 0.25f;

        float pos = 0.f;
        #pragma unroll
        for (int p = 0; p < PQ; p++) {
            float dx = qp[p * 6] - row[p * 6];
            float dy = qp[p * 6 + 1] - row[p * 6 + 1];
            float dz = qp[p * 6 + 2] - row[p * 6 + 2];
            float d = __builtin_amdgcn_sqrtf(dx * dx + dy * dy + dz * dz);
            float de = d + EPSF;
            pos += d + __logf(de) + __builtin_amdgcn_rcpf(de);
        }
        pos *= 0.25f;

        float dir = 0.f;
        #pragma unroll
        for (int p = 0; p < PQ; p++) {
            float kx = row[p * 6 + 3], ky = row[p * 6 + 4], kz = row[p * 6 + 5];
            float nk = row[40 + p];
            float nk2 = nk * nk;
            float cm = 0.f, dself = 0.f;
            #pragma unroll
            for (int pq = 0; pq < PQ; pq++) {
                float dq = qp[pq * 6 + 3] * kx + qp[pq * 6 + 4] * ky + qp[pq * 6 + 5] * kz;
                if (pq == p) dself = dq;
                cm += __builtin_amdgcn_sqrtf(fmaxf(nq2[pq] * nk2 - dq * dq, 0.0f));
            }
            cm *= 0.25f;
            dir += dself - cm * __builtin_amdgcn_rcpf(nq[p] * nk + EPSF);
        }
        dir *= 0.25f;

        float logit = scalar + dwv * (g0 * pos + g1 * dir);
        logit *= hwv;
        logit += 100000.0f * (fmi * fm[kk] - 1.0f);
        lg[r] = logit;
    }

    float mx = lg[0];
    #pragma unroll
    for (int r = 1; r < 5; r++) mx = fmaxf(mx, lg[r]);
    for (int m = 32; m; m >>= 1) mx = fmaxf(mx, __shfl_xor(mx, m, 64));

    float e[5], sm = 0.f;
    #pragma unroll
    for (int r = 0; r < 5; r++) { e[r] = __expf(lg[r] - mx); sm += e[r]; }
    for (int m = 32; m; m >>= 1) sm += __shfl_xor(sm, m, 64);
    float inv = 1.0f / sm;
    #pragma unroll
    for (int r = 0; r < 5; r++) {
        float p = e[r] * inv;
        unsigned short hi = f2b(p);
        size_t idx = ((size_t)h * 320 + iq) * 320 + r * 64 + lane;
        att_hi[idx] = hi;
        att_lo[idx] = f2b(p - b2f(hi));
    }
}

// ---------------- kernel 5: o_scalar + o_geom via split MFMA + fused finish ------
// per (iq-tile of 16, h): [16 x 320] @ [320 x 64]. grid (20,12), 64 thr.
__global__ __launch_bounds__(64) void k_sv(
    const unsigned short* __restrict__ att_hi, const unsigned short* __restrict__ att_lo,
    const unsigned short* __restrict__ vkv_hi, const unsigned short* __restrict__ vkv_lo,
    const float* __restrict__ rot, const float* __restrict__ trans,
    unsigned short* __restrict__ cc_hi, unsigned short* __restrict__ cc_lo)
{
    __shared__ unsigned short a_hi[16][56];
    __shared__ unsigned short a_lo[16][56];
    __shared__ unsigned short bt_hi[64][56];
    __shared__ unsigned short bt_lo[64][56];
    __shared__ float ogsh[16][49];
    int iq0 = blockIdx.x * 16, h = blockIdx.y;
    int tid = threadIdx.x;
    int ncol = tid & 15, blk = tid >> 4, mrow = (tid >> 4) * 4;

    f32x4 acc[4] = {};
    for (int k0 = 0; k0 < 320; k0 += 32) {
        __syncthreads();
        {
            int row = tid >> 2, seg = tid & 3;
            size_t off = ((size_t)h * 320 + iq0 + row) * 320 + k0 + seg * 8;
            *(short8*)&a_hi[row][seg * 8] = *(const short8*)(att_hi + off);
            *(short8*)&a_lo[row][seg * 8] = *(const short8*)(att_lo + off);
        }
        {
            size_t off = ((size_t)h * 64 + tid) * 320 + k0;
            #pragma unroll
            for (int j2 = 0; j2 < 4; j2++) {
                *(short8*)&bt_hi[tid][j2 * 8] = *(const short8*)(vkv_hi + off + j2 * 8);
                *(short8*)&bt_lo[tid][j2 * 8] = *(const short8*)(vkv_lo + off + j2 * 8);
            }
        }
        __syncthreads();
        short8 afh = *(short8*)&a_hi[ncol][blk * 8];
        short8 afl = *(short8*)&a_lo[ncol][blk * 8];
        #pragma unroll
        for (int s4 = 0; s4 < 4; s4++) {
            short8 bfh = *(short8*)&bt_hi[s4 * 16 + ncol][blk * 8];
            short8 bfl = *(short8*)&bt_lo[s4 * 16 + ncol][blk * 8];
            acc[s4] = __builtin_amdgcn_mfma_f32_16x16x32_bf16(afh, bfh, acc[s4], 0, 0, 0);
            acc[s4] = __builtin_amdgcn_mfma_f32_16x16x32_bf16(afh, bfl, acc[s4], 0, 0, 0);
            acc[s4] = __builtin_amdgcn_mfma_f32_16x16x32_bf16(afl, bfh, acc[s4], 0, 0, 0);
        }
    }
    #pragma unroll
    for (int s4 = 0; s4 < 4; s4++) {
        int n = s4 * 16 + ncol;
        #pragma unroll
        for (int r = 0; r < 4; r++) {
            int iq = iq0 + mrow + r;
            float v = acc[s4][r];
            if (n < 16) {
                unsigned short hi = f2b(v);
                size_t idx = (size_t)iq * 2400 + h * 16 + n;
                cc_hi[idx] = hi;
                cc_lo[idx] = f2b(v - b2f(hi));
            } else {
                ogsh[mrow + r][n - 16] = v;
            }
        }
    }
    __syncthreads();
    #pragma unroll
    for (int t2 = tid; t2 < 128; t2 += 64) {
        int iqr = t2 >> 3, p = t2 & 7;
        int l = iq0 + iqr;
        const float* R = rot + l * 9;
        float tx = trans[l * 3], ty = trans[l * 3 + 1], tz = trans[l * 3 + 2];
        const float* o = &ogsh[iqr][p * 6];
        float gx = o[0] - tx, gy = o[1] - ty, gz = o[2] - tz;
        float l0 = R[0] * gx + R[3] * gy + R[6] * gz;
        float l1 = R[1] * gx + R[4] * gy + R[7] * gz;
        float l2 = R[2] * gx + R[5] * gy + R[8] * gz;
        float dx = o[3], dy = o[4], dz = o[5];
        float e0 = R[0] * dx + R[3] * dy + R[6] * dz;
        float e1 = R[1] * dx + R[4] * dy + R[7] * dz;
        float e2 = R[2] * dx + R[5] * dy + R[8] * dz;
        float n = sqrtf(e0 * e0 + e1 * e1 + e2 * e2);
        float inv = 1.0f / fmaxf(n, 1e-12f);
        float ln = sqrtf(l0 * l0 + l1 * l1 + l2 * l2);
        float vals[7] = { l0, l1, l2, e0 * inv, e1 * inv, e2 * inv, ln };
        size_t base = (size_t)l * 2400 + 192 + (h * PV + p) * 7;
        #pragma unroll
        for (int j = 0; j < 7; j++) {
            unsigned short hi = f2b(vals[j]);
            cc_hi[base + j] = hi;
            cc_lo[base + j] = f2b(vals[j] - b2f(hi));
        }
    }
}

// ---------------- kernel 6: o_pair via MFMA (att hi+lo, z plain bf16) -------------
// per iq: [16(h) x 320] @ [320 x 128]. grid (320), 256 thr.
__global__ __launch_bounds__(256) void k_pair(
    const unsigned short* __restrict__ att_hi, const unsigned short* __restrict__ att_lo,
    const float* __restrict__ z,
    unsigned short* __restrict__ cc_hi, unsigned short* __restrict__ cc_lo)
{
    __shared__ unsigned short a_hi[16][56];
    __shared__ unsigned short a_lo[16][56];
    __shared__ unsigned short zt_sh[128][56];
    int iq = blockIdx.x;
    int tid = threadIdx.x;
    int lane = tid & 63, w = tid >> 6;
    int ncol = lane & 15, blk = lane >> 4, mrow = (lane >> 4) * 4;

    f32x4 acc[2] = {};
    for (int k0 = 0; k0 < 320; k0 += 32) {
        __syncthreads();
        if (tid < 64) {
            int row = tid >> 2, seg = tid & 3;
            size_t off = (size_t)row * 102400 + (size_t)iq * 320 + k0 + seg * 8;
            *(short8*)&a_hi[row][seg * 8] = *(const short8*)(att_hi + off);
            *(short8*)&a_lo[row][seg * 8] = *(const short8*)(att_lo + off);
        }
        {
            int kk = tid >> 3, cb = (tid & 7) * 16;
            const float* src = z + ((size_t)iq * 320 + k0 + kk) * 128 + cb;
            #pragma unroll
            for (int g4 = 0; g4 < 4; g4++) {
                float4 f = *(const float4*)(src + g4 * 4);
                zt_sh[cb + g4 * 4 + 0][kk] = f2b(f.x);
                zt_sh[cb + g4 * 4 + 1][kk] = f2b(f.y);
                zt_sh[cb + g4 * 4 + 2][kk] = f2b(f.z);
                zt_sh[cb + g4 * 4 + 3][kk] = f2b(f.w);
            }
        }
        __syncthreads();
        short8 afh = *(short8*)&a_hi[ncol][blk * 8];
        short8 afl = *(short8*)&a_lo[ncol][blk * 8];
        #pragma unroll
        for (int s2 = 0; s2 < 2; s2++) {
            short8 bf = *(short8*)&zt_sh[w * 32 + s2 * 16 + ncol][blk * 8];
            acc[s2] = __builtin_amdgcn_mfma_f32_16x16x32_bf16(afl, bf, acc[s2], 0, 0, 0);
            acc[s2] = __builtin_amdgcn_mfma_f32_16x16x32_bf16(afh, bf, acc[s2], 0, 0, 0);
        }
    }
    #pragma unroll
    for (int s2 = 0; s2 < 2; s2++) {
        int n = w * 32 + s2 * 16 + ncol;
        #pragma unroll
        for (int r = 0; r < 4; r++) {
            int h = mrow + r;
            if (h < 12) {
                float v = acc[s2][r];
                unsigned short hi = f2b(v);
                size_t idx = (size_t)iq * 2400 + 864 + h * 128 + n;
                cc_hi[idx] = hi;
                cc_lo[idx] = f2b(v - b2f(hi));
            }
        }
    }
}

// ---------------- kernel 8: partials = cc @ Wo via split MFMA (no atomics) --------
// grid (5 m-tiles of 64, 8 n-tiles of 48, 5 k-splits of 480), 256 thr.
__global__ __launch_bounds__(256) void k_gemm(
    const unsigned short* __restrict__ cc_hi, const unsigned short* __restrict__ cc_lo,
    const unsigned short* __restrict__ wo_hi, const unsigned short* __restrict__ wo_lo,
    float* __restrict__ part)
{
    __shared__ unsigned short a_hi[64][56];
    __shared__ unsigned short a_lo[64][56];
    __shared__ unsigned short w_hi[48][56];
    __shared__ unsigned short w_lo[48][56];
    int iq0 = blockIdx.x * 64, col0 = blockIdx.y * 48, ks = blockIdx.z;
    int tid = threadIdx.x;
    int lane = tid & 63, w = tid >> 6;
    int ncol = lane & 15, blk = lane >> 4, mrow = (lane >> 4) * 4;

    f32x4 acc[3] = {};
    for (int kc = 0; kc < 15; kc++) {
        int k0 = ks * 480 + kc * 32;
        __syncthreads();
        {
            int row = tid >> 2, seg = tid & 3;
            size_t off = (size_t)(iq0 + row) * 2400 + k0 + seg * 8;
            *(short8*)&a_hi[row][seg * 8] = *(const short8*)(cc_hi + off);
            *(short8*)&a_lo[row][seg * 8] = *(const short8*)(cc_lo + off);
        }
        if (tid < 96) {
            int kk = tid / 3, coff = (tid % 3) * 16;
            size_t off = (size_t)(k0 + kk) * 384 + col0 + coff;
            short8 h0 = *(const short8*)(wo_hi + off);
            short8 h1 = *(const short8*)(wo_hi + off + 8);
            short8 l0v = *(const short8*)(wo_lo + off);
            short8 l1v = *(const short8*)(wo_lo + off + 8);
            #pragma unroll
            for (int i = 0; i < 8; i++) {
                w_hi[coff + i][kk]     = (unsigned short)h0[i];
                w_hi[coff + 8 + i][kk] = (unsigned short)h1[i];
                w_lo[coff + i][kk]     = (unsigned short)l0v[i];
                w_lo[coff + 8 + i][kk] = (unsigned short)l1v[i];
            }
        }
        __syncthreads();
        short8 afh = *(short8*)&a_hi[w * 16 + ncol][blk * 8];
        short8 afl = *(short8*)&a_lo[w * 16 + ncol][blk * 8];
        #pragma unroll
        for (int s3 = 0; s3 < 3; s3++) {
            short8 bfh = *(short8*)&w_hi[s3 * 16 + ncol][blk * 8];
            short8 bfl = *(short8*)&w_lo[s3 * 16 + ncol][blk * 8];
            acc[s3] = __builtin_amdgcn_mfma_f32_16x16x32_bf16(afh, bfh, acc[s3], 0, 0, 0);
            acc[s3] = __builtin_amdgcn_mfma_f32_16x16x32_bf16(afh, bfl, acc[s3], 0, 0, 0);
            acc[s3] = __builtin_amdgcn_mfma_f32_16x16x32_bf16(afl, bfh, acc[s3], 0, 0, 0);
        }
    }
    #pragma unroll
    for (int s3 = 0; s3 < 3; s3++) {
        int cn = col0 + s3 * 16 + ncol;
        #pragma unroll
        for (int r = 0; r < 4; r++)
            part[((size_t)ks * 320 + iq0 + w * 16 + mrow + r) * 384 + cn] = acc[s3][r];
    }
}

// ---------------- kernel 9: out = bo + sum of 5 partials (deterministic) ----------
__global__ __launch_bounds__(256) void k_reduce(
    const float* __restrict__ part, const float* __restrict__ bo, float* __restrict__ out)
{
    int i = blockIdx.x * 256 + threadIdx.x;   // < 122880
    float v = bo[i % CS];
    #pragma unroll
    for (int ks = 0; ks < 5; ks++) v += part[(size_t)ks * 122880 + i];
    out[i] = v;
}

extern "C" void kernel_launch(void* const* d_in, const int* in_sizes, int n_in,
                              void* d_out, int out_size, void* d_ws, size_t ws_size,
                              hipStream_t stream)
{
    const float* s     = (const float*)d_in[0];
    const float* rot   = (const float*)d_in[1];
    const float* trans = (const float*)d_in[2];
    const float* z     = (const float*)d_in[3];
    const float* fm    = (const float*)d_in[4];
    const float* Wq    = (const float*)d_in[5];
    const float* bq    = (const float*)d_in[6];
    const float* Wkv   = (const float*)d_in[7];
    const float* bkv   = (const float*)d_in[8];
    const float* Wqp   = (const float*)d_in[9];
    const float* bqp   = (const float*)d_in[10];
    const float* Wkvp  = (const float*)d_in[11];
    const float* bkvp  = (const float*)d_in[12];
    const float* Wg    = (const float*)d_in[13];
    const float* bg    = (const float*)d_in[14];
    const float* gw    = (const float*)d_in[15];
    const float* dw    = (const float*)d_in[16];
    const float* hw    = (const float*)d_in[17];
    const float* Wo    = (const float*)d_in[18];
    const float* bo    = (const float*)d_in[19];

    float* ws = (float*)d_ws;
    float*          q       = ws + OFF_Q;
    float*          kv      = ws + OFF_KV;
    float*          qpt     = ws + OFF_QPT;
    unsigned short* att_hi  = (unsigned short*)(ws + OFF_ATTHI);
    unsigned short* att_lo  = (unsigned short*)(ws + OFF_ATTLO);
    float*          ph_hi   = ws + OFF_ATTHI + 12 * 51200;
    float*          ph_lo   = ws + OFF_ATTLO + 12 * 51200;
    unsigned short* cc_hi   = (unsigned short*)(ws + OFF_CCHI);
    unsigned short* cc_lo   = (unsigned short*)(ws + OFF_CCLO);
    unsigned short* s_hi    = (unsigned short*)(ws + OFF_SHI);
    unsigned short* s_mid   = (unsigned short*)(ws + OFF_SMID);
    unsigned short* s_lo    = (unsigned short*)(ws + OFF_SLO);
    unsigned short* wc_hi   = (unsigned short*)(ws + OFF_WCATHI);
    unsigned short* wc_mid  = (unsigned short*)(ws + OFF_WCATMID);
    unsigned short* wc_lo   = (unsigned short*)(ws + OFF_WCATLO);
    float*          bcat    = ws + OFF_BCAT;
    unsigned short* wo_hi   = (unsigned short*)(ws + OFF_WOHI);
    unsigned short* wo_lo   = (unsigned short*)(ws + OFF_WOLO);
    unsigned short* vkv_hi  = (unsigned short*)(ws + OFF_VKVHI);
    unsigned short* vkv_lo  = (unsigned short*)(ws + OFF_VKVLO);
    float*          qpr     = ws + OFF_QPR;
    float*          kvpr    = ws + OFF_KVPR;
    float*          gate    = ws + OFF_GATE;
    float*          part    = ws + OFF_PART;
    float*          krow    = ws + OFF_KROW;
    float* out = (float*)d_out;

    k_cast<<<dim3(8352), dim3(256), 0, stream>>>(s, Wq, bq, Wkv, bkv, Wqp, bqp,
                                                 Wkvp, bkvp, Wg, bg, Wo,
                                                 s_hi, s_mid, s_lo, wc_hi, wc_mid, wc_lo,
                                                 bcat, wo_hi, wo_lo, ph_hi, ph_lo);
    k_proj<<<dim3(37, 5), dim3(256), 0, stream>>>(s_hi, s_mid, s_lo, wc_hi, wc_mid, wc_lo,
                                                  bcat, q, kv, qpr, kvpr, gate);
    k_points<<<dim3(LSEQ), dim3(256), 0, stream>>>(qpr, kvpr, gate, rot, trans, kv,
                                                   qpt, krow, vkv_hi, vkv_lo);
    k_att<<<dim3(80, NH), dim3(256), 0, stream>>>(q, qpt, krow, fm, gw, dw, hw,
                                                  att_hi, att_lo);
    k_sv<<<dim3(20, NH), dim3(64), 0, stream>>>(att_hi, att_lo, vkv_hi, vkv_lo,
                                                rot, trans, cc_hi, cc_lo);
    k_pair<<<dim3(LSEQ), dim3(256), 0, stream>>>(att_hi, att_lo, z, cc_hi, cc_lo);
    k_gemm<<<dim3(5, 8, 5), dim3(256), 0, stream>>>(cc_hi, cc_lo, wo_hi, wo_lo, part);
    k_reduce<<<dim3(480), dim3(256), 0, stream>>>(part, bo, out);
}

// Round 11
// 219.113 us; speedup vs baseline: 1.0685x; 1.0005x over previous
//
#include <hip/hip_runtime.h>
#include <hip/hip_bf16.h>
#include <math.h>

#define LSEQ 320
#define CS 384
#define CZ 128
#define CH 16
#define NH 12
#define PQ 4
#define PV 8
#define EPSF 1e-8f

typedef short short8 __attribute__((ext_vector_type(8)));
typedef float f32x4 __attribute__((ext_vector_type(4)));
typedef unsigned short ush2 __attribute__((ext_vector_type(2)));

// float -> bf16 (RNE)
__device__ __forceinline__ unsigned short f2b(float x) {
    union { float f; unsigned u; } v; v.f = x;
    unsigned r = (v.u + 0x7FFF + ((v.u >> 16) & 1)) >> 16;
    return (unsigned short)r;
}
__device__ __forceinline__ float b2f(unsigned short h) {
    union { unsigned u; float f; } v; v.u = ((unsigned)h) << 16;
    return v.f;
}

// workspace float offsets (~26 MB total; ws >= 256MB per fillBuffer evidence)
#define OFF_Q       0         // fp32 [320][192]
#define OFF_KV      61440     // fp32 [320][384]
#define OFF_QPT     184320    // fp32 [320][48][6]
#define OFF_ATTHI   552960    // bf16 [16][320][320] (planes 12-15 zeroed)
#define OFF_ATTLO   1372160   // bf16 [16][320][320]
#define OFF_CCHI    2191360   // bf16 [320][2400]
#define OFF_CCLO    2575360   // bf16 [320][2400]
#define OFF_SHI     2959360   // bf16 [320][384]
#define OFF_SMID    2990080
#define OFF_SLO     3020800
#define OFF_WCATHI  3051520   // bf16 [384][1776]
#define OFF_WCATMID 3392512
#define OFF_WCATLO  3733504
#define OFF_BCAT    4074496   // fp32 [1776]
#define OFF_WOHI    4076272   // bf16 [2400][384]
#define OFF_WOLO    4537072
#define OFF_VKVHI   4997872   // bf16 [12][64][320]
#define OFF_VKVLO   5120752
#define OFF_QPR     5243632   // fp32 [320][288]
#define OFF_KVPR    5335792   // fp32 [320][864]
#define OFF_GATE    5612272   // fp32 [320][48]
#define OFF_PART    5627632   // fp32 [5][320][384]
#define OFF_KROW    6242032   // fp32 [12][320][48]  (kpt slice | k-head | nk | pad)

// ---------------- kernel 0: cast inputs (3-way s/wcat, 2-way wo), zero phantom ----
__global__ __launch_bounds__(256) void k_cast(
    const float* __restrict__ s,
    const float* __restrict__ Wq, const float* __restrict__ bq,
    const float* __restrict__ Wkv, const float* __restrict__ bkv,
    const float* __restrict__ Wqp, const float* __restrict__ bqp,
    const float* __restrict__ Wkvp, const float* __restrict__ bkvp,
    const float* __restrict__ Wg, const float* __restrict__ bg,
    const float* __restrict__ Wo,
    unsigned short* __restrict__ s_hi, unsigned short* __restrict__ s_mid,
    unsigned short* __restrict__ s_lo,
    unsigned short* __restrict__ w_hi, unsigned short* __restrict__ w_mid,
    unsigned short* __restrict__ w_lo,
    float* __restrict__ bcat,
    unsigned short* __restrict__ wo_hi, unsigned short* __restrict__ wo_lo,
    float* __restrict__ ph_hi, float* __restrict__ ph_lo)
{
    int i = blockIdx.x * 256 + threadIdx.x;
    if (i < 122880) {
        float x = s[i];
        unsigned short hi = f2b(x);
        float r1 = x - b2f(hi);
        unsigned short mid = f2b(r1);
        s_hi[i] = hi; s_mid[i] = mid; s_lo[i] = f2b(r1 - b2f(mid));
        return;
    }
    i -= 122880;
    if (i < 681984) {
        int k = i / 1776, c = i - k * 1776;
        float v;
        if (c < 192)       v = Wq[(size_t)k * 192 + c];
        else if (c < 576)  v = Wkv[(size_t)k * 384 + c - 192];
        else if (c < 864)  v = Wqp[(size_t)k * 288 + c - 576];
        else if (c < 1728) v = Wkvp[(size_t)k * 864 + c - 864];
        else               v = Wg[(size_t)k * 48 + c - 1728];
        unsigned short hi = f2b(v);
        float r1 = v - b2f(hi);
        unsigned short mid = f2b(r1);
        w_hi[i] = hi; w_mid[i] = mid; w_lo[i] = f2b(r1 - b2f(mid));
        return;
    }
    i -= 681984;
    if (i < 1776) {
        float v;
        if (i < 192)       v = bq[i];
        else if (i < 576)  v = bkv[i - 192];
        else if (i < 864)  v = bqp[i - 576];
        else if (i < 1728) v = bkvp[i - 864];
        else               v = bg[i - 1728];
        bcat[i] = v;
        return;
    }
    i -= 1776;
    if (i < 921600) {
        float v = Wo[i];
        unsigned short hi = f2b(v);
        wo_hi[i] = hi; wo_lo[i] = f2b(v - b2f(hi));
        return;
    }
    i -= 921600;
    if (i < 204800) { ph_hi[i] = 0.0f; return; }
    i -= 204800;
    if (i < 204800) ph_lo[i] = 0.0f;
}

// ---------------- kernel 1: projection GEMM, 3-way split MFMA (fp32-equivalent) ----
// grid (37 n-tiles of 48, 5 m-tiles of 64), 256 thr.
__global__ __launch_bounds__(256) void k_proj(
    const unsigned short* __restrict__ s_hi, const unsigned short* __restrict__ s_mid,
    const unsigned short* __restrict__ s_lo,
    const unsigned short* __restrict__ wc_hi, const unsigned short* __restrict__ wc_mid,
    const unsigned short* __restrict__ wc_lo,
    const float* __restrict__ bcat,
    float* __restrict__ qo, float* __restrict__ kvo,
    float* __restrict__ qpr, float* __restrict__ kvpr, float* __restrict__ gate)
{
    __shared__ unsigned short a_h[64][56], a_m[64][56], a_l[64][56];
    __shared__ unsigned short w_h[48][56], w_m[48][56], w_l[48][56];
    int col0 = blockIdx.x * 48, l0 = blockIdx.y * 64;
    int tid = threadIdx.x;
    int lane = tid & 63, w = tid >> 6;
    int ncol = lane & 15, blk = lane >> 4, mrow = (lane >> 4) * 4;

    float* dst; int nc, cbase; bool sig = false;
    if (col0 < 192)       { nc = 192; cbase = col0;        dst = qo;   }
    else if (col0 < 576)  { nc = 384; cbase = col0 - 192;  dst = kvo;  }
    else if (col0 < 864)  { nc = 288; cbase = col0 - 576;  dst = qpr;  }
    else if (col0 < 1728) { nc = 864; cbase = col0 - 864;  dst = kvpr; }
    else                  { nc = 48;  cbase = 0;           dst = gate; sig = true; }

    f32x4 acc[3] = {};
    for (int k0 = 0; k0 < 384; k0 += 32) {
        __syncthreads();
        {
            int row = tid >> 2, seg = tid & 3;
            size_t off = (size_t)(l0 + row) * 384 + k0 + seg * 8;
            *(short8*)&a_h[row][seg * 8] = *(const short8*)(s_hi + off);
            *(short8*)&a_m[row][seg * 8] = *(const short8*)(s_mid + off);
            *(short8*)&a_l[row][seg * 8] = *(const short8*)(s_lo + off);
        }
        if (tid < 96) {
            int kk = tid / 3, coff = (tid % 3) * 16;
            size_t off = (size_t)(k0 + kk) * 1776 + col0 + coff;
            short8 h0 = *(const short8*)(wc_hi + off);
            short8 h1 = *(const short8*)(wc_hi + off + 8);
            short8 m0 = *(const short8*)(wc_mid + off);
            short8 m1 = *(const short8*)(wc_mid + off + 8);
            short8 l0v = *(const short8*)(wc_lo + off);
            short8 l1v = *(const short8*)(wc_lo + off + 8);
            #pragma unroll
            for (int i = 0; i < 8; i++) {
                w_h[coff + i][kk]     = (unsigned short)h0[i];
                w_h[coff + 8 + i][kk] = (unsigned short)h1[i];
                w_m[coff + i][kk]     = (unsigned short)m0[i];
                w_m[coff + 8 + i][kk] = (unsigned short)m1[i];
                w_l[coff + i][kk]     = (unsigned short)l0v[i];
                w_l[coff + 8 + i][kk] = (unsigned short)l1v[i];
            }
        }
        __syncthreads();
        short8 afh = *(short8*)&a_h[w * 16 + ncol][blk * 8];
        short8 afm = *(short8*)&a_m[w * 16 + ncol][blk * 8];
        short8 afl = *(short8*)&a_l[w * 16 + ncol][blk * 8];
        #pragma unroll
        for (int s3 = 0; s3 < 3; s3++) {
            short8 bfh = *(short8*)&w_h[s3 * 16 + ncol][blk * 8];
            short8 bfm = *(short8*)&w_m[s3 * 16 + ncol][blk * 8];
            short8 bfl = *(short8*)&w_l[s3 * 16 + ncol][blk * 8];
            acc[s3] = __builtin_amdgcn_mfma_f32_16x16x32_bf16(afm, bfm, acc[s3], 0, 0, 0);
            acc[s3] = __builtin_amdgcn_mfma_f32_16x16x32_bf16(afh, bfl, acc[s3], 0, 0, 0);
            acc[s3] = __builtin_amdgcn_mfma_f32_16x16x32_bf16(afl, bfh, acc[s3], 0, 0, 0);
            acc[s3] = __builtin_amdgcn_mfma_f32_16x16x32_bf16(afh, bfm, acc[s3], 0, 0, 0);
            acc[s3] = __builtin_amdgcn_mfma_f32_16x16x32_bf16(afm, bfh, acc[s3], 0, 0, 0);
            acc[s3] = __builtin_amdgcn_mfma_f32_16x16x32_bf16(afh, bfh, acc[s3], 0, 0, 0);
        }
    }
    #pragma unroll
    for (int s3 = 0; s3 < 3; s3++) {
        float bv = bcat[col0 + s3 * 16 + ncol];
        int cloc = cbase + s3 * 16 + ncol;
        #pragma unroll
        for (int r = 0; r < 4; r++) {
            float v2 = acc[s3][r] + bv;
            if (sig) v2 = 1.0f / (1.0f + expf(-v2));
            dst[(size_t)(l0 + w * 16 + mrow + r) * nc + cloc] = v2;
        }
    }
}

// ---------------- kernel 2: frame transforms + vkvT hi/lo + krow table ----------
__global__ __launch_bounds__(256) void k_points(
    const float* __restrict__ qpr, const float* __restrict__ kvpr, const float* __restrict__ gate,
    const float* __restrict__ rot, const float* __restrict__ trans,
    const float* __restrict__ kv,
    float* __restrict__ qpt, float* __restrict__ krow,
    unsigned short* __restrict__ vkv_hi, unsigned short* __restrict__ vkv_lo)
{
    __shared__ float vsh[96][6];
    __shared__ float kp_s[48][6];
    __shared__ float kn_s[48];
    int l = blockIdx.x, t = threadIdx.x;
    const float* R = rot + l * 9;
    float tx = trans[l * 3], ty = trans[l * 3 + 1], tz = trans[l * 3 + 2];
    if (t < 192) {
        const float* src; float g = 1.0f; float* dst = nullptr; int vj = -1, kj = -1;
        if (t < 48)      { src = qpr + (size_t)l * 288 + t * 6; g = gate[l * 48 + t]; dst = qpt + ((size_t)l * 48 + t) * 6; }
        else if (t < 96) { kj = t - 48; src = kvpr + (size_t)l * 864 + kj * 6; }
        else             { int j = t - 96; src = kvpr + (size_t)l * 864 + 288 + j * 6; vj = j; }
        float px = src[0], py = src[1], pz = src[2], ux = src[3], uy = src[4], uz = src[5];
        float c0 = R[0] * px + R[1] * py + R[2] * pz + tx;
        float c1 = R[3] * px + R[4] * py + R[5] * pz + ty;
        float c2 = R[6] * px + R[7] * py + R[8] * pz + tz;
        float d0 = R[0] * ux + R[1] * uy + R[2] * uz;
        float d1 = R[3] * ux + R[4] * uy + R[5] * uz;
        float d2 = R[6] * ux + R[7] * uy + R[8] * uz;
        if (vj >= 0) {
            vsh[vj][0] = c0; vsh[vj][1] = c1; vsh[vj][2] = c2;
            vsh[vj][3] = d0; vsh[vj][4] = d1; vsh[vj][5] = d2;
        } else if (kj >= 0) {
            kp_s[kj][0] = c0; kp_s[kj][1] = c1; kp_s[kj][2] = c2;
            kp_s[kj][3] = d0; kp_s[kj][4] = d1; kp_s[kj][5] = d2;
            kn_s[kj] = sqrtf(d0 * d0 + d1 * d1 + d2 * d2);
        } else {
            dst[0] = c0 * g; dst[1] = c1 * g; dst[2] = c2 * g;
            dst[3] = d0 * g; dst[4] = d1 * g; dst[5] = d2 * g;
        }
    }
    __syncthreads();
    // vkvT
    #pragma unroll
    for (int e = 0; e < 3; e++) {
        int u = t * 3 + e;   // < 768
        int h = u >> 6, n = u & 63;
        float val;
        if (n < 16) val = kv[(size_t)l * 384 + 192 + h * 16 + n];
        else        val = vsh[h * 8 + (n - 16) / 6][(n - 16) % 6];
        unsigned short hi = f2b(val);
        size_t idx = ((size_t)h * 64 + n) * 320 + l;
        vkv_hi[idx] = hi;
        vkv_lo[idx] = f2b(val - b2f(hi));
    }
    // krow: [h][l][48] = kpt slice(24) | k-head(16) | nk(4) | pad(4)
    for (int idx = t; idx < 576; idx += 256) {
        int h = idx / 48, j = idx - h * 48;
        float v;
        if (j < 24)      v = kp_s[h * 4 + j / 6][j % 6];
        else if (j < 40) v = kv[(size_t)l * 384 + h * 16 + (j - 24)];
        else if (j < 44) v = kn_s[h * 4 + (j - 40)];
        else             v = 0.0f;
        krow[((size_t)h * 320 + l) * 48 + j] = v;
    }
}

// ---------------- kernel 3: attention logits + softmax -> att hi/lo ----------------
// grid (80, 12), 256 thr = 4 waves (one iq per wave, all share h). No LDS.
__global__ __launch_bounds__(256) void k_att(
    const float* __restrict__ qb, const float* __restrict__ qpt,
    const float* __restrict__ krow,
    const float* __restrict__ fm, const float* __restrict__ gw,
    const float* __restrict__ dwp, const float* __restrict__ hwp,
    unsigned short* __restrict__ att_hi, unsigned short* __restrict__ att_lo)
{
    int tid = threadIdx.x;
    int w = tid >> 6, lane = tid & 63;
    int iq = blockIdx.x * 4 + w;
    int h = blockIdx.y;

    float qv[CH];
    #pragma unroll
    for (int c = 0; c < CH; c++) qv[c] = qb[(size_t)iq * 192 + h * CH + c];
    float qp[24];
    #pragma unroll
    for (int j = 0; j < 24; j++) qp[j] = qpt[(size_t)iq * 288 + h * 24 + j];
    float nq[PQ], nq2[PQ];
    #pragma unroll
    for (int p = 0; p < PQ; p++) {
        float x = qp[p * 6 + 3], y = qp[p * 6 + 4], zz = qp[p * 6 + 5];
        nq2[p] = x * x + y * y + zz * zz;
        nq[p] = sqrtf(nq2[p]);
    }
    float dwv = dwp[0], g0 = gw[0], g1 = gw[1], hwv = hwp[h];
    float fmi = fm[iq];

    float lg[5];
    #pragma unroll
    for (int r = 0; r < 5; r++) {
        int kk = r * 64 + lane;
        const float* row = krow + ((size_t)h * 320 + kk) * 48;

        float scalar = 0.f;
        #pragma unroll
        for (int c = 0; c < CH; c++) scalar += qv[c] * row[24 + c];
        scalar *= 0.25f;

        float pos = 0.f;
        #pragma unroll
        for (int p = 0; p < PQ; p++) {
            float dx = qp[p * 6] - row[p * 6];
            float dy = qp[p * 6 + 1] - row[p * 6 + 1];
            float dz = qp[p * 6 + 2] - row[p * 6 + 2];
            float d = __builtin_amdgcn_sqrtf(dx * dx + dy * dy + dz * dz);
            float de = d + EPSF;
            pos += d + __logf(de) + __builtin_amdgcn_rcpf(de);
        }
        pos *= 0.25f;

        float dir = 0.f;
        #pragma unroll
        for (int p = 0; p < PQ; p++) {
            float kx = row[p * 6 + 3], ky = row[p * 6 + 4], kz = row[p * 6 + 5];
            float nk = row[40 + p];
            float nk2 = nk * nk;
            float cm = 0.f, dself = 0.f;
            #pragma unroll
            for (int pq = 0; pq < PQ; pq++) {
                float dq = qp[pq * 6 + 3] * kx + qp[pq * 6 + 4] * ky + qp[pq * 6 + 5] * kz;
                if (pq == p) dself = dq;
                cm += __builtin_amdgcn_sqrtf(fmaxf(nq2[pq] * nk2 - dq * dq, 0.0f));
            }
            cm *= 0.25f;
            dir += dself - cm * __builtin_amdgcn_rcpf(nq[p] * nk + EPSF);
        }
        dir *= 0.25f;

        float logit = scalar + dwv * (g0 * pos + g1 * dir);
        logit *= hwv;
        logit += 100000.0f * (fmi * fm[kk] - 1.0f);
        lg[r] = logit;
    }

    float mx = lg[0];
    #pragma unroll
    for (int r = 1; r < 5; r++) mx = fmaxf(mx, lg[r]);
    for (int m = 32; m; m >>= 1) mx = fmaxf(mx, __shfl_xor(mx, m, 64));

    float e[5], sm = 0.f;
    #pragma unroll
    for (int r = 0; r < 5; r++) { e[r] = __expf(lg[r] - mx); sm += e[r]; }
    for (int m = 32; m; m >>= 1) sm += __shfl_xor(sm, m, 64);
    float inv = 1.0f / sm;
    #pragma unroll
    for (int r = 0; r < 5; r++) {
        float p = e[r] * inv;
        unsigned short hi = f2b(p);
        size_t idx = ((size_t)h * 320 + iq) * 320 + r * 64 + lane;
        att_hi[idx] = hi;
        att_lo[idx] = f2b(p - b2f(hi));
    }
}

// ---------------- kernel 5: o_scalar + o_geom via split MFMA + fused finish ------
// per (iq-tile of 16, h): [16 x 320] @ [320 x 64]. grid (20,12), 256 thr (4 waves).
// Wave w owns n-subtile [w*16, w*16+16); A tile shared via LDS. Bit-identical to
// the 64-thr version (same per-output MFMA sequence, same k order).
__global__ __launch_bounds__(256) void k_sv(
    const unsigned short* __restrict__ att_hi, const unsigned short* __restrict__ att_lo,
    const unsigned short* __restrict__ vkv_hi, const unsigned short* __restrict__ vkv_lo,
    const float* __restrict__ rot, const float* __restrict__ trans,
    unsigned short* __restrict__ cc_hi, unsigned short* __restrict__ cc_lo)
{
    __shared__ unsigned short a_hi[16][56];
    __shared__ unsigned short a_lo[16][56];
    __shared__ unsigned short bt_hi[64][56];
    __shared__ unsigned short bt_lo[64][56];
    __shared__ float ogsh[16][49];
    int iq0 = blockIdx.x * 16, h = blockIdx.y;
    int tid = threadIdx.x;
    int lane = tid & 63, w = tid >> 6;
    int ncol = lane & 15, mrow = (lane >> 4) * 4, blk = lane >> 4;

    f32x4 acc = {};
    for (int k0 = 0; k0 < 320; k0 += 32) {
        __syncthreads();
        if (tid < 64) {
            int row = tid >> 2, seg = tid & 3;
            size_t off = ((size_t)h * 320 + iq0 + row) * 320 + k0 + seg * 8;
            *(short8*)&a_hi[row][seg * 8] = *(const short8*)(att_hi + off);
            *(short8*)&a_lo[row][seg * 8] = *(const short8*)(att_lo + off);
        }
        {
            int row = tid >> 2, seg = tid & 3;
            size_t off = ((size_t)h * 64 + row) * 320 + k0 + seg * 8;
            *(short8*)&bt_hi[row][seg * 8] = *(const short8*)(vkv_hi + off);
            *(short8*)&bt_lo[row][seg * 8] = *(const short8*)(vkv_lo + off);
        }
        __syncthreads();
        short8 afh = *(short8*)&a_hi[ncol][blk * 8];
        short8 afl = *(short8*)&a_lo[ncol][blk * 8];
        short8 bfh = *(short8*)&bt_hi[w * 16 + ncol][blk * 8];
        short8 bfl = *(short8*)&bt_lo[w * 16 + ncol][blk * 8];
        acc = __builtin_amdgcn_mfma_f32_16x16x32_bf16(afh, bfh, acc, 0, 0, 0);
        acc = __builtin_amdgcn_mfma_f32_16x16x32_bf16(afh, bfl, acc, 0, 0, 0);
        acc = __builtin_amdgcn_mfma_f32_16x16x32_bf16(afl, bfh, acc, 0, 0, 0);
    }
    {
        int n = w * 16 + ncol;
        #pragma unroll
        for (int r = 0; r < 4; r++) {
            int iq = iq0 + mrow + r;
            float v = acc[r];
            if (n < 16) {
                unsigned short hi = f2b(v);
                size_t idx = (size_t)iq * 2400 + h * 16 + n;
                cc_hi[idx] = hi;
                cc_lo[idx] = f2b(v - b2f(hi));
            } else {
                ogsh[mrow + r][n - 16] = v;
            }
        }
    }
    __syncthreads();
    if (tid < 128) {
        int iqr = tid >> 3, p = tid & 7;
        int l = iq0 + iqr;
        const float* R = rot + l * 9;
        float tx = trans[l * 3], ty = trans[l * 3 + 1], tz = trans[l * 3 + 2];
        const float* o = &ogsh[iqr][p * 6];
        float gx = o[0] - tx, gy = o[1] - ty, gz = o[2] - tz;
        float l0 = R[0] * gx + R[3] * gy + R[6] * gz;
        float l1 = R[1] * gx + R[4] * gy + R[7] * gz;
        float l2 = R[2] * gx + R[5] * gy + R[8] * gz;
        float dx = o[3], dy = o[4], dz = o[5];
        float e0 = R[0] * dx + R[3] * dy + R[6] * dz;
        float e1 = R[1] * dx + R[4] * dy + R[7] * dz;
        float e2 = R[2] * dx + R[5] * dy + R[8] * dz;
        float n = sqrtf(e0 * e0 + e1 * e1 + e2 * e2);
        float inv = 1.0f / fmaxf(n, 1e-12f);
        float ln = sqrtf(l0 * l0 + l1 * l1 + l2 * l2);
        float vals[7] = { l0, l1, l2, e0 * inv, e1 * inv, e2 * inv, ln };
        size_t base = (size_t)l * 2400 + 192 + (h * PV + p) * 7;
        #pragma unroll
        for (int j = 0; j < 7; j++) {
            unsigned short hi = f2b(vals[j]);
            cc_hi[base + j] = hi;
            cc_lo[base + j] = f2b(vals[j] - b2f(hi));
        }
    }
}

// ---------------- kernel 6: o_pair via MFMA (att hi+lo, z plain bf16) -------------
// per iq: [16(h) x 320] @ [320 x 128]. grid (320), 256 thr.
// Staging: each thread converts a 2(k) x 8(c) z-tile, writes 8 ushort2 (b32) into
// the k-contiguous LDS column layout. Same f2b values/locations as before.
__global__ __launch_bounds__(256) void k_pair(
    const unsigned short* __restrict__ att_hi, const unsigned short* __restrict__ att_lo,
    const float* __restrict__ z,
    unsigned short* __restrict__ cc_hi, unsigned short* __restrict__ cc_lo)
{
    __shared__ unsigned short a_hi[16][56];
    __shared__ unsigned short a_lo[16][56];
    __shared__ unsigned short zt_sh[128][56];
    int iq = blockIdx.x;
    int tid = threadIdx.x;
    int lane = tid & 63, w = tid >> 6;
    int ncol = lane & 15, blk = lane >> 4, mrow = (lane >> 4) * 4;

    f32x4 acc[2] = {};
    for (int k0 = 0; k0 < 320; k0 += 32) {
        __syncthreads();
        if (tid < 64) {
            int row = tid >> 2, seg = tid & 3;
            size_t off = (size_t)row * 102400 + (size_t)iq * 320 + k0 + seg * 8;
            *(short8*)&a_hi[row][seg * 8] = *(const short8*)(att_hi + off);
            *(short8*)&a_lo[row][seg * 8] = *(const short8*)(att_lo + off);
        }
        {
            int kp2 = (tid >> 4) * 2;          // 0,2,..,30
            int cb = (tid & 15) * 8;           // 0,8,..,120
            const float* src0 = z + ((size_t)iq * 320 + k0 + kp2) * 128 + cb;
            float4 a0 = *(const float4*)(src0);
            float4 a1 = *(const float4*)(src0 + 4);
            float4 b0 = *(const float4*)(src0 + 128);
            float4 b1 = *(const float4*)(src0 + 132);
            float va[8] = {a0.x, a0.y, a0.z, a0.w, a1.x, a1.y, a1.z, a1.w};
            float vb[8] = {b0.x, b0.y, b0.z, b0.w, b1.x, b1.y, b1.z, b1.w};
            #pragma unroll
            for (int c = 0; c < 8; c++) {
                ush2 pr;
                pr[0] = f2b(va[c]);
                pr[1] = f2b(vb[c]);
                *(ush2*)&zt_sh[cb + c][kp2] = pr;
            }
        }
        __syncthreads();
        short8 afh = *(short8*)&a_hi[ncol][blk * 8];
        short8 afl = *(short8*)&a_lo[ncol][blk * 8];
        #pragma unroll
        for (int s2 = 0; s2 < 2; s2++) {
            short8 bf = *(short8*)&zt_sh[w * 32 + s2 * 16 + ncol][blk * 8];
            acc[s2] = __builtin_amdgcn_mfma_f32_16x16x32_bf16(afl, bf, acc[s2], 0, 0, 0);
            acc[s2] = __builtin_amdgcn_mfma_f32_16x16x32_bf16(afh, bf, acc[s2], 0, 0, 0);
        }
    }
    #pragma unroll
    for (int s2 = 0; s2 < 2; s2++) {
        int n = w * 32 + s2 * 16 + ncol;
        #pragma unroll
        for (int r = 0; r < 4; r++) {
            int h = mrow + r;
            if (h < 12) {
                float v = acc[s2][r];
                unsigned short hi = f2b(v);
                size_t idx = (size_t)iq * 2400 + 864 + h * 128 + n;
                cc_hi[idx] = hi;
                cc_lo[idx] = f2b(v - b2f(hi));
            }
        }
    }
}

// ---------------- kernel 8: partials = cc @ Wo via split MFMA (no atomics) --------
// grid (5 m-tiles of 64, 8 n-tiles of 48, 5 k-splits of 480), 256 thr.
__global__ __launch_bounds__(256) void k_gemm(
    const unsigned short* __restrict__ cc_hi, const unsigned short* __restrict__ cc_lo,
    const unsigned short* __restrict__ wo_hi, const unsigned short* __restrict__ wo_lo,
    float* __restrict__ part)
{
    __shared__ unsigned short a_hi[64][56];
    __shared__ unsigned short a_lo[64][56];
    __shared__ unsigned short w_hi[48][56];
    __shared__ unsigned short w_lo[48][56];
    int iq0 = blockIdx.x * 64, col0 = blockIdx.y * 48, ks = blockIdx.z;
    int tid = threadIdx.x;
    int lane = tid & 63, w = tid >> 6;
    int ncol = lane & 15, blk = lane >> 4, mrow = (lane >> 4) * 4;

    f32x4 acc[3] = {};
    for (int kc = 0; kc < 15; kc++) {
        int k0 = ks * 480 + kc * 32;
        __syncthreads();
        {
            int row = tid >> 2, seg = tid & 3;
            size_t off = (size_t)(iq0 + row) * 2400 + k0 + seg * 8;
            *(short8*)&a_hi[row][seg * 8] = *(const short8*)(cc_hi + off);
            *(short8*)&a_lo[row][seg * 8] = *(const short8*)(cc_lo + off);
        }
        if (tid < 96) {
            int kk = tid / 3, coff = (tid % 3) * 16;
            size_t off = (size_t)(k0 + kk) * 384 + col0 + coff;
            short8 h0 = *(const short8*)(wo_hi + off);
            short8 h1 = *(const short8*)(wo_hi + off + 8);
            short8 l0v = *(const short8*)(wo_lo + off);
            short8 l1v = *(const short8*)(wo_lo + off + 8);
            #pragma unroll
            for (int i = 0; i < 8; i++) {
                w_hi[coff + i][kk]     = (unsigned short)h0[i];
                w_hi[coff + 8 + i][kk] = (unsigned short)h1[i];
                w_lo[coff + i][kk]     = (unsigned short)l0v[i];
                w_lo[coff + 8 + i][kk] = (unsigned short)l1v[i];
            }
        }
        __syncthreads();
        short8 afh = *(short8*)&a_hi[w * 16 + ncol][blk * 8];
        short8 afl = *(short8*)&a_lo[w * 16 + ncol][blk * 8];
        #pragma unroll
        for (int s3 = 0; s3 < 3; s3++) {
            short8 bfh = *(short8*)&w_hi[s3 * 16 + ncol][blk * 8];
            short8 bfl = *(short8*)&w_lo[s3 * 16 + ncol][blk * 8];
            acc[s3] = __builtin_amdgcn_mfma_f32_16x16x32_bf16(afh, bfh, acc[s3], 0, 0, 0);
            acc[s3] = __builtin_amdgcn_mfma_f32_16x16x32_bf16(afh, bfl, acc[s3], 0, 0, 0);
            acc[s3] = __builtin_amdgcn_mfma_f32_16x16x32_bf16(afl, bfh, acc[s3], 0, 0, 0);
        }
    }
    #pragma unroll
    for (int s3 = 0; s3 < 3; s3++) {
        int cn = col0 + s3 * 16 + ncol;
        #pragma unroll
        for (int r = 0; r < 4; r++)
            part[((size_t)ks * 320 + iq0 + w * 16 + mrow + r) * 384 + cn] = acc[s3][r];
    }
}

// ---------------- kernel 9: out = bo + sum of 5 partials (deterministic) ----------
__global__ __launch_bounds__(256) void k_reduce(
    const float* __restrict__ part, const float* __restrict__ bo, float* __restrict__ out)
{
    int i = blockIdx.x * 256 + threadIdx.x;   // < 122880
    float v = bo[i % CS];
    #pragma unroll
    for (int ks = 0; ks < 5; ks++) v += part[(size_t)ks * 122880 + i];
    out[i] = v;
}

extern "C" void kernel_launch(void* const* d_in, const int* in_sizes, int n_in,
                              void* d_out, int out_size, void* d_ws, size_t ws_size,
                              hipStream_t stream)
{
    const float* s     = (const float*)d_in[0];
    const float* rot   = (const float*)d_in[1];
    const float* trans = (const float*)d_in[2];
    const float* z     = (const float*)d_in[3];
    const float* fm    = (const float*)d_in[4];
    const float* Wq    = (const float*)d_in[5];
    const float* bq    = (const float*)d_in[6];
    const float* Wkv   = (const float*)d_in[7];
    const float* bkv   = (const float*)d_in[8];
    const float* Wqp   = (const float*)d_in[9];
    const float* bqp   = (const float*)d_in[10];
    const float* Wkvp  = (const float*)d_in[11];
    const float* bkvp  = (const float*)d_in[12];
    const float* Wg    = (const float*)d_in[13];
    const float* bg    = (const float*)d_in[14];
    const float* gw    = (const float*)d_in[15];
    const float* dw    = (const float*)d_in[16];
    const float* hw    = (const float*)d_in[17];
    const float* Wo    = (const float*)d_in[18];
    const float* bo    = (const float*)d_in[19];

    float* ws = (float*)d_ws;
    float*          q       = ws + OFF_Q;
    float*          kv      = ws + OFF_KV;
    float*          qpt     = ws + OFF_QPT;
    unsigned short* att_hi  = (unsigned short*)(ws + OFF_ATTHI);
    unsigned short* att_lo  = (unsigned short*)(ws + OFF_ATTLO);
    float*          ph_hi   = ws + OFF_ATTHI + 12 * 51200;
    float*          ph_lo   = ws + OFF_ATTLO + 12 * 51200;
    unsigned short* cc_hi   = (unsigned short*)(ws + OFF_CCHI);
    unsigned short* cc_lo   = (unsigned short*)(ws + OFF_CCLO);
    unsigned short* s_hi    = (unsigned short*)(ws + OFF_SHI);
    unsigned short* s_mid   = (unsigned short*)(ws + OFF_SMID);
    unsigned short* s_lo    = (unsigned short*)(ws + OFF_SLO);
    unsigned short* wc_hi   = (unsigned short*)(ws + OFF_WCATHI);
    unsigned short* wc_mid  = (unsigned short*)(ws + OFF_WCATMID);
    unsigned short* wc_lo   = (unsigned short*)(ws + OFF_WCATLO);
    float*          bcat    = ws + OFF_BCAT;
    unsigned short* wo_hi   = (unsigned short*)(ws + OFF_WOHI);
    unsigned short* wo_lo   = (unsigned short*)(ws + OFF_WOLO);
    unsigned short* vkv_hi  = (unsigned short*)(ws + OFF_VKVHI);
    unsigned short* vkv_lo  = (unsigned short*)(ws + OFF_VKVLO);
    float*          qpr     = ws + OFF_QPR;
    float*          kvpr    = ws + OFF_KVPR;
    float*          gate    = ws + OFF_GATE;
    float*          part    = ws + OFF_PART;
    float*          krow    = ws + OFF_KROW;
    float* out = (float*)d_out;

    k_cast<<<dim3(8352), dim3(256), 0, stream>>>(s, Wq, bq, Wkv, bkv, Wqp, bqp,
                                                 Wkvp, bkvp, Wg, bg, Wo,
                                                 s_hi, s_mid, s_lo, wc_hi, wc_mid, wc_lo,
                                                 bcat, wo_hi, wo_lo, ph_hi, ph_lo);
    k_proj<<<dim3(37, 5), dim3(256), 0, stream>>>(s_hi, s_mid, s_lo, wc_hi, wc_mid, wc_lo,
                                                  bcat, q, kv, qpr, kvpr, gate);
    k_points<<<dim3(LSEQ), dim3(256), 0, stream>>>(qpr, kvpr, gate, rot, trans, kv,
                                                   qpt, krow, vkv_hi, vkv_lo);
    k_att<<<dim3(80, NH), dim3(256), 0, stream>>>(q, qpt, krow, fm, gw, dw, hw,
                                                  att_hi, att_lo);
    k_sv<<<dim3(20, NH), dim3(256), 0, stream>>>(att_hi, att_lo, vkv_hi, vkv_lo,
                                                 rot, trans, cc_hi, cc_lo);
    k_pair<<<dim3(LSEQ), dim3(256), 0, stream>>>(att_hi, att_lo, z, cc_hi, cc_lo);
    k_gemm<<<dim3(5, 8, 5), dim3(256), 0, stream>>>(cc_hi, cc_lo, wo_hi, wo_lo, part);
    k_reduce<<<dim3(480), dim3(256), 0, stream>>>(part, bo, out);
}

// Round 12
// 216.665 us; speedup vs baseline: 1.0806x; 1.0113x over previous
//
#include <hip/hip_runtime.h>
#include <hip/hip_bf16.h>
#include <math.h>

#define LSEQ 320
#define CS 384
#define CZ 128
#define CH 16
#define NH 12
#define PQ 4
#define PV 8
#define EPSF 1e-8f

typedef short short8 __attribute__((ext_vector_type(8)));
typedef float f32x4 __attribute__((ext_vector_type(4)));
typedef unsigned short ush2 __attribute__((ext_vector_type(2)));

// float -> bf16 (RNE)
__device__ __forceinline__ unsigned short f2b(float x) {
    union { float f; unsigned u; } v; v.f = x;
    unsigned r = (v.u + 0x7FFF + ((v.u >> 16) & 1)) >> 16;
    return (unsigned short)r;
}
__device__ __forceinline__ float b2f(unsigned short h) {
    union { unsigned u; float f; } v; v.u = ((unsigned)h) << 16;
    return v.f;
}

// workspace float offsets (~34 MB total; ws >= 256MB per fillBuffer evidence)
#define OFF_Q       0         // fp32 [320][192]
#define OFF_KV      61440     // fp32 [320][384]
#define OFF_QPT     184320    // fp32 [320][48][6]
#define OFF_ATTHI   552960    // bf16 [16][320][320] (planes 12-15 zeroed)
#define OFF_ATTLO   1372160   // bf16 [16][320][320]
#define OFF_CCHI    2191360   // bf16 [320][2400]
#define OFF_CCLO    2575360   // bf16 [320][2400]
#define OFF_SHI     2959360   // bf16 [320][384]
#define OFF_SMID    2990080
#define OFF_SLO     3020800
#define OFF_WCATHI  3051520   // bf16 [384][1776]
#define OFF_WCATMID 3392512
#define OFF_WCATLO  3733504
#define OFF_BCAT    4074496   // fp32 [1776]
#define OFF_WOHI    4076272   // bf16 [2400][384]
#define OFF_WOLO    4537072
#define OFF_VKVHI   4997872   // bf16 [12][64][320]
#define OFF_VKVLO   5120752
#define OFF_QPR     5243632   // fp32 [320][288]
#define OFF_KVPR    5335792   // fp32 [320][864]
#define OFF_GATE    5612272   // fp32 [320][48]
#define OFF_PART    5627632   // fp32 [5][320][384]
#define OFF_KROW    6242032   // fp32 [12][320][48]
#define OFF_WCTHI   6426352   // bf16 [1776][384] transposed
#define OFF_WCTMID  6767344
#define OFF_WCTLO   7108336
#define OFF_WOTHI   7449328   // bf16 [384][2400] transposed
#define OFF_WOTLO   7910128

// ---------------- kernel 0: cast inputs (3-way s/wcat, 2-way wo), zero phantom ----
__global__ __launch_bounds__(256) void k_cast(
    const float* __restrict__ s,
    const float* __restrict__ Wq, const float* __restrict__ bq,
    const float* __restrict__ Wkv, const float* __restrict__ bkv,
    const float* __restrict__ Wqp, const float* __restrict__ bqp,
    const float* __restrict__ Wkvp, const float* __restrict__ bkvp,
    const float* __restrict__ Wg, const float* __restrict__ bg,
    const float* __restrict__ Wo,
    unsigned short* __restrict__ s_hi, unsigned short* __restrict__ s_mid,
    unsigned short* __restrict__ s_lo,
    unsigned short* __restrict__ w_hi, unsigned short* __restrict__ w_mid,
    unsigned short* __restrict__ w_lo,
    float* __restrict__ bcat,
    unsigned short* __restrict__ wo_hi, unsigned short* __restrict__ wo_lo,
    float* __restrict__ ph_hi, float* __restrict__ ph_lo)
{
    int i = blockIdx.x * 256 + threadIdx.x;
    if (i < 122880) {
        float x = s[i];
        unsigned short hi = f2b(x);
        float r1 = x - b2f(hi);
        unsigned short mid = f2b(r1);
        s_hi[i] = hi; s_mid[i] = mid; s_lo[i] = f2b(r1 - b2f(mid));
        return;
    }
    i -= 122880;
    if (i < 681984) {
        int k = i / 1776, c = i - k * 1776;
        float v;
        if (c < 192)       v = Wq[(size_t)k * 192 + c];
        else if (c < 576)  v = Wkv[(size_t)k * 384 + c - 192];
        else if (c < 864)  v = Wqp[(size_t)k * 288 + c - 576];
        else if (c < 1728) v = Wkvp[(size_t)k * 864 + c - 864];
        else               v = Wg[(size_t)k * 48 + c - 1728];
        unsigned short hi = f2b(v);
        float r1 = v - b2f(hi);
        unsigned short mid = f2b(r1);
        w_hi[i] = hi; w_mid[i] = mid; w_lo[i] = f2b(r1 - b2f(mid));
        return;
    }
    i -= 681984;
    if (i < 1776) {
        float v;
        if (i < 192)       v = bq[i];
        else if (i < 576)  v = bkv[i - 192];
        else if (i < 864)  v = bqp[i - 576];
        else if (i < 1728) v = bkvp[i - 864];
        else               v = bg[i - 1728];
        bcat[i] = v;
        return;
    }
    i -= 1776;
    if (i < 921600) {
        float v = Wo[i];
        unsigned short hi = f2b(v);
        wo_hi[i] = hi; wo_lo[i] = f2b(v - b2f(hi));
        return;
    }
    i -= 921600;
    if (i < 204800) { ph_hi[i] = 0.0f; return; }
    i -= 204800;
    if (i < 204800) ph_lo[i] = 0.0f;
}

// ---------------- kernel 0b: tiled transpose of weight planes -------------------
// grid (38, 28, 5); 64x64 tiles via LDS. Out-of-range blocks exit.
__global__ __launch_bounds__(256) void k_tr(
    const unsigned short* __restrict__ wc_hi, const unsigned short* __restrict__ wc_mid,
    const unsigned short* __restrict__ wc_lo,
    const unsigned short* __restrict__ wo_hi, const unsigned short* __restrict__ wo_lo,
    unsigned short* __restrict__ wcT_hi, unsigned short* __restrict__ wcT_mid,
    unsigned short* __restrict__ wcT_lo,
    unsigned short* __restrict__ woT_hi, unsigned short* __restrict__ woT_lo)
{
    int m = blockIdx.z;
    const unsigned short* in; unsigned short* outp; int R, C;
    if (m == 0)      { in = wc_hi;  outp = wcT_hi;  R = 384;  C = 1776; }
    else if (m == 1) { in = wc_mid; outp = wcT_mid; R = 384;  C = 1776; }
    else if (m == 2) { in = wc_lo;  outp = wcT_lo;  R = 384;  C = 1776; }
    else if (m == 3) { in = wo_hi;  outp = woT_hi;  R = 2400; C = 384;  }
    else             { in = wo_lo;  outp = woT_lo;  R = 2400; C = 384;  }
    int r0 = blockIdx.x * 64, c0 = blockIdx.y * 64;
    if (r0 >= R || c0 >= C) return;
    __shared__ unsigned short t[64][65];
    int tid = threadIdx.x;
    #pragma unroll
    for (int rep = 0; rep < 16; rep++) {
        int idx = rep * 256 + tid;
        int i = idx >> 6, j = idx & 63;
        if (r0 + i < R && c0 + j < C) t[i][j] = in[(size_t)(r0 + i) * C + c0 + j];
    }
    __syncthreads();
    #pragma unroll
    for (int rep = 0; rep < 16; rep++) {
        int idx = rep * 256 + tid;
        int i = idx >> 6, j = idx & 63;
        if (c0 + i < C && r0 + j < R) outp[(size_t)(c0 + i) * R + r0 + j] = t[j][i];
    }
}

// ---------------- kernel 1: projection GEMM, 3-way split MFMA (fp32-equivalent) ----
// grid (37 n-tiles of 48, 5 m-tiles of 64), 256 thr. W staged from wcT (vectorized).
__global__ __launch_bounds__(256) void k_proj(
    const unsigned short* __restrict__ s_hi, const unsigned short* __restrict__ s_mid,
    const unsigned short* __restrict__ s_lo,
    const unsigned short* __restrict__ wcT_hi, const unsigned short* __restrict__ wcT_mid,
    const unsigned short* __restrict__ wcT_lo,
    const float* __restrict__ bcat,
    float* __restrict__ qo, float* __restrict__ kvo,
    float* __restrict__ qpr, float* __restrict__ kvpr, float* __restrict__ gate)
{
    __shared__ unsigned short a_h[64][56], a_m[64][56], a_l[64][56];
    __shared__ unsigned short w_h[48][56], w_m[48][56], w_l[48][56];
    int col0 = blockIdx.x * 48, l0 = blockIdx.y * 64;
    int tid = threadIdx.x;
    int lane = tid & 63, w = tid >> 6;
    int ncol = lane & 15, blk = lane >> 4, mrow = (lane >> 4) * 4;

    float* dst; int nc, cbase; bool sig = false;
    if (col0 < 192)       { nc = 192; cbase = col0;        dst = qo;   }
    else if (col0 < 576)  { nc = 384; cbase = col0 - 192;  dst = kvo;  }
    else if (col0 < 864)  { nc = 288; cbase = col0 - 576;  dst = qpr;  }
    else if (col0 < 1728) { nc = 864; cbase = col0 - 864;  dst = kvpr; }
    else                  { nc = 48;  cbase = 0;           dst = gate; sig = true; }

    f32x4 acc[3] = {};
    for (int k0 = 0; k0 < 384; k0 += 32) {
        __syncthreads();
        {
            int row = tid >> 2, seg = tid & 3;
            size_t off = (size_t)(l0 + row) * 384 + k0 + seg * 8;
            *(short8*)&a_h[row][seg * 8] = *(const short8*)(s_hi + off);
            *(short8*)&a_m[row][seg * 8] = *(const short8*)(s_mid + off);
            *(short8*)&a_l[row][seg * 8] = *(const short8*)(s_lo + off);
        }
        if (tid < 192) {
            int row = tid >> 2, seg = tid & 3;
            size_t off = (size_t)(col0 + row) * 384 + k0 + seg * 8;
            *(short8*)&w_h[row][seg * 8] = *(const short8*)(wcT_hi + off);
            *(short8*)&w_m[row][seg * 8] = *(const short8*)(wcT_mid + off);
            *(short8*)&w_l[row][seg * 8] = *(const short8*)(wcT_lo + off);
        }
        __syncthreads();
        short8 afh = *(short8*)&a_h[w * 16 + ncol][blk * 8];
        short8 afm = *(short8*)&a_m[w * 16 + ncol][blk * 8];
        short8 afl = *(short8*)&a_l[w * 16 + ncol][blk * 8];
        #pragma unroll
        for (int s3 = 0; s3 < 3; s3++) {
            short8 bfh = *(short8*)&w_h[s3 * 16 + ncol][blk * 8];
            short8 bfm = *(short8*)&w_m[s3 * 16 + ncol][blk * 8];
            short8 bfl = *(short8*)&w_l[s3 * 16 + ncol][blk * 8];
            acc[s3] = __builtin_amdgcn_mfma_f32_16x16x32_bf16(afm, bfm, acc[s3], 0, 0, 0);
            acc[s3] = __builtin_amdgcn_mfma_f32_16x16x32_bf16(afh, bfl, acc[s3], 0, 0, 0);
            acc[s3] = __builtin_amdgcn_mfma_f32_16x16x32_bf16(afl, bfh, acc[s3], 0, 0, 0);
            acc[s3] = __builtin_amdgcn_mfma_f32_16x16x32_bf16(afh, bfm, acc[s3], 0, 0, 0);
            acc[s3] = __builtin_amdgcn_mfma_f32_16x16x32_bf16(afm, bfh, acc[s3], 0, 0, 0);
            acc[s3] = __builtin_amdgcn_mfma_f32_16x16x32_bf16(afh, bfh, acc[s3], 0, 0, 0);
        }
    }
    #pragma unroll
    for (int s3 = 0; s3 < 3; s3++) {
        float bv = bcat[col0 + s3 * 16 + ncol];
        int cloc = cbase + s3 * 16 + ncol;
        #pragma unroll
        for (int r = 0; r < 4; r++) {
            float v2 = acc[s3][r] + bv;
            if (sig) v2 = 1.0f / (1.0f + expf(-v2));
            dst[(size_t)(l0 + w * 16 + mrow + r) * nc + cloc] = v2;
        }
    }
}

// ---------------- kernel 2: frame transforms + vkvT hi/lo + krow table ----------
__global__ __launch_bounds__(256) void k_points(
    const float* __restrict__ qpr, const float* __restrict__ kvpr, const float* __restrict__ gate,
    const float* __restrict__ rot, const float* __restrict__ trans,
    const float* __restrict__ kv,
    float* __restrict__ qpt, float* __restrict__ krow,
    unsigned short* __restrict__ vkv_hi, unsigned short* __restrict__ vkv_lo)
{
    __shared__ float vsh[96][6];
    __shared__ float kp_s[48][6];
    __shared__ float kn_s[48];
    int l = blockIdx.x, t = threadIdx.x;
    const float* R = rot + l * 9;
    float tx = trans[l * 3], ty = trans[l * 3 + 1], tz = trans[l * 3 + 2];
    if (t < 192) {
        const float* src; float g = 1.0f; float* dst = nullptr; int vj = -1, kj = -1;
        if (t < 48)      { src = qpr + (size_t)l * 288 + t * 6; g = gate[l * 48 + t]; dst = qpt + ((size_t)l * 48 + t) * 6; }
        else if (t < 96) { kj = t - 48; src = kvpr + (size_t)l * 864 + kj * 6; }
        else             { int j = t - 96; src = kvpr + (size_t)l * 864 + 288 + j * 6; vj = j; }
        float px = src[0], py = src[1], pz = src[2], ux = src[3], uy = src[4], uz = src[5];
        float c0 = R[0] * px + R[1] * py + R[2] * pz + tx;
        float c1 = R[3] * px + R[4] * py + R[5] * pz + ty;
        float c2 = R[6] * px + R[7] * py + R[8] * pz + tz;
        float d0 = R[0] * ux + R[1] * uy + R[2] * uz;
        float d1 = R[3] * ux + R[4] * uy + R[5] * uz;
        float d2 = R[6] * ux + R[7] * uy + R[8] * uz;
        if (vj >= 0) {
            vsh[vj][0] = c0; vsh[vj][1] = c1; vsh[vj][2] = c2;
            vsh[vj][3] = d0; vsh[vj][4] = d1; vsh[vj][5] = d2;
        } else if (kj >= 0) {
            kp_s[kj][0] = c0; kp_s[kj][1] = c1; kp_s[kj][2] = c2;
            kp_s[kj][3] = d0; kp_s[kj][4] = d1; kp_s[kj][5] = d2;
            kn_s[kj] = sqrtf(d0 * d0 + d1 * d1 + d2 * d2);
        } else {
            dst[0] = c0 * g; dst[1] = c1 * g; dst[2] = c2 * g;
            dst[3] = d0 * g; dst[4] = d1 * g; dst[5] = d2 * g;
        }
    }
    __syncthreads();
    #pragma unroll
    for (int e = 0; e < 3; e++) {
        int u = t * 3 + e;   // < 768
        int h = u >> 6, n = u & 63;
        float val;
        if (n < 16) val = kv[(size_t)l * 384 + 192 + h * 16 + n];
        else        val = vsh[h * 8 + (n - 16) / 6][(n - 16) % 6];
        unsigned short hi = f2b(val);
        size_t idx = ((size_t)h * 64 + n) * 320 + l;
        vkv_hi[idx] = hi;
        vkv_lo[idx] = f2b(val - b2f(hi));
    }
    for (int idx = t; idx < 576; idx += 256) {
        int h = idx / 48, j = idx - h * 48;
        float v;
        if (j < 24)      v = kp_s[h * 4 + j / 6][j % 6];
        else if (j < 40) v = kv[(size_t)l * 384 + h * 16 + (j - 24)];
        else if (j < 44) v = kn_s[h * 4 + (j - 40)];
        else             v = 0.0f;
        krow[((size_t)h * 320 + l) * 48 + j] = v;
    }
}

// ---------------- kernel 3: attention logits + softmax -> att hi/lo ----------------
__global__ __launch_bounds__(256) void k_att(
    const float* __restrict__ qb, const float* __restrict__ qpt,
    const float* __restrict__ krow,
    const float* __restrict__ fm, const float* __restrict__ gw,
    const float* __restrict__ dwp, const float* __restrict__ hwp,
    unsigned short* __restrict__ att_hi, unsigned short* __restrict__ att_lo)
{
    int tid = threadIdx.x;
    int w = tid >> 6, lane = tid & 63;
    int iq = blockIdx.x * 4 + w;
    int h = blockIdx.y;

    float qv[CH];
    #pragma unroll
    for (int c = 0; c < CH; c++) qv[c] = qb[(size_t)iq * 192 + h * CH + c];
    float qp[24];
    #pragma unroll
    for (int j = 0; j < 24; j++) qp[j] = qpt[(size_t)iq * 288 + h * 24 + j];
    float nq[PQ], nq2[PQ];
    #pragma unroll
    for (int p = 0; p < PQ; p++) {
        float x = qp[p * 6 + 3], y = qp[p * 6 + 4], zz = qp[p * 6 + 5];
        nq2[p] = x * x + y * y + zz * zz;
        nq[p] = sqrtf(nq2[p]);
    }
    float dwv = dwp[0], g0 = gw[0], g1 = gw[1], hwv = hwp[h];
    float fmi = fm[iq];

    float lg[5];
    #pragma unroll
    for (int r = 0; r < 5; r++) {
        int kk = r * 64 + lane;
        const float* row = krow + ((size_t)h * 320 + kk) * 48;

        float scalar = 0.f;
        #pragma unroll
        for (int c = 0; c < CH; c++) scalar += qv[c] * row[24 + c];
        scalar *= 0.25f;

        float pos = 0.f;
        #pragma unroll
        for (int p = 0; p < PQ; p++) {
            float dx = qp[p * 6] - row[p * 6];
            float dy = qp[p * 6 + 1] - row[p * 6 + 1];
            float dz = qp[p * 6 + 2] - row[p * 6 + 2];
            float d = __builtin_amdgcn_sqrtf(dx * dx + dy * dy + dz * dz);
            float de = d + EPSF;
            pos += d + __logf(de) + __builtin_amdgcn_rcpf(de);
        }
        pos *= 0.25f;

        float dir = 0.f;
        #pragma unroll
        for (int p = 0; p < PQ; p++) {
            float kx = row[p * 6 + 3], ky = row[p * 6 + 4], kz = row[p * 6 + 5];
            float nk = row[40 + p];
            float nk2 = nk * nk;
            float cm = 0.f, dself = 0.f;
            #pragma unroll
            for (int pq = 0; pq < PQ; pq++) {
                float dq = qp[pq * 6 + 3] * kx + qp[pq * 6 + 4] * ky + qp[pq * 6 + 5] * kz;
                if (pq == p) dself = dq;
                cm += __builtin_amdgcn_sqrtf(fmaxf(nq2[pq] * nk2 - dq * dq, 0.0f));
            }
            cm *= 0.25f;
            dir += dself - cm * __builtin_amdgcn_rcpf(nq[p] * nk + EPSF);
        }
        dir *= 0.25f;

        float logit = scalar + dwv * (g0 * pos + g1 * dir);
        logit *= hwv;
        logit += 100000.0f * (fmi * fm[kk] - 1.0f);
        lg[r] = logit;
    }

    float mx = lg[0];
    #pragma unroll
    for (int r = 1; r < 5; r++) mx = fmaxf(mx, lg[r]);
    for (int m = 32; m; m >>= 1) mx = fmaxf(mx, __shfl_xor(mx, m, 64));

    float e[5], sm = 0.f;
    #pragma unroll
    for (int r = 0; r < 5; r++) { e[r] = __expf(lg[r] - mx); sm += e[r]; }
    for (int m = 32; m; m >>= 1) sm += __shfl_xor(sm, m, 64);
    float inv = 1.0f / sm;
    #pragma unroll
    for (int r = 0; r < 5; r++) {
        float p = e[r] * inv;
        unsigned short hi = f2b(p);
        size_t idx = ((size_t)h * 320 + iq) * 320 + r * 64 + lane;
        att_hi[idx] = hi;
        att_lo[idx] = f2b(p - b2f(hi));
    }
}

// ---------------- kernel 5: fused sv (blocks 0..239) + pair (blocks 240..559) -----
__global__ __launch_bounds__(256) void k_svpair(
    const unsigned short* __restrict__ att_hi, const unsigned short* __restrict__ att_lo,
    const unsigned short* __restrict__ vkv_hi, const unsigned short* __restrict__ vkv_lo,
    const float* __restrict__ z,
    const float* __restrict__ rot, const float* __restrict__ trans,
    unsigned short* __restrict__ cc_hi, unsigned short* __restrict__ cc_lo)
{
    __shared__ unsigned short a_hi[16][56];
    __shared__ unsigned short a_lo[16][56];
    __shared__ unsigned short B[128][56];   // sv: bt_hi=B[0:64], bt_lo=B[64:128]; pair: zt
    __shared__ float ogsh[16][49];
    int bid = blockIdx.x;
    int tid = threadIdx.x;
    int lane = tid & 63, w = tid >> 6;
    int ncol = lane & 15, blk = lane >> 4, mrow = (lane >> 4) * 4;

    if (bid < 240) {
        // ---------- sv: per (iq-tile of 16, h): [16 x 320] @ [320 x 64] ----------
        int iq0 = (bid % 20) * 16, h = bid / 20;
        f32x4 acc = {};
        for (int k0 = 0; k0 < 320; k0 += 32) {
            __syncthreads();
            if (tid < 64) {
                int row = tid >> 2, seg = tid & 3;
                size_t off = ((size_t)h * 320 + iq0 + row) * 320 + k0 + seg * 8;
                *(short8*)&a_hi[row][seg * 8] = *(const short8*)(att_hi + off);
                *(short8*)&a_lo[row][seg * 8] = *(const short8*)(att_lo + off);
            }
            {
                int row = tid >> 2, seg = tid & 3;
                size_t off = ((size_t)h * 64 + row) * 320 + k0 + seg * 8;
                *(short8*)&B[row][seg * 8]      = *(const short8*)(vkv_hi + off);
                *(short8*)&B[64 + row][seg * 8] = *(const short8*)(vkv_lo + off);
            }
            __syncthreads();
            short8 afh = *(short8*)&a_hi[ncol][blk * 8];
            short8 afl = *(short8*)&a_lo[ncol][blk * 8];
            short8 bfh = *(short8*)&B[w * 16 + ncol][blk * 8];
            short8 bfl = *(short8*)&B[64 + w * 16 + ncol][blk * 8];
            acc = __builtin_amdgcn_mfma_f32_16x16x32_bf16(afh, bfh, acc, 0, 0, 0);
            acc = __builtin_amdgcn_mfma_f32_16x16x32_bf16(afh, bfl, acc, 0, 0, 0);
            acc = __builtin_amdgcn_mfma_f32_16x16x32_bf16(afl, bfh, acc, 0, 0, 0);
        }
        {
            int n = w * 16 + ncol;
            #pragma unroll
            for (int r = 0; r < 4; r++) {
                int iq = iq0 + mrow + r;
                float v = acc[r];
                if (n < 16) {
                    unsigned short hi = f2b(v);
                    size_t idx = (size_t)iq * 2400 + h * 16 + n;
                    cc_hi[idx] = hi;
                    cc_lo[idx] = f2b(v - b2f(hi));
                } else {
                    ogsh[mrow + r][n - 16] = v;
                }
            }
        }
        __syncthreads();
        if (tid < 128) {
            int iqr = tid >> 3, p = tid & 7;
            int l = iq0 + iqr;
            const float* R = rot + l * 9;
            float tx = trans[l * 3], ty = trans[l * 3 + 1], tz = trans[l * 3 + 2];
            const float* o = &ogsh[iqr][p * 6];
            float gx = o[0] - tx, gy = o[1] - ty, gz = o[2] - tz;
            float l0 = R[0] * gx + R[3] * gy + R[6] * gz;
            float l1 = R[1] * gx + R[4] * gy + R[7] * gz;
            float l2 = R[2] * gx + R[5] * gy + R[8] * gz;
            float dx = o[3], dy = o[4], dz = o[5];
            float e0 = R[0] * dx + R[3] * dy + R[6] * dz;
            float e1 = R[1] * dx + R[4] * dy + R[7] * dz;
            float e2 = R[2] * dx + R[5] * dy + R[8] * dz;
            float n = sqrtf(e0 * e0 + e1 * e1 + e2 * e2);
            float inv = 1.0f / fmaxf(n, 1e-12f);
            float ln = sqrtf(l0 * l0 + l1 * l1 + l2 * l2);
            float vals[7] = { l0, l1, l2, e0 * inv, e1 * inv, e2 * inv, ln };
            size_t base = (size_t)l * 2400 + 192 + (h * PV + p) * 7;
            #pragma unroll
            for (int j = 0; j < 7; j++) {
                unsigned short hi = f2b(vals[j]);
                cc_hi[base + j] = hi;
                cc_lo[base + j] = f2b(vals[j] - b2f(hi));
            }
        }
    } else {
        // ---------- pair: per iq: [16(h) x 320] @ [320 x 128] ----------
        int iq = bid - 240;
        f32x4 acc[2] = {};
        for (int k0 = 0; k0 < 320; k0 += 32) {
            __syncthreads();
            if (tid < 64) {
                int row = tid >> 2, seg = tid & 3;
                size_t off = (size_t)row * 102400 + (size_t)iq * 320 + k0 + seg * 8;
                *(short8*)&a_hi[row][seg * 8] = *(const short8*)(att_hi + off);
                *(short8*)&a_lo[row][seg * 8] = *(const short8*)(att_lo + off);
            }
            {
                int kp2 = (tid >> 4) * 2;
                int cb = (tid & 15) * 8;
                const float* src0 = z + ((size_t)iq * 320 + k0 + kp2) * 128 + cb;
                float4 a0 = *(const float4*)(src0);
                float4 a1 = *(const float4*)(src0 + 4);
                float4 b0 = *(const float4*)(src0 + 128);
                float4 b1 = *(const float4*)(src0 + 132);
                float va[8] = {a0.x, a0.y, a0.z, a0.w, a1.x, a1.y, a1.z, a1.w};
                float vb[8] = {b0.x, b0.y, b0.z, b0.w, b1.x, b1.y, b1.z, b1.w};
                #pragma unroll
                for (int c = 0; c < 8; c++) {
                    ush2 pr;
                    pr[0] = f2b(va[c]);
                    pr[1] = f2b(vb[c]);
                    *(ush2*)&B[cb + c][kp2] = pr;
                }
            }
            __syncthreads();
            short8 afh = *(short8*)&a_hi[ncol][blk * 8];
            short8 afl = *(short8*)&a_lo[ncol][blk * 8];
            #pragma unroll
            for (int s2 = 0; s2 < 2; s2++) {
                short8 bf = *(short8*)&B[w * 32 + s2 * 16 + ncol][blk * 8];
                acc[s2] = __builtin_amdgcn_mfma_f32_16x16x32_bf16(afl, bf, acc[s2], 0, 0, 0);
                acc[s2] = __builtin_amdgcn_mfma_f32_16x16x32_bf16(afh, bf, acc[s2], 0, 0, 0);
            }
        }
        #pragma unroll
        for (int s2 = 0; s2 < 2; s2++) {
            int n = w * 32 + s2 * 16 + ncol;
            #pragma unroll
            for (int r = 0; r < 4; r++) {
                int h = mrow + r;
                if (h < 12) {
                    float v = acc[s2][r];
                    unsigned short hi = f2b(v);
                    size_t idx = (size_t)iq * 2400 + 864 + h * 128 + n;
                    cc_hi[idx] = hi;
                    cc_lo[idx] = f2b(v - b2f(hi));
                }
            }
        }
    }
}

// ---------------- kernel 8: partials = cc @ Wo via split MFMA (no atomics) --------
// grid (5 m-tiles of 64, 8 n-tiles of 48, 5 k-splits of 480), 256 thr. W from woT.
__global__ __launch_bounds__(256) void k_gemm(
    const unsigned short* __restrict__ cc_hi, const unsigned short* __restrict__ cc_lo,
    const unsigned short* __restrict__ woT_hi, const unsigned short* __restrict__ woT_lo,
    float* __restrict__ part)
{
    __shared__ unsigned short a_hi[64][56];
    __shared__ unsigned short a_lo[64][56];
    __shared__ unsigned short w_hi[48][56];
    __shared__ unsigned short w_lo[48][56];
    int iq0 = blockIdx.x * 64, col0 = blockIdx.y * 48, ks = blockIdx.z;
    int tid = threadIdx.x;
    int lane = tid & 63, w = tid >> 6;
    int ncol = lane & 15, blk = lane >> 4, mrow = (lane >> 4) * 4;

    f32x4 acc[3] = {};
    for (int kc = 0; kc < 15; kc++) {
        int k0 = ks * 480 + kc * 32;
        __syncthreads();
        {
            int row = tid >> 2, seg = tid & 3;
            size_t off = (size_t)(iq0 + row) * 2400 + k0 + seg * 8;
            *(short8*)&a_hi[row][seg * 8] = *(const short8*)(cc_hi + off);
            *(short8*)&a_lo[row][seg * 8] = *(const short8*)(cc_lo + off);
        }
        if (tid < 192) {
            int row = tid >> 2, seg = tid & 3;
            size_t off = (size_t)(col0 + row) * 2400 + k0 + seg * 8;
            *(short8*)&w_hi[row][seg * 8] = *(const short8*)(woT_hi + off);
            *(short8*)&w_lo[row][seg * 8] = *(const short8*)(woT_lo + off);
        }
        __syncthreads();
        short8 afh = *(short8*)&a_hi[w * 16 + ncol][blk * 8];
        short8 afl = *(short8*)&a_lo[w * 16 + ncol][blk * 8];
        #pragma unroll
        for (int s3 = 0; s3 < 3; s3++) {
            short8 bfh = *(short8*)&w_hi[s3 * 16 + ncol][blk * 8];
            short8 bfl = *(short8*)&w_lo[s3 * 16 + ncol][blk * 8];
            acc[s3] = __builtin_amdgcn_mfma_f32_16x16x32_bf16(afh, bfh, acc[s3], 0, 0, 0);
            acc[s3] = __builtin_amdgcn_mfma_f32_16x16x32_bf16(afh, bfl, acc[s3], 0, 0, 0);
            acc[s3] = __builtin_amdgcn_mfma_f32_16x16x32_bf16(afl, bfh, acc[s3], 0, 0, 0);
        }
    }
    #pragma unroll
    for (int s3 = 0; s3 < 3; s3++) {
        int cn = col0 + s3 * 16 + ncol;
        #pragma unroll
        for (int r = 0; r < 4; r++)
            part[((size_t)ks * 320 + iq0 + w * 16 + mrow + r) * 384 + cn] = acc[s3][r];
    }
}

// ---------------- kernel 9: out = bo + sum of 5 partials (deterministic) ----------
__global__ __launch_bounds__(256) void k_reduce(
    const float* __restrict__ part, const float* __restrict__ bo, float* __restrict__ out)
{
    int i = blockIdx.x * 256 + threadIdx.x;   // < 122880
    float v = bo[i % CS];
    #pragma unroll
    for (int ks = 0; ks < 5; ks++) v += part[(size_t)ks * 122880 + i];
    out[i] = v;
}

extern "C" void kernel_launch(void* const* d_in, const int* in_sizes, int n_in,
                              void* d_out, int out_size, void* d_ws, size_t ws_size,
                              hipStream_t stream)
{
    const float* s     = (const float*)d_in[0];
    const float* rot   = (const float*)d_in[1];
    const float* trans = (const float*)d_in[2];
    const float* z     = (const float*)d_in[3];
    const float* fm    = (const float*)d_in[4];
    const float* Wq    = (const float*)d_in[5];
    const float* bq    = (const float*)d_in[6];
    const float* Wkv   = (const float*)d_in[7];
    const float* bkv   = (const float*)d_in[8];
    const float* Wqp   = (const float*)d_in[9];
    const float* bqp   = (const float*)d_in[10];
    const float* Wkvp  = (const float*)d_in[11];
    const float* bkvp  = (const float*)d_in[12];
    const float* Wg    = (const float*)d_in[13];
    const float* bg    = (const float*)d_in[14];
    const float* gw    = (const float*)d_in[15];
    const float* dw    = (const float*)d_in[16];
    const float* hw    = (const float*)d_in[17];
    const float* Wo    = (const float*)d_in[18];
    const float* bo    = (const float*)d_in[19];

    float* ws = (float*)d_ws;
    float*          q       = ws + OFF_Q;
    float*          kv      = ws + OFF_KV;
    float*          qpt     = ws + OFF_QPT;
    unsigned short* att_hi  = (unsigned short*)(ws + OFF_ATTHI);
    unsigned short* att_lo  = (unsigned short*)(ws + OFF_ATTLO);
    float*          ph_hi   = ws + OFF_ATTHI + 12 * 51200;
    float*          ph_lo   = ws + OFF_ATTLO + 12 * 51200;
    unsigned short* cc_hi   = (unsigned short*)(ws + OFF_CCHI);
    unsigned short* cc_lo   = (unsigned short*)(ws + OFF_CCLO);
    unsigned short* s_hi    = (unsigned short*)(ws + OFF_SHI);
    unsigned short* s_mid   = (unsigned short*)(ws + OFF_SMID);
    unsigned short* s_lo    = (unsigned short*)(ws + OFF_SLO);
    unsigned short* wc_hi   = (unsigned short*)(ws + OFF_WCATHI);
    unsigned short* wc_mid  = (unsigned short*)(ws + OFF_WCATMID);
    unsigned short* wc_lo   = (unsigned short*)(ws + OFF_WCATLO);
    float*          bcat    = ws + OFF_BCAT;
    unsigned short* wo_hi   = (unsigned short*)(ws + OFF_WOHI);
    unsigned short* wo_lo   = (unsigned short*)(ws + OFF_WOLO);
    unsigned short* vkv_hi  = (unsigned short*)(ws + OFF_VKVHI);
    unsigned short* vkv_lo  = (unsigned short*)(ws + OFF_VKVLO);
    float*          qpr     = ws + OFF_QPR;
    float*          kvpr    = ws + OFF_KVPR;
    float*          gate    = ws + OFF_GATE;
    float*          part    = ws + OFF_PART;
    float*          krow    = ws + OFF_KROW;
    unsigned short* wcT_hi  = (unsigned short*)(ws + OFF_WCTHI);
    unsigned short* wcT_mid = (unsigned short*)(ws + OFF_WCTMID);
    unsigned short* wcT_lo  = (unsigned short*)(ws + OFF_WCTLO);
    unsigned short* woT_hi  = (unsigned short*)(ws + OFF_WOTHI);
    unsigned short* woT_lo  = (unsigned short*)(ws + OFF_WOTLO);
    float* out = (float*)d_out;

    k_cast<<<dim3(8352), dim3(256), 0, stream>>>(s, Wq, bq, Wkv, bkv, Wqp, bqp,
                                                 Wkvp, bkvp, Wg, bg, Wo,
                                                 s_hi, s_mid, s_lo, wc_hi, wc_mid, wc_lo,
                                                 bcat, wo_hi, wo_lo, ph_hi, ph_lo);
    k_tr<<<dim3(38, 28, 5), dim3(256), 0, stream>>>(wc_hi, wc_mid, wc_lo, wo_hi, wo_lo,
                                                    wcT_hi, wcT_mid, wcT_lo, woT_hi, woT_lo);
    k_proj<<<dim3(37, 5), dim3(256), 0, stream>>>(s_hi, s_mid, s_lo, wcT_hi, wcT_mid, wcT_lo,
                                                  bcat, q, kv, qpr, kvpr, gate);
    k_points<<<dim3(LSEQ), dim3(256), 0, stream>>>(qpr, kvpr, gate, rot, trans, kv,
                                                   qpt, krow, vkv_hi, vkv_lo);
    k_att<<<dim3(80, NH), dim3(256), 0, stream>>>(q, qpt, krow, fm, gw, dw, hw,
                                                  att_hi, att_lo);
    k_svpair<<<dim3(560), dim3(256), 0, stream>>>(att_hi, att_lo, vkv_hi, vkv_lo, z,
                                                  rot, trans, cc_hi, cc_lo);
    k_gemm<<<dim3(5, 8, 5), dim3(256), 0, stream>>>(cc_hi, cc_lo, woT_hi, woT_lo, part);
    k_reduce<<<dim3(480), dim3(256), 0, stream>>>(part, bo, out);
}

// Round 13
// 210.046 us; speedup vs baseline: 1.1146x; 1.0315x over previous
//
#include <hip/hip_runtime.h>
#include <hip/hip_bf16.h>
#include <math.h>

#define LSEQ 320
#define CS 384
#define CZ 128
#define CH 16
#define NH 12
#define PQ 4
#define PV 8
#define EPSF 1e-8f

typedef short short8 __attribute__((ext_vector_type(8)));
typedef float f32x4 __attribute__((ext_vector_type(4)));
typedef unsigned short ush2 __attribute__((ext_vector_type(2)));

// float -> bf16 (RNE)
__device__ __forceinline__ unsigned short f2b(float x) {
    union { float f; unsigned u; } v; v.f = x;
    unsigned r = (v.u + 0x7FFF + ((v.u >> 16) & 1)) >> 16;
    return (unsigned short)r;
}
__device__ __forceinline__ float b2f(unsigned short h) {
    union { unsigned u; float f; } v; v.u = ((unsigned)h) << 16;
    return v.f;
}

// workspace float offsets (~34 MB total)
#define OFF_Q       0
#define OFF_KV      61440
#define OFF_QPT     184320
#define OFF_ATTHI   552960
#define OFF_ATTLO   1372160
#define OFF_CCHI    2191360
#define OFF_CCLO    2575360
#define OFF_SHI     2959360
#define OFF_SMID    2990080
#define OFF_SLO     3020800
#define OFF_WCATHI  3051520
#define OFF_WCATMID 3392512
#define OFF_WCATLO  3733504
#define OFF_BCAT    4074496
#define OFF_WOHI    4076272
#define OFF_WOLO    4537072
#define OFF_VKVHI   4997872
#define OFF_VKVLO   5120752
#define OFF_QPR     5243632
#define OFF_KVPR    5335792
#define OFF_GATE    5612272
#define OFF_PART    5627632
#define OFF_KROW    6242032
#define OFF_WCTHI   6426352
#define OFF_WCTMID  6767344
#define OFF_WCTLO   7108336
#define OFF_WOTHI   7449328
#define OFF_WOTLO   7910128

// ---------------- kernel 0: cast inputs (3-way s/wcat, 2-way wo), zero phantom ----
__global__ __launch_bounds__(256) void k_cast(
    const float* __restrict__ s,
    const float* __restrict__ Wq, const float* __restrict__ bq,
    const float* __restrict__ Wkv, const float* __restrict__ bkv,
    const float* __restrict__ Wqp, const float* __restrict__ bqp,
    const float* __restrict__ Wkvp, const float* __restrict__ bkvp,
    const float* __restrict__ Wg, const float* __restrict__ bg,
    const float* __restrict__ Wo,
    unsigned short* __restrict__ s_hi, unsigned short* __restrict__ s_mid,
    unsigned short* __restrict__ s_lo,
    unsigned short* __restrict__ w_hi, unsigned short* __restrict__ w_mid,
    unsigned short* __restrict__ w_lo,
    float* __restrict__ bcat,
    unsigned short* __restrict__ wo_hi, unsigned short* __restrict__ wo_lo,
    float* __restrict__ ph_hi, float* __restrict__ ph_lo)
{
    int i = blockIdx.x * 256 + threadIdx.x;
    if (i < 122880) {
        float x = s[i];
        unsigned short hi = f2b(x);
        float r1 = x - b2f(hi);
        unsigned short mid = f2b(r1);
        s_hi[i] = hi; s_mid[i] = mid; s_lo[i] = f2b(r1 - b2f(mid));
        return;
    }
    i -= 122880;
    if (i < 681984) {
        int k = i / 1776, c = i - k * 1776;
        float v;
        if (c < 192)       v = Wq[(size_t)k * 192 + c];
        else if (c < 576)  v = Wkv[(size_t)k * 384 + c - 192];
        else if (c < 864)  v = Wqp[(size_t)k * 288 + c - 576];
        else if (c < 1728) v = Wkvp[(size_t)k * 864 + c - 864];
        else               v = Wg[(size_t)k * 48 + c - 1728];
        unsigned short hi = f2b(v);
        float r1 = v - b2f(hi);
        unsigned short mid = f2b(r1);
        w_hi[i] = hi; w_mid[i] = mid; w_lo[i] = f2b(r1 - b2f(mid));
        return;
    }
    i -= 681984;
    if (i < 1776) {
        float v;
        if (i < 192)       v = bq[i];
        else if (i < 576)  v = bkv[i - 192];
        else if (i < 864)  v = bqp[i - 576];
        else if (i < 1728) v = bkvp[i - 864];
        else               v = bg[i - 1728];
        bcat[i] = v;
        return;
    }
    i -= 1776;
    if (i < 921600) {
        float v = Wo[i];
        unsigned short hi = f2b(v);
        wo_hi[i] = hi; wo_lo[i] = f2b(v - b2f(hi));
        return;
    }
    i -= 921600;
    if (i < 204800) { ph_hi[i] = 0.0f; return; }
    i -= 204800;
    if (i < 204800) ph_lo[i] = 0.0f;
}

// ---------------- kernel 0b: tiled transpose of weight planes -------------------
__global__ __launch_bounds__(256) void k_tr(
    const unsigned short* __restrict__ wc_hi, const unsigned short* __restrict__ wc_mid,
    const unsigned short* __restrict__ wc_lo,
    const unsigned short* __restrict__ wo_hi, const unsigned short* __restrict__ wo_lo,
    unsigned short* __restrict__ wcT_hi, unsigned short* __restrict__ wcT_mid,
    unsigned short* __restrict__ wcT_lo,
    unsigned short* __restrict__ woT_hi, unsigned short* __restrict__ woT_lo)
{
    int m = blockIdx.z;
    const unsigned short* in; unsigned short* outp; int R, C;
    if (m == 0)      { in = wc_hi;  outp = wcT_hi;  R = 384;  C = 1776; }
    else if (m == 1) { in = wc_mid; outp = wcT_mid; R = 384;  C = 1776; }
    else if (m == 2) { in = wc_lo;  outp = wcT_lo;  R = 384;  C = 1776; }
    else if (m == 3) { in = wo_hi;  outp = woT_hi;  R = 2400; C = 384;  }
    else             { in = wo_lo;  outp = woT_lo;  R = 2400; C = 384;  }
    int r0 = blockIdx.x * 64, c0 = blockIdx.y * 64;
    if (r0 >= R || c0 >= C) return;
    __shared__ unsigned short t[64][65];
    int tid = threadIdx.x;
    #pragma unroll
    for (int rep = 0; rep < 16; rep++) {
        int idx = rep * 256 + tid;
        int i = idx >> 6, j = idx & 63;
        if (r0 + i < R && c0 + j < C) t[i][j] = in[(size_t)(r0 + i) * C + c0 + j];
    }
    __syncthreads();
    #pragma unroll
    for (int rep = 0; rep < 16; rep++) {
        int idx = rep * 256 + tid;
        int i = idx >> 6, j = idx & 63;
        if (c0 + i < C && r0 + j < R) outp[(size_t)(c0 + i) * R + r0 + j] = t[j][i];
    }
}

// ---------------- kernel 1: projection GEMM, 3-way split MFMA, m=16 tiles ---------
// grid (37 n-tiles of 48, 20 m-tiles of 16), 192 thr (3 waves; wave w = s3 subtile).
__global__ __launch_bounds__(192) void k_proj(
    const unsigned short* __restrict__ s_hi, const unsigned short* __restrict__ s_mid,
    const unsigned short* __restrict__ s_lo,
    const unsigned short* __restrict__ wcT_hi, const unsigned short* __restrict__ wcT_mid,
    const unsigned short* __restrict__ wcT_lo,
    const float* __restrict__ bcat,
    float* __restrict__ qo, float* __restrict__ kvo,
    float* __restrict__ qpr, float* __restrict__ kvpr, float* __restrict__ gate)
{
    __shared__ unsigned short a_h[16][56], a_m[16][56], a_l[16][56];
    __shared__ unsigned short w_h[48][56], w_m[48][56], w_l[48][56];
    int col0 = blockIdx.x * 48, l0 = blockIdx.y * 16;
    int tid = threadIdx.x;
    int lane = tid & 63, w = tid >> 6;   // w = 0..2 (s3 subtile)
    int ncol = lane & 15, blk = lane >> 4, mrow = (lane >> 4) * 4;

    float* dst; int nc, cbase; bool sig = false;
    if (col0 < 192)       { nc = 192; cbase = col0;        dst = qo;   }
    else if (col0 < 576)  { nc = 384; cbase = col0 - 192;  dst = kvo;  }
    else if (col0 < 864)  { nc = 288; cbase = col0 - 576;  dst = qpr;  }
    else if (col0 < 1728) { nc = 864; cbase = col0 - 864;  dst = kvpr; }
    else                  { nc = 48;  cbase = 0;           dst = gate; sig = true; }

    f32x4 acc = {};
    for (int k0 = 0; k0 < 384; k0 += 32) {
        __syncthreads();
        {
            // a: 16 rows x 4 segs x 3 arrays = 192 slots, one per thread
            int arr = tid >> 6, idx = tid & 63;
            int row = idx >> 2, seg = idx & 3;
            size_t off = (size_t)(l0 + row) * 384 + k0 + seg * 8;
            if (arr == 0)      *(short8*)&a_h[row][seg * 8] = *(const short8*)(s_hi + off);
            else if (arr == 1) *(short8*)&a_m[row][seg * 8] = *(const short8*)(s_mid + off);
            else               *(short8*)&a_l[row][seg * 8] = *(const short8*)(s_lo + off);
        }
        {
            // w: 48 rows x 4 segs x 3 arrays = 576 slots, three per thread
            int row = tid >> 2, seg = tid & 3;
            size_t off = (size_t)(col0 + row) * 384 + k0 + seg * 8;
            *(short8*)&w_h[row][seg * 8] = *(const short8*)(wcT_hi + off);
            *(short8*)&w_m[row][seg * 8] = *(const short8*)(wcT_mid + off);
            *(short8*)&w_l[row][seg * 8] = *(const short8*)(wcT_lo + off);
        }
        __syncthreads();
        short8 afh = *(short8*)&a_h[ncol][blk * 8];
        short8 afm = *(short8*)&a_m[ncol][blk * 8];
        short8 afl = *(short8*)&a_l[ncol][blk * 8];
        short8 bfh = *(short8*)&w_h[w * 16 + ncol][blk * 8];
        short8 bfm = *(short8*)&w_m[w * 16 + ncol][blk * 8];
        short8 bfl = *(short8*)&w_l[w * 16 + ncol][blk * 8];
        acc = __builtin_amdgcn_mfma_f32_16x16x32_bf16(afm, bfm, acc, 0, 0, 0);
        acc = __builtin_amdgcn_mfma_f32_16x16x32_bf16(afh, bfl, acc, 0, 0, 0);
        acc = __builtin_amdgcn_mfma_f32_16x16x32_bf16(afl, bfh, acc, 0, 0, 0);
        acc = __builtin_amdgcn_mfma_f32_16x16x32_bf16(afh, bfm, acc, 0, 0, 0);
        acc = __builtin_amdgcn_mfma_f32_16x16x32_bf16(afm, bfh, acc, 0, 0, 0);
        acc = __builtin_amdgcn_mfma_f32_16x16x32_bf16(afh, bfh, acc, 0, 0, 0);
    }
    {
        int n = w * 16 + ncol;
        float bv = bcat[col0 + n];
        int cloc = cbase + n;
        #pragma unroll
        for (int r = 0; r < 4; r++) {
            float v2 = acc[r] + bv;
            if (sig) v2 = 1.0f / (1.0f + expf(-v2));
            dst[(size_t)(l0 + mrow + r) * nc + cloc] = v2;
        }
    }
}

// ---------------- kernel 2: frame transforms + vkvT hi/lo + krow table ----------
__global__ __launch_bounds__(256) void k_points(
    const float* __restrict__ qpr, const float* __restrict__ kvpr, const float* __restrict__ gate,
    const float* __restrict__ rot, const float* __restrict__ trans,
    const float* __restrict__ kv,
    float* __restrict__ qpt, float* __restrict__ krow,
    unsigned short* __restrict__ vkv_hi, unsigned short* __restrict__ vkv_lo)
{
    __shared__ float vsh[96][6];
    __shared__ float kp_s[48][6];
    __shared__ float kn_s[48];
    int l = blockIdx.x, t = threadIdx.x;
    const float* R = rot + l * 9;
    float tx = trans[l * 3], ty = trans[l * 3 + 1], tz = trans[l * 3 + 2];
    if (t < 192) {
        const float* src; float g = 1.0f; float* dst = nullptr; int vj = -1, kj = -1;
        if (t < 48)      { src = qpr + (size_t)l * 288 + t * 6; g = gate[l * 48 + t]; dst = qpt + ((size_t)l * 48 + t) * 6; }
        else if (t < 96) { kj = t - 48; src = kvpr + (size_t)l * 864 + kj * 6; }
        else             { int j = t - 96; src = kvpr + (size_t)l * 864 + 288 + j * 6; vj = j; }
        float px = src[0], py = src[1], pz = src[2], ux = src[3], uy = src[4], uz = src[5];
        float c0 = R[0] * px + R[1] * py + R[2] * pz + tx;
        float c1 = R[3] * px + R[4] * py + R[5] * pz + ty;
        float c2 = R[6] * px + R[7] * py + R[8] * pz + tz;
        float d0 = R[0] * ux + R[1] * uy + R[2] * uz;
        float d1 = R[3] * ux + R[4] * uy + R[5] * uz;
        float d2 = R[6] * ux + R[7] * uy + R[8] * uz;
        if (vj >= 0) {
            vsh[vj][0] = c0; vsh[vj][1] = c1; vsh[vj][2] = c2;
            vsh[vj][3] = d0; vsh[vj][4] = d1; vsh[vj][5] = d2;
        } else if (kj >= 0) {
            kp_s[kj][0] = c0; kp_s[kj][1] = c1; kp_s[kj][2] = c2;
            kp_s[kj][3] = d0; kp_s[kj][4] = d1; kp_s[kj][5] = d2;
            kn_s[kj] = sqrtf(d0 * d0 + d1 * d1 + d2 * d2);
        } else {
            dst[0] = c0 * g; dst[1] = c1 * g; dst[2] = c2 * g;
            dst[3] = d0 * g; dst[4] = d1 * g; dst[5] = d2 * g;
        }
    }
    __syncthreads();
    #pragma unroll
    for (int e = 0; e < 3; e++) {
        int u = t * 3 + e;   // < 768
        int h = u >> 6, n = u & 63;
        float val;
        if (n < 16) val = kv[(size_t)l * 384 + 192 + h * 16 + n];
        else        val = vsh[h * 8 + (n - 16) / 6][(n - 16) % 6];
        unsigned short hi = f2b(val);
        size_t idx = ((size_t)h * 64 + n) * 320 + l;
        vkv_hi[idx] = hi;
        vkv_lo[idx] = f2b(val - b2f(hi));
    }
    for (int idx = t; idx < 576; idx += 256) {
        int h = idx / 48, j = idx - h * 48;
        float v;
        if (j < 24)      v = kp_s[h * 4 + j / 6][j % 6];
        else if (j < 40) v = kv[(size_t)l * 384 + h * 16 + (j - 24)];
        else if (j < 44) v = kn_s[h * 4 + (j - 40)];
        else             v = 0.0f;
        krow[((size_t)h * 320 + l) * 48 + j] = v;
    }
}

// ---------------- kernel 3: attention logits + softmax, 2 iq per wave -------------
// grid (40, 12), 256 thr = 4 waves; each wave handles iq pair, sharing k-row loads.
__global__ __launch_bounds__(256) void k_att(
    const float* __restrict__ qb, const float* __restrict__ qpt,
    const float* __restrict__ krow,
    const float* __restrict__ fm, const float* __restrict__ gw,
    const float* __restrict__ dwp, const float* __restrict__ hwp,
    unsigned short* __restrict__ att_hi, unsigned short* __restrict__ att_lo)
{
    int tid = threadIdx.x;
    int w = tid >> 6, lane = tid & 63;
    int iqA = blockIdx.x * 8 + w * 2;
    int iqB = iqA + 1;
    int h = blockIdx.y;

    float qvA[CH], qvB[CH];
    #pragma unroll
    for (int c = 0; c < CH; c++) {
        qvA[c] = qb[(size_t)iqA * 192 + h * CH + c];
        qvB[c] = qb[(size_t)iqB * 192 + h * CH + c];
    }
    float qpA[24], qpB[24];
    #pragma unroll
    for (int j = 0; j < 24; j++) {
        qpA[j] = qpt[(size_t)iqA * 288 + h * 24 + j];
        qpB[j] = qpt[(size_t)iqB * 288 + h * 24 + j];
    }
    float nqA[PQ], nq2A[PQ], nqB[PQ], nq2B[PQ];
    #pragma unroll
    for (int p = 0; p < PQ; p++) {
        float x = qpA[p * 6 + 3], y = qpA[p * 6 + 4], zz = qpA[p * 6 + 5];
        nq2A[p] = x * x + y * y + zz * zz; nqA[p] = sqrtf(nq2A[p]);
        x = qpB[p * 6 + 3]; y = qpB[p * 6 + 4]; zz = qpB[p * 6 + 5];
        nq2B[p] = x * x + y * y + zz * zz; nqB[p] = sqrtf(nq2B[p]);
    }
    float dwv = dwp[0], g0 = gw[0], g1 = gw[1], hwv = hwp[h];
    float fmA = fm[iqA], fmB = fm[iqB];

    float lgA[5], lgB[5];
    for (int r = 0; r < 5; r++) {
        int kk = r * 64 + lane;
        const float* rowp = krow + ((size_t)h * 320 + kk) * 48;
        float rw[44];
        #pragma unroll
        for (int j = 0; j < 44; j++) rw[j] = rowp[j];
        float fmk = fm[kk];

        #pragma unroll
        for (int which = 0; which < 2; which++) {
            const float* qp = which ? qpB : qpA;
            const float* qv = which ? qvB : qvA;
            const float* nq = which ? nqB : nqA;
            const float* nq2 = which ? nq2B : nq2A;
            float fmi = which ? fmB : fmA;

            float scalar = 0.f;
            #pragma unroll
            for (int c = 0; c < CH; c++) scalar += qv[c] * rw[24 + c];
            scalar *= 0.25f;

            float pos = 0.f;
            #pragma unroll
            for (int p = 0; p < PQ; p++) {
                float dx = qp[p * 6] - rw[p * 6];
                float dy = qp[p * 6 + 1] - rw[p * 6 + 1];
                float dz = qp[p * 6 + 2] - rw[p * 6 + 2];
                float d = __builtin_amdgcn_sqrtf(dx * dx + dy * dy + dz * dz);
                float de = d + EPSF;
                pos += d + __logf(de) + __builtin_amdgcn_rcpf(de);
            }
            pos *= 0.25f;

            float dir = 0.f;
            #pragma unroll
            for (int p = 0; p < PQ; p++) {
                float kx = rw[p * 6 + 3], ky = rw[p * 6 + 4], kz = rw[p * 6 + 5];
                float nk = rw[40 + p];
                float nk2 = nk * nk;
                float cm = 0.f, dself = 0.f;
                #pragma unroll
                for (int pq = 0; pq < PQ; pq++) {
                    float dq = qp[pq * 6 + 3] * kx + qp[pq * 6 + 4] * ky + qp[pq * 6 + 5] * kz;
                    if (pq == p) dself = dq;
                    cm += __builtin_amdgcn_sqrtf(fmaxf(nq2[pq] * nk2 - dq * dq, 0.0f));
                }
                cm *= 0.25f;
                dir += dself - cm * __builtin_amdgcn_rcpf(nq[p] * nk + EPSF);
            }
            dir *= 0.25f;

            float logit = scalar + dwv * (g0 * pos + g1 * dir);
            logit *= hwv;
            logit += 100000.0f * (fmi * fmk - 1.0f);
            if (which) lgB[r] = logit; else lgA[r] = logit;
        }
    }

    // softmax for A
    float mxA = lgA[0];
    #pragma unroll
    for (int r = 1; r < 5; r++) mxA = fmaxf(mxA, lgA[r]);
    for (int m = 32; m; m >>= 1) mxA = fmaxf(mxA, __shfl_xor(mxA, m, 64));
    float eA[5], smA = 0.f;
    #pragma unroll
    for (int r = 0; r < 5; r++) { eA[r] = __expf(lgA[r] - mxA); smA += eA[r]; }
    for (int m = 32; m; m >>= 1) smA += __shfl_xor(smA, m, 64);
    float invA = 1.0f / smA;
    #pragma unroll
    for (int r = 0; r < 5; r++) {
        float p = eA[r] * invA;
        unsigned short hi = f2b(p);
        size_t idx = ((size_t)h * 320 + iqA) * 320 + r * 64 + lane;
        att_hi[idx] = hi;
        att_lo[idx] = f2b(p - b2f(hi));
    }
    // softmax for B
    float mxB = lgB[0];
    #pragma unroll
    for (int r = 1; r < 5; r++) mxB = fmaxf(mxB, lgB[r]);
    for (int m = 32; m; m >>= 1) mxB = fmaxf(mxB, __shfl_xor(mxB, m, 64));
    float eB[5], smB = 0.f;
    #pragma unroll
    for (int r = 0; r < 5; r++) { eB[r] = __expf(lgB[r] - mxB); smB += eB[r]; }
    for (int m = 32; m; m >>= 1) smB += __shfl_xor(smB, m, 64);
    float invB = 1.0f / smB;
    #pragma unroll
    for (int r = 0; r < 5; r++) {
        float p = eB[r] * invB;
        unsigned short hi = f2b(p);
        size_t idx = ((size_t)h * 320 + iqB) * 320 + r * 64 + lane;
        att_hi[idx] = hi;
        att_lo[idx] = f2b(p - b2f(hi));
    }
}

// ---------------- kernel 5: fused sv (blocks 0..239) + pair (blocks 240..559) -----
__global__ __launch_bounds__(256) void k_svpair(
    const unsigned short* __restrict__ att_hi, const unsigned short* __restrict__ att_lo,
    const unsigned short* __restrict__ vkv_hi, const unsigned short* __restrict__ vkv_lo,
    const float* __restrict__ z,
    const float* __restrict__ rot, const float* __restrict__ trans,
    unsigned short* __restrict__ cc_hi, unsigned short* __restrict__ cc_lo)
{
    __shared__ unsigned short a_hi[16][56];
    __shared__ unsigned short a_lo[16][56];
    __shared__ unsigned short B[128][56];
    __shared__ float ogsh[16][49];
    int bid = blockIdx.x;
    int tid = threadIdx.x;
    int lane = tid & 63, w = tid >> 6;
    int ncol = lane & 15, blk = lane >> 4, mrow = (lane >> 4) * 4;

    if (bid < 240) {
        int iq0 = (bid % 20) * 16, h = bid / 20;
        f32x4 acc = {};
        for (int k0 = 0; k0 < 320; k0 += 32) {
            __syncthreads();
            if (tid < 64) {
                int row = tid >> 2, seg = tid & 3;
                size_t off = ((size_t)h * 320 + iq0 + row) * 320 + k0 + seg * 8;
                *(short8*)&a_hi[row][seg * 8] = *(const short8*)(att_hi + off);
                *(short8*)&a_lo[row][seg * 8] = *(const short8*)(att_lo + off);
            }
            {
                int row = tid >> 2, seg = tid & 3;
                size_t off = ((size_t)h * 64 + row) * 320 + k0 + seg * 8;
                *(short8*)&B[row][seg * 8]      = *(const short8*)(vkv_hi + off);
                *(short8*)&B[64 + row][seg * 8] = *(const short8*)(vkv_lo + off);
            }
            __syncthreads();
            short8 afh = *(short8*)&a_hi[ncol][blk * 8];
            short8 afl = *(short8*)&a_lo[ncol][blk * 8];
            short8 bfh = *(short8*)&B[w * 16 + ncol][blk * 8];
            short8 bfl = *(short8*)&B[64 + w * 16 + ncol][blk * 8];
            acc = __builtin_amdgcn_mfma_f32_16x16x32_bf16(afh, bfh, acc, 0, 0, 0);
            acc = __builtin_amdgcn_mfma_f32_16x16x32_bf16(afh, bfl, acc, 0, 0, 0);
            acc = __builtin_amdgcn_mfma_f32_16x16x32_bf16(afl, bfh, acc, 0, 0, 0);
        }
        {
            int n = w * 16 + ncol;
            #pragma unroll
            for (int r = 0; r < 4; r++) {
                int iq = iq0 + mrow + r;
                float v = acc[r];
                if (n < 16) {
                    unsigned short hi = f2b(v);
                    size_t idx = (size_t)iq * 2400 + h * 16 + n;
                    cc_hi[idx] = hi;
                    cc_lo[idx] = f2b(v - b2f(hi));
                } else {
                    ogsh[mrow + r][n - 16] = v;
                }
            }
        }
        __syncthreads();
        if (tid < 128) {
            int iqr = tid >> 3, p = tid & 7;
            int l = iq0 + iqr;
            const float* R = rot + l * 9;
            float tx = trans[l * 3], ty = trans[l * 3 + 1], tz = trans[l * 3 + 2];
            const float* o = &ogsh[iqr][p * 6];
            float gx = o[0] - tx, gy = o[1] - ty, gz = o[2] - tz;
            float l0 = R[0] * gx + R[3] * gy + R[6] * gz;
            float l1 = R[1] * gx + R[4] * gy + R[7] * gz;
            float l2 = R[2] * gx + R[5] * gy + R[8] * gz;
            float dx = o[3], dy = o[4], dz = o[5];
            float e0 = R[0] * dx + R[3] * dy + R[6] * dz;
            float e1 = R[1] * dx + R[4] * dy + R[7] * dz;
            float e2 = R[2] * dx + R[5] * dy + R[8] * dz;
            float n = sqrtf(e0 * e0 + e1 * e1 + e2 * e2);
            float inv = 1.0f / fmaxf(n, 1e-12f);
            float ln = sqrtf(l0 * l0 + l1 * l1 + l2 * l2);
            float vals[7] = { l0, l1, l2, e0 * inv, e1 * inv, e2 * inv, ln };
            size_t base = (size_t)l * 2400 + 192 + (h * PV + p) * 7;
            #pragma unroll
            for (int j = 0; j < 7; j++) {
                unsigned short hi = f2b(vals[j]);
                cc_hi[base + j] = hi;
                cc_lo[base + j] = f2b(vals[j] - b2f(hi));
            }
        }
    } else {
        int iq = bid - 240;
        f32x4 acc[2] = {};
        for (int k0 = 0; k0 < 320; k0 += 32) {
            __syncthreads();
            if (tid < 64) {
                int row = tid >> 2, seg = tid & 3;
                size_t off = (size_t)row * 102400 + (size_t)iq * 320 + k0 + seg * 8;
                *(short8*)&a_hi[row][seg * 8] = *(const short8*)(att_hi + off);
                *(short8*)&a_lo[row][seg * 8] = *(const short8*)(att_lo + off);
            }
            {
                // swapped mapping: lanes sharing kp2 drop 16 -> 4 (bank conflicts 16-way -> 4-way)
                int kp2 = (tid & 15) * 2;
                int cb = (tid >> 4) * 8;
                const float* src0 = z + ((size_t)iq * 320 + k0 + kp2) * 128 + cb;
                float4 a0 = *(const float4*)(src0);
                float4 a1 = *(const float4*)(src0 + 4);
                float4 b0 = *(const float4*)(src0 + 128);
                float4 b1 = *(const float4*)(src0 + 132);
                float va[8] = {a0.x, a0.y, a0.z, a0.w, a1.x, a1.y, a1.z, a1.w};
                float vb[8] = {b0.x, b0.y, b0.z, b0.w, b1.x, b1.y, b1.z, b1.w};
                #pragma unroll
                for (int c = 0; c < 8; c++) {
                    ush2 pr;
                    pr[0] = f2b(va[c]);
                    pr[1] = f2b(vb[c]);
                    *(ush2*)&B[cb + c][kp2] = pr;
                }
            }
            __syncthreads();
            short8 afh = *(short8*)&a_hi[ncol][blk * 8];
            short8 afl = *(short8*)&a_lo[ncol][blk * 8];
            #pragma unroll
            for (int s2 = 0; s2 < 2; s2++) {
                short8 bf = *(short8*)&B[w * 32 + s2 * 16 + ncol][blk * 8];
                acc[s2] = __builtin_amdgcn_mfma_f32_16x16x32_bf16(afl, bf, acc[s2], 0, 0, 0);
                acc[s2] = __builtin_amdgcn_mfma_f32_16x16x32_bf16(afh, bf, acc[s2], 0, 0, 0);
            }
        }
        #pragma unroll
        for (int s2 = 0; s2 < 2; s2++) {
            int n = w * 32 + s2 * 16 + ncol;
            #pragma unroll
            for (int r = 0; r < 4; r++) {
                int h = mrow + r;
                if (h < 12) {
                    float v = acc[s2][r];
                    unsigned short hi = f2b(v);
                    size_t idx = (size_t)iq * 2400 + 864 + h * 128 + n;
                    cc_hi[idx] = hi;
                    cc_lo[idx] = f2b(v - b2f(hi));
                }
            }
        }
    }
}

// ---------------- kernel 8: partials = cc @ Wo via split MFMA, m=16 tiles ---------
// grid (20 m-tiles of 16, 6 n-tiles of 64, 5 k-splits of 480), 256 thr.
__global__ __launch_bounds__(256) void k_gemm(
    const unsigned short* __restrict__ cc_hi, const unsigned short* __restrict__ cc_lo,
    const unsigned short* __restrict__ woT_hi, const unsigned short* __restrict__ woT_lo,
    float* __restrict__ part)
{
    __shared__ unsigned short a_h[16][56], a_l[16][56];
    __shared__ unsigned short w_h[64][56], w_l[64][56];
    int iq0 = blockIdx.x * 16, col0 = blockIdx.y * 64, ks = blockIdx.z;
    int tid = threadIdx.x;
    int lane = tid & 63, w = tid >> 6;
    int ncol = lane & 15, blk = lane >> 4, mrow = (lane >> 4) * 4;

    f32x4 acc = {};
    for (int kc = 0; kc < 15; kc++) {
        int k0 = ks * 480 + kc * 32;
        __syncthreads();
        if (tid < 128) {
            int arr = tid >> 6, idx = tid & 63;
            int row = idx >> 2, seg = idx & 3;
            size_t off = (size_t)(iq0 + row) * 2400 + k0 + seg * 8;
            if (arr == 0) *(short8*)&a_h[row][seg * 8] = *(const short8*)(cc_hi + off);
            else          *(short8*)&a_l[row][seg * 8] = *(const short8*)(cc_lo + off);
        }
        #pragma unroll
        for (int t2 = 0; t2 < 2; t2++) {
            int idx = tid * 2 + t2;          // 0..511
            int arr = idx >> 8, i2 = idx & 255;
            int row = i2 >> 2, seg = i2 & 3;
            size_t off = (size_t)(col0 + row) * 2400 + k0 + seg * 8;
            if (arr == 0) *(short8*)&w_h[row][seg * 8] = *(const short8*)(woT_hi + off);
            else          *(short8*)&w_l[row][seg * 8] = *(const short8*)(woT_lo + off);
        }
        __syncthreads();
        short8 afh = *(short8*)&a_h[ncol][blk * 8];
        short8 afl = *(short8*)&a_l[ncol][blk * 8];
        short8 bfh = *(short8*)&w_h[w * 16 + ncol][blk * 8];
        short8 bfl = *(short8*)&w_l[w * 16 + ncol][blk * 8];
        acc = __builtin_amdgcn_mfma_f32_16x16x32_bf16(afh, bfh, acc, 0, 0, 0);
        acc = __builtin_amdgcn_mfma_f32_16x16x32_bf16(afh, bfl, acc, 0, 0, 0);
        acc = __builtin_amdgcn_mfma_f32_16x16x32_bf16(afl, bfh, acc, 0, 0, 0);
    }
    {
        int cn = col0 + w * 16 + ncol;
        #pragma unroll
        for (int r = 0; r < 4; r++)
            part[((size_t)ks * 320 + iq0 + mrow + r) * 384 + cn] = acc[r];
    }
}

// ---------------- kernel 9: out = bo + sum of 5 partials (deterministic) ----------
__global__ __launch_bounds__(256) void k_reduce(
    const float* __restrict__ part, const float* __restrict__ bo, float* __restrict__ out)
{
    int i = blockIdx.x * 256 + threadIdx.x;   // < 122880
    float v = bo[i % CS];
    #pragma unroll
    for (int ks = 0; ks < 5; ks++) v += part[(size_t)ks * 122880 + i];
    out[i] = v;
}

extern "C" void kernel_launch(void* const* d_in, const int* in_sizes, int n_in,
                              void* d_out, int out_size, void* d_ws, size_t ws_size,
                              hipStream_t stream)
{
    const float* s     = (const float*)d_in[0];
    const float* rot   = (const float*)d_in[1];
    const float* trans = (const float*)d_in[2];
    const float* z     = (const float*)d_in[3];
    const float* fm    = (const float*)d_in[4];
    const float* Wq    = (const float*)d_in[5];
    const float* bq    = (const float*)d_in[6];
    const float* Wkv   = (const float*)d_in[7];
    const float* bkv   = (const float*)d_in[8];
    const float* Wqp   = (const float*)d_in[9];
    const float* bqp   = (const float*)d_in[10];
    const float* Wkvp  = (const float*)d_in[11];
    const float* bkvp  = (const float*)d_in[12];
    const float* Wg    = (const float*)d_in[13];
    const float* bg    = (const float*)d_in[14];
    const float* gw    = (const float*)d_in[15];
    const float* dw    = (const float*)d_in[16];
    const float* hw    = (const float*)d_in[17];
    const float* Wo    = (const float*)d_in[18];
    const float* bo    = (const float*)d_in[19];

    float* ws = (float*)d_ws;
    float*          q       = ws + OFF_Q;
    float*          kv      = ws + OFF_KV;
    float*          qpt     = ws + OFF_QPT;
    unsigned short* att_hi  = (unsigned short*)(ws + OFF_ATTHI);
    unsigned short* att_lo  = (unsigned short*)(ws + OFF_ATTLO);
    float*          ph_hi   = ws + OFF_ATTHI + 12 * 51200;
    float*          ph_lo   = ws + OFF_ATTLO + 12 * 51200;
    unsigned short* cc_hi   = (unsigned short*)(ws + OFF_CCHI);
    unsigned short* cc_lo   = (unsigned short*)(ws + OFF_CCLO);
    unsigned short* s_hi    = (unsigned short*)(ws + OFF_SHI);
    unsigned short* s_mid   = (unsigned short*)(ws + OFF_SMID);
    unsigned short* s_lo    = (unsigned short*)(ws + OFF_SLO);
    unsigned short* wc_hi   = (unsigned short*)(ws + OFF_WCATHI);
    unsigned short* wc_mid  = (unsigned short*)(ws + OFF_WCATMID);
    unsigned short* wc_lo   = (unsigned short*)(ws + OFF_WCATLO);
    float*          bcat    = ws + OFF_BCAT;
    unsigned short* wo_hi   = (unsigned short*)(ws + OFF_WOHI);
    unsigned short* wo_lo   = (unsigned short*)(ws + OFF_WOLO);
    unsigned short* vkv_hi  = (unsigned short*)(ws + OFF_VKVHI);
    unsigned short* vkv_lo  = (unsigned short*)(ws + OFF_VKVLO);
    float*          qpr     = ws + OFF_QPR;
    float*          kvpr    = ws + OFF_KVPR;
    float*          gate    = ws + OFF_GATE;
    float*          part    = ws + OFF_PART;
    float*          krow    = ws + OFF_KROW;
    unsigned short* wcT_hi  = (unsigned short*)(ws + OFF_WCTHI);
    unsigned short* wcT_mid = (unsigned short*)(ws + OFF_WCTMID);
    unsigned short* wcT_lo  = (unsigned short*)(ws + OFF_WCTLO);
    unsigned short* woT_hi  = (unsigned short*)(ws + OFF_WOTHI);
    unsigned short* woT_lo  = (unsigned short*)(ws + OFF_WOTLO);
    float* out = (float*)d_out;

    k_cast<<<dim3(8352), dim3(256), 0, stream>>>(s, Wq, bq, Wkv, bkv, Wqp, bqp,
                                                 Wkvp, bkvp, Wg, bg, Wo,
                                                 s_hi, s_mid, s_lo, wc_hi, wc_mid, wc_lo,
                                                 bcat, wo_hi, wo_lo, ph_hi, ph_lo);
    k_tr<<<dim3(38, 28, 5), dim3(256), 0, stream>>>(wc_hi, wc_mid, wc_lo, wo_hi, wo_lo,
                                                    wcT_hi, wcT_mid, wcT_lo, woT_hi, woT_lo);
    k_proj<<<dim3(37, 20), dim3(192), 0, stream>>>(s_hi, s_mid, s_lo, wcT_hi, wcT_mid, wcT_lo,
                                                   bcat, q, kv, qpr, kvpr, gate);
    k_points<<<dim3(LSEQ), dim3(256), 0, stream>>>(qpr, kvpr, gate, rot, trans, kv,
                                                   qpt, krow, vkv_hi, vkv_lo);
    k_att<<<dim3(40, NH), dim3(256), 0, stream>>>(q, qpt, krow, fm, gw, dw, hw,
                                                  att_hi, att_lo);
    k_svpair<<<dim3(560), dim3(256), 0, stream>>>(att_hi, att_lo, vkv_hi, vkv_lo, z,
                                                  rot, trans, cc_hi, cc_lo);
    k_gemm<<<dim3(20, 6, 5), dim3(256), 0, stream>>>(cc_hi, cc_lo, woT_hi, woT_lo, part);
    k_reduce<<<dim3(480), dim3(256), 0, stream>>>(part, bo, out);
}